// Round 7
// baseline (2324.517 us; speedup 1.0000x reference)
//
#include <hip/hip_runtime.h>
#include <hip/hip_bf16.h>

// All inputs/outputs are float32 (per the reference file's setup_inputs).

// 16-lane butterfly sum via DPP (VALU, no DS-pipe traffic).
static __device__ __forceinline__ float dpp_sum16(float x)
{
    x += __int_as_float(__builtin_amdgcn_update_dpp(
        0, __float_as_int(x), 0xB1, 0xF, 0xF, true));   // quad_perm [1,0,3,2]
    x += __int_as_float(__builtin_amdgcn_update_dpp(
        0, __float_as_int(x), 0x4E, 0xF, 0xF, true));   // quad_perm [2,3,0,1]
    x += __int_as_float(__builtin_amdgcn_update_dpp(
        0, __float_as_int(x), 0x141, 0xF, 0xF, true));  // row_half_mirror
    x += __int_as_float(__builtin_amdgcn_update_dpp(
        0, __float_as_int(x), 0x140, 0xF, 0xF, true));  // row_mirror
    return x;
}

__device__ __forceinline__ void loadw9(float* wf, const float* wbase)
{
    const float4* wq = (const float4*)wbase;
#pragma unroll
    for (int m = 0; m < 9; ++m) *(float4*)&wf[m * 4] = wq[m];
}

// ---------------------------------------------------------------------------
// 3x3 SAME conv, 64->64 ch, NCHW. Block = one (b,h) row, 512 threads (8
// waves = 2/SIMD for latency overlap). lane = w pixel; wave owns 8 co.
// Weights: double-buffered float4 prefetch (next co loads issue during
// current co's FMAs); 4 partial accumulators break the FMA dep chain.
// ---------------------------------------------------------------------------
__global__ __launch_bounds__(512) void conv3x3_k(const float* __restrict__ in,
    const float* __restrict__ w, const float* __restrict__ bias,
    const float* __restrict__ addsrc, float* __restrict__ out)
{
    const int bh = blockIdx.x;
    const int b = bh >> 6, h = bh & 63;
    const int t = threadIdx.x;
    __shared__ float lin[3 * 4096];  // [r][ci][w]
    for (int e4 = t; e4 < 3072; e4 += 512) {
        const int flat = e4 * 4;
        const int r = flat >> 12, ci = (flat >> 6) & 63, w4 = flat & 63;
        const int hh = h - 1 + r;
        float4 v = make_float4(0.f, 0.f, 0.f, 0.f);
        if (hh >= 0 && hh < 64)
            v = *(const float4*)&in[((b * 64 + ci) * 64 + hh) * 64 + w4];
        *(float4*)&lin[flat] = v;
    }
    __syncthreads();
    const int wv = t >> 6;       // wave id 0..7
    const int lane = t & 63;     // = w pixel
    const int co0 = wv * 8;
    float acc[8];
#pragma unroll
    for (int i = 0; i < 8; ++i) acc[i] = bias[co0 + i];

    float wf0[36], wf1[36];
    loadw9(wf0, w + ((size_t)co0 * 64 + 0) * 9);
    loadw9(wf0 + 12, w + ((size_t)co0 * 64 + 0) * 9 + 12);
    loadw9(wf0 + 24, w + ((size_t)co0 * 64 + 0) * 9 + 24);
    // (loadw9 loads 36 floats via 9 float4 — the three calls above are
    //  redundant-safe: first call already loads all 36; keep single use)
    for (int ci4 = 0; ci4 < 64; ci4 += 4) {
        float rvv[36];
#pragma unroll
        for (int c = 0; c < 4; ++c) {
#pragma unroll
            for (int r = 0; r < 3; ++r) {
                const float* row = &lin[r * 4096 + (ci4 + c) * 64];
                const float vc = row[lane];
                const float vm = (lane > 0) ? row[lane - 1] : 0.f;
                const float vn = (lane < 63) ? row[lane + 1] : 0.f;
                rvv[c * 9 + r * 3 + 0] = vm;
                rvv[c * 9 + r * 3 + 1] = vc;
                rvv[c * 9 + r * 3 + 2] = vn;
            }
        }
#pragma unroll
        for (int i = 0; i < 8; ++i) {
            float* cur = (i & 1) ? wf1 : wf0;
            float* nxt = (i & 1) ? wf0 : wf1;
            const int ni = (i == 7) ? 0 : i + 1;
            const int nci = (i == 7) ? ci4 + 4 : ci4;
            if (nci < 64)
                loadw9(nxt, w + ((size_t)(co0 + ni) * 64 + nci) * 9);
            float p0 = 0.f, p1 = 0.f, p2 = 0.f, p3 = 0.f;
#pragma unroll
            for (int q = 0; q < 36; q += 4) {
                p0 = fmaf(rvv[q + 0], cur[q + 0], p0);
                p1 = fmaf(rvv[q + 1], cur[q + 1], p1);
                p2 = fmaf(rvv[q + 2], cur[q + 2], p2);
                p3 = fmaf(rvv[q + 3], cur[q + 3], p3);
            }
            acc[i] += (p0 + p1) + (p2 + p3);
        }
    }
#pragma unroll
    for (int i = 0; i < 8; ++i) {
        const size_t o = ((size_t)(b * 64 + co0 + i) * 64 + h) * 64 + lane;
        float v = acc[i];
        if (addsrc) v += addsrc[o];
        out[o] = v;
    }
}

// ---------------------------------------------------------------------------
// InstanceNorm over HxW per (b,c) + LeakyReLU(0.2). Block per (b,c).
// ---------------------------------------------------------------------------
__global__ __launch_bounds__(256) void inorm_lrelu_k(const float* __restrict__ in,
                                                     float* __restrict__ out)
{
    const int bc = blockIdx.x;
    const float* row = in + (size_t)bc * 4096;
    float s1 = 0.f, s2 = 0.f;
    for (int i = threadIdx.x; i < 4096; i += 256) {
        const float v = row[i];
        s1 += v; s2 = fmaf(v, v, s2);
    }
#pragma unroll
    for (int mk = 1; mk < 64; mk <<= 1) {
        s1 += __shfl_xor(s1, mk, 64);
        s2 += __shfl_xor(s2, mk, 64);
    }
    __shared__ float a1[4], a2[4];
    const int wid = threadIdx.x >> 6;
    if ((threadIdx.x & 63) == 0) { a1[wid] = s1; a2[wid] = s2; }
    __syncthreads();
    const float S1 = a1[0] + a1[1] + a1[2] + a1[3];
    const float S2 = a2[0] + a2[1] + a2[2] + a2[3];
    const float mu = S1 * (1.f / 4096.f);
    const float var = S2 * (1.f / 4096.f) - mu * mu;
    const float rstd = rsqrtf(var + 1e-5f);
    float* orow = out + (size_t)bc * 4096;
    for (int i = threadIdx.x; i < 4096; i += 256) {
        float v = (row[i] - mu) * rstd;
        v = (v >= 0.f) ? v : 0.2f * v;
        orow[i] = v;
    }
}

// ---------------------------------------------------------------------------
// LayerNorm over 64 ch (NHWC view of x1) + in_proj (256x64). No LDS.
// ---------------------------------------------------------------------------
__global__ __launch_bounds__(256) void ln_inproj_k(const float* __restrict__ x1,
    const float* __restrict__ g, const float* __restrict__ be,
    const float* __restrict__ w, float* __restrict__ xin_raw, float* __restrict__ z)
{
    const int bx = blockIdx.x;
    const int b = bx >> 7, l0 = (bx & 127) * 32;
    const int t = threadIdx.x;
    const int j = t & 31, co0 = (t >> 5) * 32;
    float xr[64];
    float s1 = 0.f, s2 = 0.f;
#pragma unroll
    for (int c = 0; c < 64; ++c) {
        const float v = x1[(b * 64 + c) * 4096 + l0 + j];
        xr[c] = v; s1 += v; s2 = fmaf(v, v, s2);
    }
    const float mu = s1 * (1.f / 64.f);
    const float var = s2 * (1.f / 64.f) - mu * mu;
    const float rstd = rsqrtf(var + 1e-5f);
#pragma unroll
    for (int c = 0; c < 64; ++c)
        xr[c] = (xr[c] - mu) * rstd * g[c] + be[c];
    for (int i = 0; i < 32; ++i) {
        const int e = co0 + i;
        const float4* wp = (const float4*)(w + e * 64);
        float a = 0.f;
#pragma unroll
        for (int c4 = 0; c4 < 16; ++c4) {
            const float4 wv = wp[c4];
            a = fmaf(xr[c4 * 4 + 0], wv.x, a);
            a = fmaf(xr[c4 * 4 + 1], wv.y, a);
            a = fmaf(xr[c4 * 4 + 2], wv.z, a);
            a = fmaf(xr[c4 * 4 + 3], wv.w, a);
        }
        if (e < 128) xin_raw[(b * 128 + e) * 4096 + l0 + j] = a;
        else z[((size_t)(b * 4096 + l0 + j)) * 128 + (e - 128)] = a;
    }
}

// ---------------------------------------------------------------------------
// Depthwise 3x3 SAME conv + bias + SiLU on (b,128,64,64).
// ---------------------------------------------------------------------------
__global__ __launch_bounds__(256) void dwconv_silu_k(const float* __restrict__ in,
    const float* __restrict__ w, const float* __restrict__ bias, float* __restrict__ out)
{
    const int idx = blockIdx.x * 256 + threadIdx.x;  // (b*128+d)*4096 + l
    const int l = idx & 4095, bd = idx >> 12, d = bd & 127;
    const int hh = l >> 6, ww = l & 63;
    const float* base = in + (size_t)bd * 4096;
    float acc = bias[d];
    const float* wp = w + d * 9;
#pragma unroll
    for (int dy = 0; dy < 3; ++dy) {
        const int y = hh + dy - 1;
        if (y < 0 || y > 63) continue;
#pragma unroll
        for (int dx = 0; dx < 3; ++dx) {
            const int xx = ww + dx - 1;
            if (xx < 0 || xx > 63) continue;
            acc = fmaf(base[y * 64 + xx], wp[dy * 3 + dx], acc);
        }
    }
    out[idx] = acc / (1.f + __expf(-acc));  // silu
}

// ---------------------------------------------------------------------------
// 64x64 spatial transpose per (b,d).
// ---------------------------------------------------------------------------
__global__ __launch_bounds__(256) void transpose_k(const float* __restrict__ in,
                                                   float* __restrict__ out)
{
    const int bd = blockIdx.x;
    __shared__ float tl[64 * 65];
    const float* src = in + (size_t)bd * 4096;
    for (int e = threadIdx.x; e < 4096; e += 256) {
        const int r = e >> 6, c = e & 63;
        tl[r * 65 + c] = src[e];
    }
    __syncthreads();
    float* dst = out + (size_t)bd * 4096;
    for (int e = threadIdx.x; e < 4096; e += 256) {
        const int wi = e >> 6, hi = e & 63;
        dst[e] = tl[hi * 65 + wi];
    }
}

// ---------------------------------------------------------------------------
// x_dbl[b,k,c,m] = sum_d xs[b,k,d,m] * x_proj_w[k,c,d]  (c=36, scan order m).
// LDS tile [j][d] (pad 132) -> ds_read_b128 over d; float4 weight loads.
// ---------------------------------------------------------------------------
__global__ __launch_bounds__(256) void xdbl_k(const float* __restrict__ xin_s,
    const float* __restrict__ xin_T, const float* __restrict__ xpw,
    float* __restrict__ xdbl)
{
    const int bx = blockIdx.x;
    const int bk = bx >> 7, m0 = (bx & 127) * 32;
    const int b = bk >> 2, k = bk & 3;
    __shared__ float tl[32 * 132];   // [j][d], pad 132
    const float* src = (k & 1) ? xin_T : xin_s;
    const bool rev = (k >= 2);
    for (int e = threadIdx.x; e < 4096; e += 256) {
        const int d = e >> 5, j = e & 31;
        const int m = m0 + j;
        const int um = rev ? (4095 - m) : m;
        tl[j * 132 + d] = src[(b * 128 + d) * 4096 + um];
    }
    __syncthreads();
    const int j = threadIdx.x & 31, c0 = threadIdx.x >> 5;
    const float4* xv4 = (const float4*)(tl + j * 132);
    float acc[5] = {0.f, 0.f, 0.f, 0.f, 0.f};
    for (int d4 = 0; d4 < 32; ++d4) {
        const float4 xv = xv4[d4];
#pragma unroll
        for (int q = 0; q < 5; ++q) {
            const int c = c0 + q * 8;
            if (c < 36) {
                const float4 wv = *(const float4*)&xpw[((size_t)(k * 36 + c)) * 128 + d4 * 4];
                acc[q] = fmaf(xv.x, wv.x, acc[q]);
                acc[q] = fmaf(xv.y, wv.y, acc[q]);
                acc[q] = fmaf(xv.z, wv.z, acc[q]);
                acc[q] = fmaf(xv.w, wv.w, acc[q]);
            }
        }
    }
#pragma unroll
    for (int q = 0; q < 5; ++q) {
        const int c = c0 + q * 8;
        if (c < 36) xdbl[((size_t)bk * 36 + c) * 4096 + m0 + j] = acc[q];
    }
}

// ---------------------------------------------------------------------------
// Segmented selective scan, phase 1 (unchanged).
// ---------------------------------------------------------------------------
__global__ __launch_bounds__(256) void scan_p1_k(const float* __restrict__ xdbl,
    const float* __restrict__ xin_s, const float* __restrict__ xin_T,
    const float* __restrict__ A_logs, const float* __restrict__ dtw,
    const float* __restrict__ dtb, float* __restrict__ hseg,
    float* __restrict__ pseg)
{
    const int bx = blockIdx.x;
    const int seg = bx & 31, d8 = (bx >> 5) & 7, bk = bx >> 8;
    const int b = bk >> 2, k = bk & 3;
    const int t = threadIdx.x;
    const int chain = t >> 4, n = t & 15;
    const int d = d8 * 16 + chain;
    const float A = -__expf(A_logs[(k * 128 + d) * 16 + n]);
    __shared__ float sB[16 * 132], sdt[16 * 132], su[16 * 132];
    const float* srcu = (k & 1) ? xin_T : xin_s;
    const bool rev = (k >= 2);
    const int jj = t & 127, half = t >> 7;
    const int m0 = seg * 128;
    {
        const float dts0 = xdbl[((size_t)bk * 36 + 0) * 4096 + m0 + jj];
        const float dts1 = xdbl[((size_t)bk * 36 + 1) * 4096 + m0 + jj];
        const float dts2 = xdbl[((size_t)bk * 36 + 2) * 4096 + m0 + jj];
        const float dts3 = xdbl[((size_t)bk * 36 + 3) * 4096 + m0 + jj];
        const int m = m0 + jj;
        const int um = rev ? (4095 - m) : m;
#pragma unroll
        for (int i = 0; i < 8; ++i) {
            const int nn = half + 2 * i;
            sB[nn * 132 + jj] = xdbl[((size_t)bk * 36 + 4 + nn) * 4096 + m0 + jj];
            const int dd = d8 * 16 + nn;
            const float* wp = dtw + (k * 128 + dd) * 4;
            float s = dtb[k * 128 + dd];
            s = fmaf(dts0, wp[0], s);
            s = fmaf(dts1, wp[1], s);
            s = fmaf(dts2, wp[2], s);
            s = fmaf(dts3, wp[3], s);
            sdt[nn * 132 + jj] = (s > 20.f) ? s : log1pf(__expf(s));
            su[nn * 132 + jj] = srcu[(b * 128 + dd) * 4096 + um];
        }
    }
    __syncthreads();
    const float4* B4  = (const float4*)(sB + n * 132);
    const float4* dt4 = (const float4*)(sdt + chain * 132);
    const float4* u4  = (const float4*)(su + chain * 132);
    float h = 0.f, pr = 1.f;
#pragma unroll 4
    for (int q = 0; q < 32; ++q) {
        const float4 dt = dt4[q], uu = u4[q], BB = B4[q];
        float a;
        a = __expf(dt.x * A); h = fmaf(h, a, dt.x * uu.x * BB.x); pr *= a;
        a = __expf(dt.y * A); h = fmaf(h, a, dt.y * uu.y * BB.y); pr *= a;
        a = __expf(dt.z * A); h = fmaf(h, a, dt.z * uu.z * BB.z); pr *= a;
        a = __expf(dt.w * A); h = fmaf(h, a, dt.w * uu.w * BB.w); pr *= a;
    }
    const size_t idx = (size_t)seg * 32768 + (size_t)(bk * 128 + d) * 16 + n;
    hseg[idx] = h;
    pseg[idx] = pr;
}

// ---------------------------------------------------------------------------
// Combine segment summaries (coalesced). pseg is overwritten with h_start.
// ---------------------------------------------------------------------------
__global__ __launch_bounds__(256) void scan_combine_k(const float* __restrict__ hseg,
                                                      float* __restrict__ pseg)
{
    const int i = blockIdx.x * 256 + threadIdx.x;  // 0..32767
    float h = 0.f;
#pragma unroll 4
    for (int s = 0; s < 32; ++s) {
        const size_t idx = (size_t)s * 32768 + i;
        const float p = pseg[idx];
        const float he = hseg[idx];
        pseg[idx] = h;
        h = fmaf(h, p, he);
    }
}

// ---------------------------------------------------------------------------
// Segmented scan, phase 2: recurrence seeded with h_start; y via DPP butterfly
// into LDS tile, then stored into ybuf[k][b][l_out][d] at the OUTPUT position
// (direction map applied at store). k==0 blocks fold in Dsum*u. No atomics.
// ---------------------------------------------------------------------------
__global__ __launch_bounds__(256) void scan_p2_k(const float* __restrict__ xdbl,
    const float* __restrict__ xin_s, const float* __restrict__ xin_T,
    const float* __restrict__ A_logs, const float* __restrict__ dtw,
    const float* __restrict__ dtb, const float* __restrict__ hstart,
    const float* __restrict__ Dsp, float* __restrict__ ybuf)
{
    const int bx = blockIdx.x;
    const int seg = bx & 31, d8 = (bx >> 5) & 7, bk = bx >> 8;
    const int b = bk >> 2, k = bk & 3;
    const int t = threadIdx.x;
    const int chain = t >> 4, n = t & 15;
    const int d = d8 * 16 + chain;
    const float A = -__expf(A_logs[(k * 128 + d) * 16 + n]);
    __shared__ float sB[16 * 132], sC[16 * 132], sdt[16 * 132], su[16 * 132];
    __shared__ float sy[128 * 16];  // [j][dd]
    const float* srcu = (k & 1) ? xin_T : xin_s;
    const bool rev = (k >= 2);
    const int jj = t & 127, half = t >> 7;
    const int m0 = seg * 128;
    {
        const float dts0 = xdbl[((size_t)bk * 36 + 0) * 4096 + m0 + jj];
        const float dts1 = xdbl[((size_t)bk * 36 + 1) * 4096 + m0 + jj];
        const float dts2 = xdbl[((size_t)bk * 36 + 2) * 4096 + m0 + jj];
        const float dts3 = xdbl[((size_t)bk * 36 + 3) * 4096 + m0 + jj];
        const int m = m0 + jj;
        const int um = rev ? (4095 - m) : m;
#pragma unroll
        for (int i = 0; i < 8; ++i) {
            const int nn = half + 2 * i;
            sB[nn * 132 + jj] = xdbl[((size_t)bk * 36 + 4 + nn) * 4096 + m0 + jj];
            sC[nn * 132 + jj] = xdbl[((size_t)bk * 36 + 20 + nn) * 4096 + m0 + jj];
            const int dd = d8 * 16 + nn;
            const float* wp = dtw + (k * 128 + dd) * 4;
            float s = dtb[k * 128 + dd];
            s = fmaf(dts0, wp[0], s);
            s = fmaf(dts1, wp[1], s);
            s = fmaf(dts2, wp[2], s);
            s = fmaf(dts3, wp[3], s);
            sdt[nn * 132 + jj] = (s > 20.f) ? s : log1pf(__expf(s));
            su[nn * 132 + jj] = srcu[(b * 128 + dd) * 4096 + um];
        }
    }
    __syncthreads();
    const float4* B4  = (const float4*)(sB + n * 132);
    const float4* C4  = (const float4*)(sC + n * 132);
    const float4* dt4 = (const float4*)(sdt + chain * 132);
    const float4* u4  = (const float4*)(su + chain * 132);
    float h = hstart[(size_t)seg * 32768 + (size_t)(bk * 128 + d) * 16 + n];
#pragma unroll 4
    for (int q = 0; q < 32; ++q) {
        const float4 dt = dt4[q], uu = u4[q], BB = B4[q], CC = C4[q];
        float a, p;
#define SCAN_STEP(E, IDX)                                                     \
        a = __expf(dt.E * A);                                                 \
        h = fmaf(h, a, dt.E * uu.E * BB.E);                                   \
        p = dpp_sum16(h * CC.E);                                              \
        if (n == 0) sy[(q * 4 + IDX) * 16 + chain] = p;
        SCAN_STEP(x, 0)
        SCAN_STEP(y, 1)
        SCAN_STEP(z, 2)
        SCAN_STEP(w, 3)
#undef SCAN_STEP
    }
    __syncthreads();
    // store at OUTPUT l (direction map). Each thread has fixed local d.
    const int ddl = t & 15;
    const int dg = d8 * 16 + ddl;
    const float Dsum = (k == 0)
        ? (Dsp[dg] + Dsp[128 + dg] + Dsp[256 + dg] + Dsp[384 + dg]) : 0.f;
    float* yk = ybuf + (size_t)(k * 4 + b) * 4096 * 128;
#pragma unroll
    for (int p2 = 0; p2 < 8; ++p2) {
        const int e = p2 * 256 + t;
        const int j = e >> 4;               // 0..127
        const int m = m0 + j;
        int l;
        if (k == 0) l = m;
        else if (k == 1) l = ((m & 63) << 6) | (m >> 6);
        else if (k == 2) l = 4095 - m;
        else { const int mf = 4095 - m; l = ((mf & 63) << 6) | (mf >> 6); }
        float v = sy[j * 16 + ddl];
        if (k == 0) v = fmaf(Dsum, su[ddl * 132 + j], v);
        yk[(size_t)l * 128 + dg] = v;
    }
}

// ---------------------------------------------------------------------------
// Finalize: v[d] = sum_k ybuf[k][b][l][d] (Dsum*u already folded in k=0);
// LN over 128; * silu(z); out_proj GEMV (8 co per thread-group);
// LDS-transposed coalesced store of res + skip*x1. Block = 32 l, 256 thr.
// ---------------------------------------------------------------------------
__global__ __launch_bounds__(256) void finalize_k(const float* __restrict__ ybuf,
    const float* __restrict__ z, const float* __restrict__ x1,
    const float* __restrict__ ong, const float* __restrict__ onb,
    const float* __restrict__ opw, const float* __restrict__ skipp,
    float* __restrict__ res)
{
    const int bx = blockIdx.x;               // b*128 + tile
    const int b = bx >> 7, l0 = (bx & 127) * 32;
    const int t = threadIdx.x;
    const int j = t & 31, g = t >> 5;        // g 0..7
    const int l = l0 + j;
    const float4* y0p = (const float4*)(ybuf + ((size_t)(0 + b) * 4096 + l) * 128);
    const float4* y1p = (const float4*)(ybuf + ((size_t)(4 + b) * 4096 + l) * 128);
    const float4* y2p = (const float4*)(ybuf + ((size_t)(8 + b) * 4096 + l) * 128);
    const float4* y3p = (const float4*)(ybuf + ((size_t)(12 + b) * 4096 + l) * 128);
    float4 v4[32];
    float s1 = 0.f, s2 = 0.f;
#pragma unroll
    for (int d4 = 0; d4 < 32; ++d4) {
        const float4 a0 = y0p[d4], a1 = y1p[d4], a2 = y2p[d4], a3 = y3p[d4];
        float4 a;
        a.x = (a0.x + a1.x) + (a2.x + a3.x);
        a.y = (a0.y + a1.y) + (a2.y + a3.y);
        a.z = (a0.z + a1.z) + (a2.z + a3.z);
        a.w = (a0.w + a1.w) + (a2.w + a3.w);
        v4[d4] = a;
        s1 += (a.x + a.y) + (a.z + a.w);
        s2 = fmaf(a.x, a.x, s2); s2 = fmaf(a.y, a.y, s2);
        s2 = fmaf(a.z, a.z, s2); s2 = fmaf(a.w, a.w, s2);
    }
    const float mu = s1 * (1.f / 128.f);
    const float var = s2 * (1.f / 128.f) - mu * mu;
    const float rstd = rsqrtf(var + 1e-5f);
    const float4* zp = (const float4*)(z + ((size_t)(b * 4096 + l)) * 128);
    const float4* gp = (const float4*)ong;
    const float4* bp = (const float4*)onb;
#pragma unroll
    for (int d4 = 0; d4 < 32; ++d4) {
        const float4 gg = gp[d4], bb = bp[d4], zz = zp[d4];
        float4 a = v4[d4];
#define GATE(E)                                                               \
        {                                                                     \
            const float yln = (a.E - mu) * rstd * gg.E + bb.E;                \
            a.E = yln * (zz.E / (1.f + __expf(-zz.E)));                       \
        }
        GATE(x) GATE(y) GATE(z) GATE(w)
#undef GATE
        v4[d4] = a;
    }
    float acc[8] = {0.f, 0.f, 0.f, 0.f, 0.f, 0.f, 0.f, 0.f};
    for (int d4 = 0; d4 < 32; ++d4) {
        const float4 a = v4[d4];
#pragma unroll
        for (int q = 0; q < 8; ++q) {
            const float4 wv = *(const float4*)&opw[(size_t)(g * 8 + q) * 128 + d4 * 4];
            acc[q] = fmaf(a.x, wv.x, acc[q]);
            acc[q] = fmaf(a.y, wv.y, acc[q]);
            acc[q] = fmaf(a.z, wv.z, acc[q]);
            acc[q] = fmaf(a.w, wv.w, acc[q]);
        }
    }
    __shared__ float sres[64 * 33];
#pragma unroll
    for (int q = 0; q < 8; ++q) sres[(g * 8 + q) * 33 + j] = acc[q];
    __syncthreads();
    const float sk = skipp[0];
    for (int e = t; e < 2048; e += 256) {
        const int co = e >> 5, jj = e & 31;
        const size_t o = ((size_t)(b * 64 + co)) * 4096 + l0 + jj;
        res[o] = sres[co * 33 + jj] + sk * x1[o];
    }
}

// ---------------------------------------------------------------------------
// Workspace layout (floats), total 20,185,088 floats = 77.0 MB (as R6):
//   x1 @0 (1M), xin_s @1M (2M), zbuf @3M (2M), xin_T @5M (2M),
//   xdbl @7,340,032 (2,359,296), ybuf @9,699,328 (8,388,608, [k][b][l][d]),
//   G @18,087,936 (2M): conv chain / xin_raw / hseg+pseg / res+tmp
// ---------------------------------------------------------------------------
extern "C" void kernel_launch(void* const* d_in, const int* in_sizes, int n_in,
                              void* d_out, int out_size, void* d_ws, size_t ws_size,
                              hipStream_t stream)
{
    const float* x          = (const float*)d_in[0];
    const float* conv1_w    = (const float*)d_in[1];
    const float* conv1_b    = (const float*)d_in[2];
    const float* conv2_w    = (const float*)d_in[3];
    const float* conv2_b    = (const float*)d_in[4];
    const float* cf_w       = (const float*)d_in[5];
    const float* cf_b       = (const float*)d_in[6];
    const float* ln_g       = (const float*)d_in[7];
    const float* ln_b       = (const float*)d_in[8];
    const float* in_proj_w  = (const float*)d_in[9];
    const float* dw_w       = (const float*)d_in[10];
    const float* dw_b       = (const float*)d_in[11];
    const float* x_proj_w   = (const float*)d_in[12];
    const float* dt_proj_w  = (const float*)d_in[13];
    const float* dt_proj_b  = (const float*)d_in[14];
    const float* A_logs     = (const float*)d_in[15];
    const float* Ds         = (const float*)d_in[16];
    const float* out_norm_g = (const float*)d_in[17];
    const float* out_norm_b = (const float*)d_in[18];
    const float* out_proj_w = (const float*)d_in[19];
    const float* skip_scale = (const float*)d_in[20];
    const float* cb_w       = (const float*)d_in[21];
    const float* cb_b       = (const float*)d_in[22];

    float* ws = (float*)d_ws;
    float* x1    = ws;                 // 1,048,576
    float* xin_s = ws + 1048576;       // 2,097,152
    float* zbuf  = ws + 3145728;       // 2,097,152
    float* xin_T = ws + 5242880;       // 2,097,152
    float* xdbl  = ws + 7340032;       // 2,359,296
    float* ybuf  = ws + 9699328;       // 8,388,608
    float* G     = ws + 18087936;      // 2,097,152 scratch
    float* G0 = G;
    float* G1 = G + 1048576;

    conv3x3_k<<<256, 512, 0, stream>>>(x, conv1_w, conv1_b, nullptr, G0);
    inorm_lrelu_k<<<256, 256, 0, stream>>>(G0, G1);
    conv3x3_k<<<256, 512, 0, stream>>>(G1, conv2_w, conv2_b, nullptr, G0);
    conv3x3_k<<<256, 512, 0, stream>>>(G0, cf_w, cf_b, nullptr, x1);
    ln_inproj_k<<<512, 256, 0, stream>>>(x1, ln_g, ln_b, in_proj_w, G /*xin_raw*/, zbuf);
    dwconv_silu_k<<<8192, 256, 0, stream>>>(G /*xin_raw*/, dw_w, dw_b, xin_s);
    transpose_k<<<512, 256, 0, stream>>>(xin_s, xin_T);
    xdbl_k<<<2048, 256, 0, stream>>>(xin_s, xin_T, x_proj_w, xdbl);
    scan_p1_k<<<4096, 256, 0, stream>>>(xdbl, xin_s, xin_T, A_logs, dt_proj_w,
                                        dt_proj_b, G0 /*hseg*/, G1 /*pseg*/);
    scan_combine_k<<<128, 256, 0, stream>>>(G0 /*hseg*/, G1 /*pseg->hstart*/);
    scan_p2_k<<<4096, 256, 0, stream>>>(xdbl, xin_s, xin_T, A_logs, dt_proj_w,
                                        dt_proj_b, G1 /*hstart*/, Ds, ybuf);
    finalize_k<<<512, 256, 0, stream>>>(ybuf, zbuf, x1, out_norm_g, out_norm_b,
                                        out_proj_w, skip_scale, G0 /*res*/);
    conv3x3_k<<<256, 512, 0, stream>>>(G0 /*res*/, cb_w, cb_b, x1, G1 /*tmp*/);
    inorm_lrelu_k<<<256, 256, 0, stream>>>(G1 /*tmp*/, (float*)d_out);
}

// Round 8
// 711.147 us; speedup vs baseline: 3.2687x; 3.2687x over previous
//
#include <hip/hip_runtime.h>
#include <hip/hip_bf16.h>

// All inputs/outputs are float32 (per the reference file's setup_inputs).

// 16-lane butterfly sum via DPP (VALU, no DS-pipe traffic).
static __device__ __forceinline__ float dpp_sum16(float x)
{
    x += __int_as_float(__builtin_amdgcn_update_dpp(
        0, __float_as_int(x), 0xB1, 0xF, 0xF, true));   // quad_perm [1,0,3,2]
    x += __int_as_float(__builtin_amdgcn_update_dpp(
        0, __float_as_int(x), 0x4E, 0xF, 0xF, true));   // quad_perm [2,3,0,1]
    x += __int_as_float(__builtin_amdgcn_update_dpp(
        0, __float_as_int(x), 0x141, 0xF, 0xF, true));  // row_half_mirror
    x += __int_as_float(__builtin_amdgcn_update_dpp(
        0, __float_as_int(x), 0x140, 0xF, 0xF, true));  // row_mirror
    return x;
}

// ---------------------------------------------------------------------------
// 3x3 SAME conv, 64->64 ch, NCHW. Block = one (b,h) row, 512 threads (8
// waves = 2/SIMD). lane = w pixel; wave owns 8 co. Weights loaded as NAMED
// float4s (q0..q8) with fully-static array indexing everywhere -> all values
// SROA-promoted to VGPRs (the R7 scratch-spill bug was a data-dependent
// pointer into stack arrays). __launch_bounds__(512,1) lifts the VGPR cap so
// the compiler can keep next-iteration weight loads in flight.
// ---------------------------------------------------------------------------
__global__ __launch_bounds__(512, 1) void conv3x3_k(const float* __restrict__ in,
    const float* __restrict__ w, const float* __restrict__ bias,
    const float* __restrict__ addsrc, float* __restrict__ out)
{
    const int bh = blockIdx.x;
    const int b = bh >> 6, h = bh & 63;
    const int t = threadIdx.x;
    __shared__ float lin[3 * 4096];  // [r][ci][w]
    for (int e4 = t; e4 < 3072; e4 += 512) {
        const int flat = e4 * 4;
        const int r = flat >> 12, ci = (flat >> 6) & 63, w4 = flat & 63;
        const int hh = h - 1 + r;
        float4 v = make_float4(0.f, 0.f, 0.f, 0.f);
        if (hh >= 0 && hh < 64)
            v = *(const float4*)&in[((b * 64 + ci) * 64 + hh) * 64 + w4];
        *(float4*)&lin[flat] = v;
    }
    __syncthreads();
    const int wv = t >> 6;       // wave id 0..7
    const int lane = t & 63;     // = w pixel
    const int co0 = wv * 8;
    float acc[8];
#pragma unroll
    for (int i = 0; i < 8; ++i) acc[i] = bias[co0 + i];

    for (int ci4 = 0; ci4 < 64; ci4 += 4) {
        float rvv[36];
#pragma unroll
        for (int c = 0; c < 4; ++c) {
#pragma unroll
            for (int r = 0; r < 3; ++r) {
                const float* row = &lin[r * 4096 + (ci4 + c) * 64];
                const float vc = row[lane];
                const float vm = (lane > 0) ? row[lane - 1] : 0.f;
                const float vn = (lane < 63) ? row[lane + 1] : 0.f;
                rvv[c * 9 + r * 3 + 0] = vm;
                rvv[c * 9 + r * 3 + 1] = vc;
                rvv[c * 9 + r * 3 + 2] = vn;
            }
        }
#pragma unroll
        for (int i = 0; i < 8; ++i) {
            const float* wb = w + ((size_t)(co0 + i) * 64 + ci4) * 9;
            const float4 q0 = *(const float4*)(wb + 0);
            const float4 q1 = *(const float4*)(wb + 4);
            const float4 q2 = *(const float4*)(wb + 8);
            const float4 q3 = *(const float4*)(wb + 12);
            const float4 q4 = *(const float4*)(wb + 16);
            const float4 q5 = *(const float4*)(wb + 20);
            const float4 q6 = *(const float4*)(wb + 24);
            const float4 q7 = *(const float4*)(wb + 28);
            const float4 q8 = *(const float4*)(wb + 32);
            float p0 = 0.f, p1 = 0.f, p2 = 0.f, p3 = 0.f;
#define FMA4(m)                                                               \
            p0 = fmaf(rvv[m * 4 + 0], q##m.x, p0);                            \
            p1 = fmaf(rvv[m * 4 + 1], q##m.y, p1);                            \
            p2 = fmaf(rvv[m * 4 + 2], q##m.z, p2);                            \
            p3 = fmaf(rvv[m * 4 + 3], q##m.w, p3);
            FMA4(0) FMA4(1) FMA4(2) FMA4(3) FMA4(4)
            FMA4(5) FMA4(6) FMA4(7) FMA4(8)
#undef FMA4
            acc[i] += (p0 + p1) + (p2 + p3);
        }
    }
#pragma unroll
    for (int i = 0; i < 8; ++i) {
        const size_t o = ((size_t)(b * 64 + co0 + i) * 64 + h) * 64 + lane;
        float v = acc[i];
        if (addsrc) v += addsrc[o];
        out[o] = v;
    }
}

// ---------------------------------------------------------------------------
// InstanceNorm over HxW per (b,c) + LeakyReLU(0.2). Block per (b,c).
// ---------------------------------------------------------------------------
__global__ __launch_bounds__(256) void inorm_lrelu_k(const float* __restrict__ in,
                                                     float* __restrict__ out)
{
    const int bc = blockIdx.x;
    const float* row = in + (size_t)bc * 4096;
    float s1 = 0.f, s2 = 0.f;
    for (int i = threadIdx.x; i < 4096; i += 256) {
        const float v = row[i];
        s1 += v; s2 = fmaf(v, v, s2);
    }
#pragma unroll
    for (int mk = 1; mk < 64; mk <<= 1) {
        s1 += __shfl_xor(s1, mk, 64);
        s2 += __shfl_xor(s2, mk, 64);
    }
    __shared__ float a1[4], a2[4];
    const int wid = threadIdx.x >> 6;
    if ((threadIdx.x & 63) == 0) { a1[wid] = s1; a2[wid] = s2; }
    __syncthreads();
    const float S1 = a1[0] + a1[1] + a1[2] + a1[3];
    const float S2 = a2[0] + a2[1] + a2[2] + a2[3];
    const float mu = S1 * (1.f / 4096.f);
    const float var = S2 * (1.f / 4096.f) - mu * mu;
    const float rstd = rsqrtf(var + 1e-5f);
    float* orow = out + (size_t)bc * 4096;
    for (int i = threadIdx.x; i < 4096; i += 256) {
        float v = (row[i] - mu) * rstd;
        v = (v >= 0.f) ? v : 0.2f * v;
        orow[i] = v;
    }
}

// ---------------------------------------------------------------------------
// LayerNorm over 64 ch (NHWC view of x1) + in_proj (256x64). No LDS.
// ---------------------------------------------------------------------------
__global__ __launch_bounds__(256) void ln_inproj_k(const float* __restrict__ x1,
    const float* __restrict__ g, const float* __restrict__ be,
    const float* __restrict__ w, float* __restrict__ xin_raw, float* __restrict__ z)
{
    const int bx = blockIdx.x;
    const int b = bx >> 7, l0 = (bx & 127) * 32;
    const int t = threadIdx.x;
    const int j = t & 31, co0 = (t >> 5) * 32;
    float xr[64];
    float s1 = 0.f, s2 = 0.f;
#pragma unroll
    for (int c = 0; c < 64; ++c) {
        const float v = x1[(b * 64 + c) * 4096 + l0 + j];
        xr[c] = v; s1 += v; s2 = fmaf(v, v, s2);
    }
    const float mu = s1 * (1.f / 64.f);
    const float var = s2 * (1.f / 64.f) - mu * mu;
    const float rstd = rsqrtf(var + 1e-5f);
#pragma unroll
    for (int c = 0; c < 64; ++c)
        xr[c] = (xr[c] - mu) * rstd * g[c] + be[c];
    for (int i = 0; i < 32; ++i) {
        const int e = co0 + i;
        const float4* wp = (const float4*)(w + e * 64);
        float a = 0.f;
#pragma unroll
        for (int c4 = 0; c4 < 16; ++c4) {
            const float4 wv = wp[c4];
            a = fmaf(xr[c4 * 4 + 0], wv.x, a);
            a = fmaf(xr[c4 * 4 + 1], wv.y, a);
            a = fmaf(xr[c4 * 4 + 2], wv.z, a);
            a = fmaf(xr[c4 * 4 + 3], wv.w, a);
        }
        if (e < 128) xin_raw[(b * 128 + e) * 4096 + l0 + j] = a;
        else z[((size_t)(b * 4096 + l0 + j)) * 128 + (e - 128)] = a;
    }
}

// ---------------------------------------------------------------------------
// Depthwise 3x3 SAME conv + bias + SiLU on (b,128,64,64).
// ---------------------------------------------------------------------------
__global__ __launch_bounds__(256) void dwconv_silu_k(const float* __restrict__ in,
    const float* __restrict__ w, const float* __restrict__ bias, float* __restrict__ out)
{
    const int idx = blockIdx.x * 256 + threadIdx.x;  // (b*128+d)*4096 + l
    const int l = idx & 4095, bd = idx >> 12, d = bd & 127;
    const int hh = l >> 6, ww = l & 63;
    const float* base = in + (size_t)bd * 4096;
    float acc = bias[d];
    const float* wp = w + d * 9;
#pragma unroll
    for (int dy = 0; dy < 3; ++dy) {
        const int y = hh + dy - 1;
        if (y < 0 || y > 63) continue;
#pragma unroll
        for (int dx = 0; dx < 3; ++dx) {
            const int xx = ww + dx - 1;
            if (xx < 0 || xx > 63) continue;
            acc = fmaf(base[y * 64 + xx], wp[dy * 3 + dx], acc);
        }
    }
    out[idx] = acc / (1.f + __expf(-acc));  // silu
}

// ---------------------------------------------------------------------------
// 64x64 spatial transpose per (b,d).
// ---------------------------------------------------------------------------
__global__ __launch_bounds__(256) void transpose_k(const float* __restrict__ in,
                                                   float* __restrict__ out)
{
    const int bd = blockIdx.x;
    __shared__ float tl[64 * 65];
    const float* src = in + (size_t)bd * 4096;
    for (int e = threadIdx.x; e < 4096; e += 256) {
        const int r = e >> 6, c = e & 63;
        tl[r * 65 + c] = src[e];
    }
    __syncthreads();
    float* dst = out + (size_t)bd * 4096;
    for (int e = threadIdx.x; e < 4096; e += 256) {
        const int wi = e >> 6, hi = e & 63;
        dst[e] = tl[hi * 65 + wi];
    }
}

// ---------------------------------------------------------------------------
// x_dbl[b,k,c,m] = sum_d xs[b,k,d,m] * x_proj_w[k,c,d]  (c=36, scan order m).
// LDS tile [j][d] (pad 132) -> ds_read_b128 over d; float4 weight loads.
// ---------------------------------------------------------------------------
__global__ __launch_bounds__(256) void xdbl_k(const float* __restrict__ xin_s,
    const float* __restrict__ xin_T, const float* __restrict__ xpw,
    float* __restrict__ xdbl)
{
    const int bx = blockIdx.x;
    const int bk = bx >> 7, m0 = (bx & 127) * 32;
    const int b = bk >> 2, k = bk & 3;
    __shared__ float tl[32 * 132];   // [j][d], pad 132
    const float* src = (k & 1) ? xin_T : xin_s;
    const bool rev = (k >= 2);
    for (int e = threadIdx.x; e < 4096; e += 256) {
        const int d = e >> 5, j = e & 31;
        const int m = m0 + j;
        const int um = rev ? (4095 - m) : m;
        tl[j * 132 + d] = src[(b * 128 + d) * 4096 + um];
    }
    __syncthreads();
    const int j = threadIdx.x & 31, c0 = threadIdx.x >> 5;
    const float4* xv4 = (const float4*)(tl + j * 132);
    float acc[5] = {0.f, 0.f, 0.f, 0.f, 0.f};
    for (int d4 = 0; d4 < 32; ++d4) {
        const float4 xv = xv4[d4];
#pragma unroll
        for (int q = 0; q < 5; ++q) {
            const int c = c0 + q * 8;
            if (c < 36) {
                const float4 wv = *(const float4*)&xpw[((size_t)(k * 36 + c)) * 128 + d4 * 4];
                acc[q] = fmaf(xv.x, wv.x, acc[q]);
                acc[q] = fmaf(xv.y, wv.y, acc[q]);
                acc[q] = fmaf(xv.z, wv.z, acc[q]);
                acc[q] = fmaf(xv.w, wv.w, acc[q]);
            }
        }
    }
#pragma unroll
    for (int q = 0; q < 5; ++q) {
        const int c = c0 + q * 8;
        if (c < 36) xdbl[((size_t)bk * 36 + c) * 4096 + m0 + j] = acc[q];
    }
}

// ---------------------------------------------------------------------------
// Segmented selective scan, phase 1 (unchanged).
// ---------------------------------------------------------------------------
__global__ __launch_bounds__(256) void scan_p1_k(const float* __restrict__ xdbl,
    const float* __restrict__ xin_s, const float* __restrict__ xin_T,
    const float* __restrict__ A_logs, const float* __restrict__ dtw,
    const float* __restrict__ dtb, float* __restrict__ hseg,
    float* __restrict__ pseg)
{
    const int bx = blockIdx.x;
    const int seg = bx & 31, d8 = (bx >> 5) & 7, bk = bx >> 8;
    const int b = bk >> 2, k = bk & 3;
    const int t = threadIdx.x;
    const int chain = t >> 4, n = t & 15;
    const int d = d8 * 16 + chain;
    const float A = -__expf(A_logs[(k * 128 + d) * 16 + n]);
    __shared__ float sB[16 * 132], sdt[16 * 132], su[16 * 132];
    const float* srcu = (k & 1) ? xin_T : xin_s;
    const bool rev = (k >= 2);
    const int jj = t & 127, half = t >> 7;
    const int m0 = seg * 128;
    {
        const float dts0 = xdbl[((size_t)bk * 36 + 0) * 4096 + m0 + jj];
        const float dts1 = xdbl[((size_t)bk * 36 + 1) * 4096 + m0 + jj];
        const float dts2 = xdbl[((size_t)bk * 36 + 2) * 4096 + m0 + jj];
        const float dts3 = xdbl[((size_t)bk * 36 + 3) * 4096 + m0 + jj];
        const int m = m0 + jj;
        const int um = rev ? (4095 - m) : m;
#pragma unroll
        for (int i = 0; i < 8; ++i) {
            const int nn = half + 2 * i;
            sB[nn * 132 + jj] = xdbl[((size_t)bk * 36 + 4 + nn) * 4096 + m0 + jj];
            const int dd = d8 * 16 + nn;
            const float* wp = dtw + (k * 128 + dd) * 4;
            float s = dtb[k * 128 + dd];
            s = fmaf(dts0, wp[0], s);
            s = fmaf(dts1, wp[1], s);
            s = fmaf(dts2, wp[2], s);
            s = fmaf(dts3, wp[3], s);
            sdt[nn * 132 + jj] = (s > 20.f) ? s : log1pf(__expf(s));
            su[nn * 132 + jj] = srcu[(b * 128 + dd) * 4096 + um];
        }
    }
    __syncthreads();
    const float4* B4  = (const float4*)(sB + n * 132);
    const float4* dt4 = (const float4*)(sdt + chain * 132);
    const float4* u4  = (const float4*)(su + chain * 132);
    float h = 0.f, pr = 1.f;
#pragma unroll 4
    for (int q = 0; q < 32; ++q) {
        const float4 dt = dt4[q], uu = u4[q], BB = B4[q];
        float a;
        a = __expf(dt.x * A); h = fmaf(h, a, dt.x * uu.x * BB.x); pr *= a;
        a = __expf(dt.y * A); h = fmaf(h, a, dt.y * uu.y * BB.y); pr *= a;
        a = __expf(dt.z * A); h = fmaf(h, a, dt.z * uu.z * BB.z); pr *= a;
        a = __expf(dt.w * A); h = fmaf(h, a, dt.w * uu.w * BB.w); pr *= a;
    }
    const size_t idx = (size_t)seg * 32768 + (size_t)(bk * 128 + d) * 16 + n;
    hseg[idx] = h;
    pseg[idx] = pr;
}

// ---------------------------------------------------------------------------
// Combine segment summaries (coalesced). pseg is overwritten with h_start.
// ---------------------------------------------------------------------------
__global__ __launch_bounds__(256) void scan_combine_k(const float* __restrict__ hseg,
                                                      float* __restrict__ pseg)
{
    const int i = blockIdx.x * 256 + threadIdx.x;  // 0..32767
    float h = 0.f;
#pragma unroll 4
    for (int s = 0; s < 32; ++s) {
        const size_t idx = (size_t)s * 32768 + i;
        const float p = pseg[idx];
        const float he = hseg[idx];
        pseg[idx] = h;
        h = fmaf(h, p, he);
    }
}

// ---------------------------------------------------------------------------
// Segmented scan, phase 2: recurrence seeded with h_start; y via DPP butterfly
// into LDS tile, then stored into ybuf[k][b][l_out][d] at the OUTPUT position
// (direction map applied at store). k==0 blocks fold in Dsum*u. No atomics.
// ---------------------------------------------------------------------------
__global__ __launch_bounds__(256) void scan_p2_k(const float* __restrict__ xdbl,
    const float* __restrict__ xin_s, const float* __restrict__ xin_T,
    const float* __restrict__ A_logs, const float* __restrict__ dtw,
    const float* __restrict__ dtb, const float* __restrict__ hstart,
    const float* __restrict__ Dsp, float* __restrict__ ybuf)
{
    const int bx = blockIdx.x;
    const int seg = bx & 31, d8 = (bx >> 5) & 7, bk = bx >> 8;
    const int b = bk >> 2, k = bk & 3;
    const int t = threadIdx.x;
    const int chain = t >> 4, n = t & 15;
    const int d = d8 * 16 + chain;
    const float A = -__expf(A_logs[(k * 128 + d) * 16 + n]);
    __shared__ float sB[16 * 132], sC[16 * 132], sdt[16 * 132], su[16 * 132];
    __shared__ float sy[128 * 16];  // [j][dd]
    const float* srcu = (k & 1) ? xin_T : xin_s;
    const bool rev = (k >= 2);
    const int jj = t & 127, half = t >> 7;
    const int m0 = seg * 128;
    {
        const float dts0 = xdbl[((size_t)bk * 36 + 0) * 4096 + m0 + jj];
        const float dts1 = xdbl[((size_t)bk * 36 + 1) * 4096 + m0 + jj];
        const float dts2 = xdbl[((size_t)bk * 36 + 2) * 4096 + m0 + jj];
        const float dts3 = xdbl[((size_t)bk * 36 + 3) * 4096 + m0 + jj];
        const int m = m0 + jj;
        const int um = rev ? (4095 - m) : m;
#pragma unroll
        for (int i = 0; i < 8; ++i) {
            const int nn = half + 2 * i;
            sB[nn * 132 + jj] = xdbl[((size_t)bk * 36 + 4 + nn) * 4096 + m0 + jj];
            sC[nn * 132 + jj] = xdbl[((size_t)bk * 36 + 20 + nn) * 4096 + m0 + jj];
            const int dd = d8 * 16 + nn;
            const float* wp = dtw + (k * 128 + dd) * 4;
            float s = dtb[k * 128 + dd];
            s = fmaf(dts0, wp[0], s);
            s = fmaf(dts1, wp[1], s);
            s = fmaf(dts2, wp[2], s);
            s = fmaf(dts3, wp[3], s);
            sdt[nn * 132 + jj] = (s > 20.f) ? s : log1pf(__expf(s));
            su[nn * 132 + jj] = srcu[(b * 128 + dd) * 4096 + um];
        }
    }
    __syncthreads();
    const float4* B4  = (const float4*)(sB + n * 132);
    const float4* C4  = (const float4*)(sC + n * 132);
    const float4* dt4 = (const float4*)(sdt + chain * 132);
    const float4* u4  = (const float4*)(su + chain * 132);
    float h = hstart[(size_t)seg * 32768 + (size_t)(bk * 128 + d) * 16 + n];
#pragma unroll 4
    for (int q = 0; q < 32; ++q) {
        const float4 dt = dt4[q], uu = u4[q], BB = B4[q], CC = C4[q];
        float a, p;
#define SCAN_STEP(E, IDX)                                                     \
        a = __expf(dt.E * A);                                                 \
        h = fmaf(h, a, dt.E * uu.E * BB.E);                                   \
        p = dpp_sum16(h * CC.E);                                              \
        if (n == 0) sy[(q * 4 + IDX) * 16 + chain] = p;
        SCAN_STEP(x, 0)
        SCAN_STEP(y, 1)
        SCAN_STEP(z, 2)
        SCAN_STEP(w, 3)
#undef SCAN_STEP
    }
    __syncthreads();
    // store at OUTPUT l (direction map). Each thread has fixed local d.
    const int ddl = t & 15;
    const int dg = d8 * 16 + ddl;
    const float Dsum = (k == 0)
        ? (Dsp[dg] + Dsp[128 + dg] + Dsp[256 + dg] + Dsp[384 + dg]) : 0.f;
    float* yk = ybuf + (size_t)(k * 4 + b) * 4096 * 128;
#pragma unroll
    for (int p2 = 0; p2 < 8; ++p2) {
        const int e = p2 * 256 + t;
        const int j = e >> 4;               // 0..127
        const int m = m0 + j;
        int l;
        if (k == 0) l = m;
        else if (k == 1) l = ((m & 63) << 6) | (m >> 6);
        else if (k == 2) l = 4095 - m;
        else { const int mf = 4095 - m; l = ((mf & 63) << 6) | (mf >> 6); }
        float v = sy[j * 16 + ddl];
        if (k == 0) v = fmaf(Dsum, su[ddl * 132 + j], v);
        yk[(size_t)l * 128 + dg] = v;
    }
}

// ---------------------------------------------------------------------------
// Finalize: v[d] = sum_k ybuf[k][b][l][d] (Dsum*u already folded in k=0);
// LN over 128; * silu(z); out_proj GEMV (8 co per thread-group);
// LDS-transposed coalesced store of res + skip*x1. Block = 32 l, 256 thr.
// ---------------------------------------------------------------------------
__global__ __launch_bounds__(256) void finalize_k(const float* __restrict__ ybuf,
    const float* __restrict__ z, const float* __restrict__ x1,
    const float* __restrict__ ong, const float* __restrict__ onb,
    const float* __restrict__ opw, const float* __restrict__ skipp,
    float* __restrict__ res)
{
    const int bx = blockIdx.x;               // b*128 + tile
    const int b = bx >> 7, l0 = (bx & 127) * 32;
    const int t = threadIdx.x;
    const int j = t & 31, g = t >> 5;        // g 0..7
    const int l = l0 + j;
    const float4* y0p = (const float4*)(ybuf + ((size_t)(0 + b) * 4096 + l) * 128);
    const float4* y1p = (const float4*)(ybuf + ((size_t)(4 + b) * 4096 + l) * 128);
    const float4* y2p = (const float4*)(ybuf + ((size_t)(8 + b) * 4096 + l) * 128);
    const float4* y3p = (const float4*)(ybuf + ((size_t)(12 + b) * 4096 + l) * 128);
    float4 v4[32];
    float s1 = 0.f, s2 = 0.f;
#pragma unroll
    for (int d4 = 0; d4 < 32; ++d4) {
        const float4 a0 = y0p[d4], a1 = y1p[d4], a2 = y2p[d4], a3 = y3p[d4];
        float4 a;
        a.x = (a0.x + a1.x) + (a2.x + a3.x);
        a.y = (a0.y + a1.y) + (a2.y + a3.y);
        a.z = (a0.z + a1.z) + (a2.z + a3.z);
        a.w = (a0.w + a1.w) + (a2.w + a3.w);
        v4[d4] = a;
        s1 += (a.x + a.y) + (a.z + a.w);
        s2 = fmaf(a.x, a.x, s2); s2 = fmaf(a.y, a.y, s2);
        s2 = fmaf(a.z, a.z, s2); s2 = fmaf(a.w, a.w, s2);
    }
    const float mu = s1 * (1.f / 128.f);
    const float var = s2 * (1.f / 128.f) - mu * mu;
    const float rstd = rsqrtf(var + 1e-5f);
    const float4* zp = (const float4*)(z + ((size_t)(b * 4096 + l)) * 128);
    const float4* gp = (const float4*)ong;
    const float4* bp = (const float4*)onb;
#pragma unroll
    for (int d4 = 0; d4 < 32; ++d4) {
        const float4 gg = gp[d4], bb = bp[d4], zz = zp[d4];
        float4 a = v4[d4];
#define GATE(E)                                                               \
        {                                                                     \
            const float yln = (a.E - mu) * rstd * gg.E + bb.E;                \
            a.E = yln * (zz.E / (1.f + __expf(-zz.E)));                       \
        }
        GATE(x) GATE(y) GATE(z) GATE(w)
#undef GATE
        v4[d4] = a;
    }
    float acc[8] = {0.f, 0.f, 0.f, 0.f, 0.f, 0.f, 0.f, 0.f};
    for (int d4 = 0; d4 < 32; ++d4) {
        const float4 a = v4[d4];
#pragma unroll
        for (int q = 0; q < 8; ++q) {
            const float4 wv = *(const float4*)&opw[(size_t)(g * 8 + q) * 128 + d4 * 4];
            acc[q] = fmaf(a.x, wv.x, acc[q]);
            acc[q] = fmaf(a.y, wv.y, acc[q]);
            acc[q] = fmaf(a.z, wv.z, acc[q]);
            acc[q] = fmaf(a.w, wv.w, acc[q]);
        }
    }
    __shared__ float sres[64 * 33];
#pragma unroll
    for (int q = 0; q < 8; ++q) sres[(g * 8 + q) * 33 + j] = acc[q];
    __syncthreads();
    const float sk = skipp[0];
    for (int e = t; e < 2048; e += 256) {
        const int co = e >> 5, jj = e & 31;
        const size_t o = ((size_t)(b * 64 + co)) * 4096 + l0 + jj;
        res[o] = sres[co * 33 + jj] + sk * x1[o];
    }
}

// ---------------------------------------------------------------------------
// Workspace layout (floats), total 20,185,088 floats = 77.0 MB:
//   x1 @0 (1M), xin_s @1M (2M), zbuf @3M (2M), xin_T @5M (2M),
//   xdbl @7,340,032 (2,359,296), ybuf @9,699,328 (8,388,608, [k][b][l][d]),
//   G @18,087,936 (2M): conv chain / xin_raw / hseg+pseg / res+tmp
// ---------------------------------------------------------------------------
extern "C" void kernel_launch(void* const* d_in, const int* in_sizes, int n_in,
                              void* d_out, int out_size, void* d_ws, size_t ws_size,
                              hipStream_t stream)
{
    const float* x          = (const float*)d_in[0];
    const float* conv1_w    = (const float*)d_in[1];
    const float* conv1_b    = (const float*)d_in[2];
    const float* conv2_w    = (const float*)d_in[3];
    const float* conv2_b    = (const float*)d_in[4];
    const float* cf_w       = (const float*)d_in[5];
    const float* cf_b       = (const float*)d_in[6];
    const float* ln_g       = (const float*)d_in[7];
    const float* ln_b       = (const float*)d_in[8];
    const float* in_proj_w  = (const float*)d_in[9];
    const float* dw_w       = (const float*)d_in[10];
    const float* dw_b       = (const float*)d_in[11];
    const float* x_proj_w   = (const float*)d_in[12];
    const float* dt_proj_w  = (const float*)d_in[13];
    const float* dt_proj_b  = (const float*)d_in[14];
    const float* A_logs     = (const float*)d_in[15];
    const float* Ds         = (const float*)d_in[16];
    const float* out_norm_g = (const float*)d_in[17];
    const float* out_norm_b = (const float*)d_in[18];
    const float* out_proj_w = (const float*)d_in[19];
    const float* skip_scale = (const float*)d_in[20];
    const float* cb_w       = (const float*)d_in[21];
    const float* cb_b       = (const float*)d_in[22];

    float* ws = (float*)d_ws;
    float* x1    = ws;                 // 1,048,576
    float* xin_s = ws + 1048576;       // 2,097,152
    float* zbuf  = ws + 3145728;       // 2,097,152
    float* xin_T = ws + 5242880;       // 2,097,152
    float* xdbl  = ws + 7340032;       // 2,359,296
    float* ybuf  = ws + 9699328;       // 8,388,608
    float* G     = ws + 18087936;      // 2,097,152 scratch
    float* G0 = G;
    float* G1 = G + 1048576;

    conv3x3_k<<<256, 512, 0, stream>>>(x, conv1_w, conv1_b, nullptr, G0);
    inorm_lrelu_k<<<256, 256, 0, stream>>>(G0, G1);
    conv3x3_k<<<256, 512, 0, stream>>>(G1, conv2_w, conv2_b, nullptr, G0);
    conv3x3_k<<<256, 512, 0, stream>>>(G0, cf_w, cf_b, nullptr, x1);
    ln_inproj_k<<<512, 256, 0, stream>>>(x1, ln_g, ln_b, in_proj_w, G /*xin_raw*/, zbuf);
    dwconv_silu_k<<<8192, 256, 0, stream>>>(G /*xin_raw*/, dw_w, dw_b, xin_s);
    transpose_k<<<512, 256, 0, stream>>>(xin_s, xin_T);
    xdbl_k<<<2048, 256, 0, stream>>>(xin_s, xin_T, x_proj_w, xdbl);
    scan_p1_k<<<4096, 256, 0, stream>>>(xdbl, xin_s, xin_T, A_logs, dt_proj_w,
                                        dt_proj_b, G0 /*hseg*/, G1 /*pseg*/);
    scan_combine_k<<<128, 256, 0, stream>>>(G0 /*hseg*/, G1 /*pseg->hstart*/);
    scan_p2_k<<<4096, 256, 0, stream>>>(xdbl, xin_s, xin_T, A_logs, dt_proj_w,
                                        dt_proj_b, G1 /*hstart*/, Ds, ybuf);
    finalize_k<<<512, 256, 0, stream>>>(ybuf, zbuf, x1, out_norm_g, out_norm_b,
                                        out_proj_w, skip_scale, G0 /*res*/);
    conv3x3_k<<<256, 512, 0, stream>>>(G0 /*res*/, cb_w, cb_b, x1, G1 /*tmp*/);
    inorm_lrelu_k<<<256, 256, 0, stream>>>(G1 /*tmp*/, (float*)d_out);
}

// Round 9
// 689.802 us; speedup vs baseline: 3.3698x; 1.0309x over previous
//
#include <hip/hip_runtime.h>
#include <hip/hip_bf16.h>

// All inputs/outputs are float32 (per the reference file's setup_inputs).

// 16-lane butterfly sum via DPP (VALU, no DS-pipe traffic).
static __device__ __forceinline__ float dpp_sum16(float x)
{
    x += __int_as_float(__builtin_amdgcn_update_dpp(
        0, __float_as_int(x), 0xB1, 0xF, 0xF, true));   // quad_perm [1,0,3,2]
    x += __int_as_float(__builtin_amdgcn_update_dpp(
        0, __float_as_int(x), 0x4E, 0xF, 0xF, true));   // quad_perm [2,3,0,1]
    x += __int_as_float(__builtin_amdgcn_update_dpp(
        0, __float_as_int(x), 0x141, 0xF, 0xF, true));  // row_half_mirror
    x += __int_as_float(__builtin_amdgcn_update_dpp(
        0, __float_as_int(x), 0x140, 0xF, 0xF, true));  // row_mirror
    return x;
}

// ---------------------------------------------------------------------------
// 3x3 SAME conv, 64->64 ch, NCHW. Block = one (b,h) row, 512 threads.
// lane = w pixel; wave owns 8 co. Explicit 2-deep software pipeline over the
// co loop with TWO named float4 buffer sets (qa/qb): group i+1's 9 weight
// loads issue before group i's FMAs. (R8 reused one buffer set -> compiler
// had to serialize load->FMA->load, ~215cy/group = raw L2 latency.)
// ---------------------------------------------------------------------------
__global__ __launch_bounds__(512, 1) void conv3x3_k(const float* __restrict__ in,
    const float* __restrict__ w, const float* __restrict__ bias,
    const float* __restrict__ addsrc, float* __restrict__ out)
{
    const int bh = blockIdx.x;
    const int b = bh >> 6, h = bh & 63;
    const int t = threadIdx.x;
    __shared__ float lin[3 * 4096];  // [r][ci][w]
    for (int e4 = t; e4 < 3072; e4 += 512) {
        const int flat = e4 * 4;
        const int r = flat >> 12, ci = (flat >> 6) & 63, w4 = flat & 63;
        const int hh = h - 1 + r;
        float4 v = make_float4(0.f, 0.f, 0.f, 0.f);
        if (hh >= 0 && hh < 64)
            v = *(const float4*)&in[((b * 64 + ci) * 64 + hh) * 64 + w4];
        *(float4*)&lin[flat] = v;
    }
    __syncthreads();
    const int wv = t >> 6;       // wave id 0..7
    const int lane = t & 63;     // = w pixel
    const int co0 = wv * 8;
    float acc[8];
#pragma unroll
    for (int i = 0; i < 8; ++i) acc[i] = bias[co0 + i];

    float4 qa0, qa1, qa2, qa3, qa4, qa5, qa6, qa7, qa8;
    float4 qb0, qb1, qb2, qb3, qb4, qb5, qb6, qb7, qb8;

#define LOADW(B, co, ci)                                                      \
    {                                                                         \
        const float* _p = w + ((size_t)(co) * 64 + (ci)) * 9;                 \
        B##0 = *(const float4*)(_p + 0);                                      \
        B##1 = *(const float4*)(_p + 4);                                      \
        B##2 = *(const float4*)(_p + 8);                                      \
        B##3 = *(const float4*)(_p + 12);                                     \
        B##4 = *(const float4*)(_p + 16);                                     \
        B##5 = *(const float4*)(_p + 20);                                     \
        B##6 = *(const float4*)(_p + 24);                                     \
        B##7 = *(const float4*)(_p + 28);                                     \
        B##8 = *(const float4*)(_p + 32);                                     \
    }
#define FQ(B, m)                                                              \
    p0 = fmaf(rvv[m * 4 + 0], B##m.x, p0);                                    \
    p1 = fmaf(rvv[m * 4 + 1], B##m.y, p1);                                    \
    p2 = fmaf(rvv[m * 4 + 2], B##m.z, p2);                                    \
    p3 = fmaf(rvv[m * 4 + 3], B##m.w, p3);
#define DOFMA(i, B)                                                           \
    {                                                                         \
        float p0 = 0.f, p1 = 0.f, p2 = 0.f, p3 = 0.f;                         \
        FQ(B, 0) FQ(B, 1) FQ(B, 2) FQ(B, 3) FQ(B, 4)                          \
        FQ(B, 5) FQ(B, 6) FQ(B, 7) FQ(B, 8)                                   \
        acc[i] += (p0 + p1) + (p2 + p3);                                      \
    }

    LOADW(qa, co0, 0);
    for (int ci4 = 0; ci4 < 64; ci4 += 4) {
        float rvv[36];
#pragma unroll
        for (int c = 0; c < 4; ++c) {
#pragma unroll
            for (int r = 0; r < 3; ++r) {
                const float* row = &lin[r * 4096 + (ci4 + c) * 64];
                const float vc = row[lane];
                const float vm = (lane > 0) ? row[lane - 1] : 0.f;
                const float vn = (lane < 63) ? row[lane + 1] : 0.f;
                rvv[c * 9 + r * 3 + 0] = vm;
                rvv[c * 9 + r * 3 + 1] = vc;
                rvv[c * 9 + r * 3 + 2] = vn;
            }
        }
        const int nci = (ci4 + 4 < 64) ? ci4 + 4 : 0;
        LOADW(qb, co0 + 1, ci4) DOFMA(0, qa)
        LOADW(qa, co0 + 2, ci4) DOFMA(1, qb)
        LOADW(qb, co0 + 3, ci4) DOFMA(2, qa)
        LOADW(qa, co0 + 4, ci4) DOFMA(3, qb)
        LOADW(qb, co0 + 5, ci4) DOFMA(4, qa)
        LOADW(qa, co0 + 6, ci4) DOFMA(5, qb)
        LOADW(qb, co0 + 7, ci4) DOFMA(6, qa)
        LOADW(qa, co0 + 0, nci) DOFMA(7, qb)
    }
#undef LOADW
#undef FQ
#undef DOFMA
#pragma unroll
    for (int i = 0; i < 8; ++i) {
        const size_t o = ((size_t)(b * 64 + co0 + i) * 64 + h) * 64 + lane;
        float v = acc[i];
        if (addsrc) v += addsrc[o];
        out[o] = v;
    }
}

// ---------------------------------------------------------------------------
// InstanceNorm over HxW per (b,c) + LeakyReLU(0.2). Block per (b,c).
// ---------------------------------------------------------------------------
__global__ __launch_bounds__(256) void inorm_lrelu_k(const float* __restrict__ in,
                                                     float* __restrict__ out)
{
    const int bc = blockIdx.x;
    const float* row = in + (size_t)bc * 4096;
    float s1 = 0.f, s2 = 0.f;
    for (int i = threadIdx.x; i < 4096; i += 256) {
        const float v = row[i];
        s1 += v; s2 = fmaf(v, v, s2);
    }
#pragma unroll
    for (int mk = 1; mk < 64; mk <<= 1) {
        s1 += __shfl_xor(s1, mk, 64);
        s2 += __shfl_xor(s2, mk, 64);
    }
    __shared__ float a1[4], a2[4];
    const int wid = threadIdx.x >> 6;
    if ((threadIdx.x & 63) == 0) { a1[wid] = s1; a2[wid] = s2; }
    __syncthreads();
    const float S1 = a1[0] + a1[1] + a1[2] + a1[3];
    const float S2 = a2[0] + a2[1] + a2[2] + a2[3];
    const float mu = S1 * (1.f / 4096.f);
    const float var = S2 * (1.f / 4096.f) - mu * mu;
    const float rstd = rsqrtf(var + 1e-5f);
    float* orow = out + (size_t)bc * 4096;
    for (int i = threadIdx.x; i < 4096; i += 256) {
        float v = (row[i] - mu) * rstd;
        v = (v >= 0.f) ? v : 0.2f * v;
        orow[i] = v;
    }
}

// ---------------------------------------------------------------------------
// LayerNorm over 64 ch (NHWC view of x1) + in_proj (256x64). No LDS.
// ---------------------------------------------------------------------------
__global__ __launch_bounds__(256) void ln_inproj_k(const float* __restrict__ x1,
    const float* __restrict__ g, const float* __restrict__ be,
    const float* __restrict__ w, float* __restrict__ xin_raw, float* __restrict__ z)
{
    const int bx = blockIdx.x;
    const int b = bx >> 7, l0 = (bx & 127) * 32;
    const int t = threadIdx.x;
    const int j = t & 31, co0 = (t >> 5) * 32;
    float xr[64];
    float s1 = 0.f, s2 = 0.f;
#pragma unroll
    for (int c = 0; c < 64; ++c) {
        const float v = x1[(b * 64 + c) * 4096 + l0 + j];
        xr[c] = v; s1 += v; s2 = fmaf(v, v, s2);
    }
    const float mu = s1 * (1.f / 64.f);
    const float var = s2 * (1.f / 64.f) - mu * mu;
    const float rstd = rsqrtf(var + 1e-5f);
#pragma unroll
    for (int c = 0; c < 64; ++c)
        xr[c] = (xr[c] - mu) * rstd * g[c] + be[c];
    for (int i = 0; i < 32; ++i) {
        const int e = co0 + i;
        const float4* wp = (const float4*)(w + e * 64);
        float a = 0.f;
#pragma unroll
        for (int c4 = 0; c4 < 16; ++c4) {
            const float4 wv = wp[c4];
            a = fmaf(xr[c4 * 4 + 0], wv.x, a);
            a = fmaf(xr[c4 * 4 + 1], wv.y, a);
            a = fmaf(xr[c4 * 4 + 2], wv.z, a);
            a = fmaf(xr[c4 * 4 + 3], wv.w, a);
        }
        if (e < 128) xin_raw[(b * 128 + e) * 4096 + l0 + j] = a;
        else z[((size_t)(b * 4096 + l0 + j)) * 128 + (e - 128)] = a;
    }
}

// ---------------------------------------------------------------------------
// Depthwise 3x3 SAME conv + bias + SiLU on (b,128,64,64).
// ---------------------------------------------------------------------------
__global__ __launch_bounds__(256) void dwconv_silu_k(const float* __restrict__ in,
    const float* __restrict__ w, const float* __restrict__ bias, float* __restrict__ out)
{
    const int idx = blockIdx.x * 256 + threadIdx.x;  // (b*128+d)*4096 + l
    const int l = idx & 4095, bd = idx >> 12, d = bd & 127;
    const int hh = l >> 6, ww = l & 63;
    const float* base = in + (size_t)bd * 4096;
    float acc = bias[d];
    const float* wp = w + d * 9;
#pragma unroll
    for (int dy = 0; dy < 3; ++dy) {
        const int y = hh + dy - 1;
        if (y < 0 || y > 63) continue;
#pragma unroll
        for (int dx = 0; dx < 3; ++dx) {
            const int xx = ww + dx - 1;
            if (xx < 0 || xx > 63) continue;
            acc = fmaf(base[y * 64 + xx], wp[dy * 3 + dx], acc);
        }
    }
    out[idx] = acc / (1.f + __expf(-acc));  // silu
}

// ---------------------------------------------------------------------------
// 64x64 spatial transpose per (b,d).
// ---------------------------------------------------------------------------
__global__ __launch_bounds__(256) void transpose_k(const float* __restrict__ in,
                                                   float* __restrict__ out)
{
    const int bd = blockIdx.x;
    __shared__ float tl[64 * 65];
    const float* src = in + (size_t)bd * 4096;
    for (int e = threadIdx.x; e < 4096; e += 256) {
        const int r = e >> 6, c = e & 63;
        tl[r * 65 + c] = src[e];
    }
    __syncthreads();
    float* dst = out + (size_t)bd * 4096;
    for (int e = threadIdx.x; e < 4096; e += 256) {
        const int wi = e >> 6, hi = e & 63;
        dst[e] = tl[hi * 65 + wi];
    }
}

// ---------------------------------------------------------------------------
// x_dbl[b,k,c,m] = sum_d xs[b,k,d,m] * x_proj_w[k,c,d]  (c=36, scan order m).
// ---------------------------------------------------------------------------
__global__ __launch_bounds__(256) void xdbl_k(const float* __restrict__ xin_s,
    const float* __restrict__ xin_T, const float* __restrict__ xpw,
    float* __restrict__ xdbl)
{
    const int bx = blockIdx.x;
    const int bk = bx >> 7, m0 = (bx & 127) * 32;
    const int b = bk >> 2, k = bk & 3;
    __shared__ float tl[32 * 132];   // [j][d], pad 132
    const float* src = (k & 1) ? xin_T : xin_s;
    const bool rev = (k >= 2);
    for (int e = threadIdx.x; e < 4096; e += 256) {
        const int d = e >> 5, j = e & 31;
        const int m = m0 + j;
        const int um = rev ? (4095 - m) : m;
        tl[j * 132 + d] = src[(b * 128 + d) * 4096 + um];
    }
    __syncthreads();
    const int j = threadIdx.x & 31, c0 = threadIdx.x >> 5;
    const float4* xv4 = (const float4*)(tl + j * 132);
    float acc[5] = {0.f, 0.f, 0.f, 0.f, 0.f};
    for (int d4 = 0; d4 < 32; ++d4) {
        const float4 xv = xv4[d4];
#pragma unroll
        for (int q = 0; q < 5; ++q) {
            const int c = c0 + q * 8;
            if (c < 36) {
                const float4 wv = *(const float4*)&xpw[((size_t)(k * 36 + c)) * 128 + d4 * 4];
                acc[q] = fmaf(xv.x, wv.x, acc[q]);
                acc[q] = fmaf(xv.y, wv.y, acc[q]);
                acc[q] = fmaf(xv.z, wv.z, acc[q]);
                acc[q] = fmaf(xv.w, wv.w, acc[q]);
            }
        }
    }
#pragma unroll
    for (int q = 0; q < 5; ++q) {
        const int c = c0 + q * 8;
        if (c < 36) xdbl[((size_t)bk * 36 + c) * 4096 + m0 + j] = acc[q];
    }
}

// ---------------------------------------------------------------------------
// Segmented scan, phase 1. Staging split into two 64-step chunks: LDS =
// 3 x [16][68] = 13KB -> 8 blocks/CU (was 25KB/6).
// ---------------------------------------------------------------------------
__global__ __launch_bounds__(256) void scan_p1_k(const float* __restrict__ xdbl,
    const float* __restrict__ xin_s, const float* __restrict__ xin_T,
    const float* __restrict__ A_logs, const float* __restrict__ dtw,
    const float* __restrict__ dtb, float* __restrict__ hseg,
    float* __restrict__ pseg)
{
    const int bx = blockIdx.x;
    const int seg = bx & 31, d8 = (bx >> 5) & 7, bk = bx >> 8;
    const int b = bk >> 2, k = bk & 3;
    const int t = threadIdx.x;
    const int chain = t >> 4, n = t & 15;
    const int d = d8 * 16 + chain;
    const float A = -__expf(A_logs[(k * 128 + d) * 16 + n]);
    __shared__ float sB[16 * 68], sdt[16 * 68], su[16 * 68];
    const float* srcu = (k & 1) ? xin_T : xin_s;
    const bool rev = (k >= 2);
    const int col = t & 63, r0 = t >> 6;
    const int m0 = seg * 128;
    float h = 0.f, pr = 1.f;
    for (int c = 0; c < 2; ++c) {
        const int cb = m0 + c * 64;
        __syncthreads();
        const float dts0 = xdbl[((size_t)bk * 36 + 0) * 4096 + cb + col];
        const float dts1 = xdbl[((size_t)bk * 36 + 1) * 4096 + cb + col];
        const float dts2 = xdbl[((size_t)bk * 36 + 2) * 4096 + cb + col];
        const float dts3 = xdbl[((size_t)bk * 36 + 3) * 4096 + cb + col];
        const int m = cb + col;
        const int um = rev ? (4095 - m) : m;
#pragma unroll
        for (int i = 0; i < 4; ++i) {
            const int nn = r0 + 4 * i;
            sB[nn * 68 + col] = xdbl[((size_t)bk * 36 + 4 + nn) * 4096 + cb + col];
            const int dd = d8 * 16 + nn;
            const float* wp = dtw + (k * 128 + dd) * 4;
            float s = dtb[k * 128 + dd];
            s = fmaf(dts0, wp[0], s);
            s = fmaf(dts1, wp[1], s);
            s = fmaf(dts2, wp[2], s);
            s = fmaf(dts3, wp[3], s);
            sdt[nn * 68 + col] = (s > 20.f) ? s : log1pf(__expf(s));
            su[nn * 68 + col] = srcu[(b * 128 + dd) * 4096 + um];
        }
        __syncthreads();
        const float4* B4  = (const float4*)(sB + n * 68);
        const float4* dt4 = (const float4*)(sdt + chain * 68);
        const float4* u4  = (const float4*)(su + chain * 68);
#pragma unroll 4
        for (int q = 0; q < 16; ++q) {
            const float4 dt = dt4[q], uu = u4[q], BB = B4[q];
            float a;
            a = __expf(dt.x * A); h = fmaf(h, a, dt.x * uu.x * BB.x); pr *= a;
            a = __expf(dt.y * A); h = fmaf(h, a, dt.y * uu.y * BB.y); pr *= a;
            a = __expf(dt.z * A); h = fmaf(h, a, dt.z * uu.z * BB.z); pr *= a;
            a = __expf(dt.w * A); h = fmaf(h, a, dt.w * uu.w * BB.w); pr *= a;
        }
    }
    const size_t idx = (size_t)seg * 32768 + (size_t)(bk * 128 + d) * 16 + n;
    hseg[idx] = h;
    pseg[idx] = pr;
}

// ---------------------------------------------------------------------------
// Combine segment summaries (coalesced). pseg is overwritten with h_start.
// ---------------------------------------------------------------------------
__global__ __launch_bounds__(256) void scan_combine_k(const float* __restrict__ hseg,
                                                      float* __restrict__ pseg)
{
    const int i = blockIdx.x * 256 + threadIdx.x;  // 0..32767
    float h = 0.f;
#pragma unroll 4
    for (int s = 0; s < 32; ++s) {
        const size_t idx = (size_t)s * 32768 + i;
        const float p = pseg[idx];
        const float he = hseg[idx];
        pseg[idx] = h;
        h = fmaf(h, p, he);
    }
}

// ---------------------------------------------------------------------------
// Segmented scan, phase 2. Two 64-step staging chunks: LDS = 4x[16][68] +
// sy[128][16] = 25.6KB -> 6 blocks/CU (was 42KB/3). Dsum*u folded in-loop
// (k==0) so su isn't needed at store time. No atomics.
// ---------------------------------------------------------------------------
__global__ __launch_bounds__(256) void scan_p2_k(const float* __restrict__ xdbl,
    const float* __restrict__ xin_s, const float* __restrict__ xin_T,
    const float* __restrict__ A_logs, const float* __restrict__ dtw,
    const float* __restrict__ dtb, const float* __restrict__ hstart,
    const float* __restrict__ Dsp, float* __restrict__ ybuf)
{
    const int bx = blockIdx.x;
    const int seg = bx & 31, d8 = (bx >> 5) & 7, bk = bx >> 8;
    const int b = bk >> 2, k = bk & 3;
    const int t = threadIdx.x;
    const int chain = t >> 4, n = t & 15;
    const int d = d8 * 16 + chain;
    const float A = -__expf(A_logs[(k * 128 + d) * 16 + n]);
    __shared__ float sB[16 * 68], sC[16 * 68], sdt[16 * 68], su[16 * 68];
    __shared__ float sy[128 * 16];  // [j][dd]
    const float* srcu = (k & 1) ? xin_T : xin_s;
    const bool rev = (k >= 2);
    const int col = t & 63, r0 = t >> 6;
    const int m0 = seg * 128;
    const float Dk0 = (k == 0)
        ? (Dsp[d] + Dsp[128 + d] + Dsp[256 + d] + Dsp[384 + d]) : 0.f;
    float h = hstart[(size_t)seg * 32768 + (size_t)(bk * 128 + d) * 16 + n];
    for (int c = 0; c < 2; ++c) {
        const int cb = m0 + c * 64;
        __syncthreads();
        const float dts0 = xdbl[((size_t)bk * 36 + 0) * 4096 + cb + col];
        const float dts1 = xdbl[((size_t)bk * 36 + 1) * 4096 + cb + col];
        const float dts2 = xdbl[((size_t)bk * 36 + 2) * 4096 + cb + col];
        const float dts3 = xdbl[((size_t)bk * 36 + 3) * 4096 + cb + col];
        const int m = cb + col;
        const int um = rev ? (4095 - m) : m;
#pragma unroll
        for (int i = 0; i < 4; ++i) {
            const int nn = r0 + 4 * i;
            sB[nn * 68 + col] = xdbl[((size_t)bk * 36 + 4 + nn) * 4096 + cb + col];
            sC[nn * 68 + col] = xdbl[((size_t)bk * 36 + 20 + nn) * 4096 + cb + col];
            const int dd = d8 * 16 + nn;
            const float* wp = dtw + (k * 128 + dd) * 4;
            float s = dtb[k * 128 + dd];
            s = fmaf(dts0, wp[0], s);
            s = fmaf(dts1, wp[1], s);
            s = fmaf(dts2, wp[2], s);
            s = fmaf(dts3, wp[3], s);
            sdt[nn * 68 + col] = (s > 20.f) ? s : log1pf(__expf(s));
            su[nn * 68 + col] = srcu[(b * 128 + dd) * 4096 + um];
        }
        __syncthreads();
        const float4* B4  = (const float4*)(sB + n * 68);
        const float4* C4  = (const float4*)(sC + n * 68);
        const float4* dt4 = (const float4*)(sdt + chain * 68);
        const float4* u4  = (const float4*)(su + chain * 68);
#pragma unroll 4
        for (int q = 0; q < 16; ++q) {
            const float4 dt = dt4[q], uu = u4[q], BB = B4[q], CC = C4[q];
            float a, p;
#define SCAN_STEP(E, IDX)                                                     \
            a = __expf(dt.E * A);                                             \
            h = fmaf(h, a, dt.E * uu.E * BB.E);                               \
            p = dpp_sum16(h * CC.E);                                          \
            if (n == 0) {                                                     \
                const int jg = c * 64 + q * 4 + IDX;                          \
                sy[jg * 16 + chain] = fmaf(Dk0, uu.E, p);                     \
            }
            SCAN_STEP(x, 0)
            SCAN_STEP(y, 1)
            SCAN_STEP(z, 2)
            SCAN_STEP(w, 3)
#undef SCAN_STEP
        }
    }
    __syncthreads();
    // store at OUTPUT l (direction map). Each thread has fixed local d.
    const int ddl = t & 15;
    const int dg = d8 * 16 + ddl;
    float* yk = ybuf + (size_t)(k * 4 + b) * 4096 * 128;
#pragma unroll
    for (int p2 = 0; p2 < 8; ++p2) {
        const int e = p2 * 256 + t;
        const int j = e >> 4;               // 0..127
        const int m = m0 + j;
        int l;
        if (k == 0) l = m;
        else if (k == 1) l = ((m & 63) << 6) | (m >> 6);
        else if (k == 2) l = 4095 - m;
        else { const int mf = 4095 - m; l = ((mf & 63) << 6) | (mf >> 6); }
        yk[(size_t)l * 128 + dg] = sy[j * 16 + ddl];
    }
}

// ---------------------------------------------------------------------------
// Finalize: v[d] = sum_k ybuf[k][b][l][d] (Dsum*u folded in k=0); LN over
// 128; * silu(z); out_proj GEMV; LDS-transposed coalesced store + skip*x1.
// ---------------------------------------------------------------------------
__global__ __launch_bounds__(256) void finalize_k(const float* __restrict__ ybuf,
    const float* __restrict__ z, const float* __restrict__ x1,
    const float* __restrict__ ong, const float* __restrict__ onb,
    const float* __restrict__ opw, const float* __restrict__ skipp,
    float* __restrict__ res)
{
    const int bx = blockIdx.x;               // b*128 + tile
    const int b = bx >> 7, l0 = (bx & 127) * 32;
    const int t = threadIdx.x;
    const int j = t & 31, g = t >> 5;        // g 0..7
    const int l = l0 + j;
    const float4* y0p = (const float4*)(ybuf + ((size_t)(0 + b) * 4096 + l) * 128);
    const float4* y1p = (const float4*)(ybuf + ((size_t)(4 + b) * 4096 + l) * 128);
    const float4* y2p = (const float4*)(ybuf + ((size_t)(8 + b) * 4096 + l) * 128);
    const float4* y3p = (const float4*)(ybuf + ((size_t)(12 + b) * 4096 + l) * 128);
    float4 v4[32];
    float s1 = 0.f, s2 = 0.f;
#pragma unroll
    for (int d4 = 0; d4 < 32; ++d4) {
        const float4 a0 = y0p[d4], a1 = y1p[d4], a2 = y2p[d4], a3 = y3p[d4];
        float4 a;
        a.x = (a0.x + a1.x) + (a2.x + a3.x);
        a.y = (a0.y + a1.y) + (a2.y + a3.y);
        a.z = (a0.z + a1.z) + (a2.z + a3.z);
        a.w = (a0.w + a1.w) + (a2.w + a3.w);
        v4[d4] = a;
        s1 += (a.x + a.y) + (a.z + a.w);
        s2 = fmaf(a.x, a.x, s2); s2 = fmaf(a.y, a.y, s2);
        s2 = fmaf(a.z, a.z, s2); s2 = fmaf(a.w, a.w, s2);
    }
    const float mu = s1 * (1.f / 128.f);
    const float var = s2 * (1.f / 128.f) - mu * mu;
    const float rstd = rsqrtf(var + 1e-5f);
    const float4* zp = (const float4*)(z + ((size_t)(b * 4096 + l)) * 128);
    const float4* gp = (const float4*)ong;
    const float4* bp = (const float4*)onb;
#pragma unroll
    for (int d4 = 0; d4 < 32; ++d4) {
        const float4 gg = gp[d4], bb = bp[d4], zz = zp[d4];
        float4 a = v4[d4];
#define GATE(E)                                                               \
        {                                                                     \
            const float yln = (a.E - mu) * rstd * gg.E + bb.E;                \
            a.E = yln * (zz.E / (1.f + __expf(-zz.E)));                       \
        }
        GATE(x) GATE(y) GATE(z) GATE(w)
#undef GATE
        v4[d4] = a;
    }
    float acc[8] = {0.f, 0.f, 0.f, 0.f, 0.f, 0.f, 0.f, 0.f};
    for (int d4 = 0; d4 < 32; ++d4) {
        const float4 a = v4[d4];
#pragma unroll
        for (int q = 0; q < 8; ++q) {
            const float4 wv = *(const float4*)&opw[(size_t)(g * 8 + q) * 128 + d4 * 4];
            acc[q] = fmaf(a.x, wv.x, acc[q]);
            acc[q] = fmaf(a.y, wv.y, acc[q]);
            acc[q] = fmaf(a.z, wv.z, acc[q]);
            acc[q] = fmaf(a.w, wv.w, acc[q]);
        }
    }
    __shared__ float sres[64 * 33];
#pragma unroll
    for (int q = 0; q < 8; ++q) sres[(g * 8 + q) * 33 + j] = acc[q];
    __syncthreads();
    const float sk = skipp[0];
    for (int e = t; e < 2048; e += 256) {
        const int co = e >> 5, jj = e & 31;
        const size_t o = ((size_t)(b * 64 + co)) * 4096 + l0 + jj;
        res[o] = sres[co * 33 + jj] + sk * x1[o];
    }
}

// ---------------------------------------------------------------------------
// Workspace layout (floats), total 20,185,088 floats = 77.0 MB:
//   x1 @0 (1M), xin_s @1M (2M), zbuf @3M (2M), xin_T @5M (2M),
//   xdbl @7,340,032 (2,359,296), ybuf @9,699,328 (8,388,608, [k][b][l][d]),
//   G @18,087,936 (2M): conv chain / xin_raw / hseg+pseg / res+tmp
// ---------------------------------------------------------------------------
extern "C" void kernel_launch(void* const* d_in, const int* in_sizes, int n_in,
                              void* d_out, int out_size, void* d_ws, size_t ws_size,
                              hipStream_t stream)
{
    const float* x          = (const float*)d_in[0];
    const float* conv1_w    = (const float*)d_in[1];
    const float* conv1_b    = (const float*)d_in[2];
    const float* conv2_w    = (const float*)d_in[3];
    const float* conv2_b    = (const float*)d_in[4];
    const float* cf_w       = (const float*)d_in[5];
    const float* cf_b       = (const float*)d_in[6];
    const float* ln_g       = (const float*)d_in[7];
    const float* ln_b       = (const float*)d_in[8];
    const float* in_proj_w  = (const float*)d_in[9];
    const float* dw_w       = (const float*)d_in[10];
    const float* dw_b       = (const float*)d_in[11];
    const float* x_proj_w   = (const float*)d_in[12];
    const float* dt_proj_w  = (const float*)d_in[13];
    const float* dt_proj_b  = (const float*)d_in[14];
    const float* A_logs     = (const float*)d_in[15];
    const float* Ds         = (const float*)d_in[16];
    const float* out_norm_g = (const float*)d_in[17];
    const float* out_norm_b = (const float*)d_in[18];
    const float* out_proj_w = (const float*)d_in[19];
    const float* skip_scale = (const float*)d_in[20];
    const float* cb_w       = (const float*)d_in[21];
    const float* cb_b       = (const float*)d_in[22];

    float* ws = (float*)d_ws;
    float* x1    = ws;                 // 1,048,576
    float* xin_s = ws + 1048576;       // 2,097,152
    float* zbuf  = ws + 3145728;       // 2,097,152
    float* xin_T = ws + 5242880;       // 2,097,152
    float* xdbl  = ws + 7340032;       // 2,359,296
    float* ybuf  = ws + 9699328;       // 8,388,608
    float* G     = ws + 18087936;      // 2,097,152 scratch
    float* G0 = G;
    float* G1 = G + 1048576;

    conv3x3_k<<<256, 512, 0, stream>>>(x, conv1_w, conv1_b, nullptr, G0);
    inorm_lrelu_k<<<256, 256, 0, stream>>>(G0, G1);
    conv3x3_k<<<256, 512, 0, stream>>>(G1, conv2_w, conv2_b, nullptr, G0);
    conv3x3_k<<<256, 512, 0, stream>>>(G0, cf_w, cf_b, nullptr, x1);
    ln_inproj_k<<<512, 256, 0, stream>>>(x1, ln_g, ln_b, in_proj_w, G /*xin_raw*/, zbuf);
    dwconv_silu_k<<<8192, 256, 0, stream>>>(G /*xin_raw*/, dw_w, dw_b, xin_s);
    transpose_k<<<512, 256, 0, stream>>>(xin_s, xin_T);
    xdbl_k<<<2048, 256, 0, stream>>>(xin_s, xin_T, x_proj_w, xdbl);
    scan_p1_k<<<4096, 256, 0, stream>>>(xdbl, xin_s, xin_T, A_logs, dt_proj_w,
                                        dt_proj_b, G0 /*hseg*/, G1 /*pseg*/);
    scan_combine_k<<<128, 256, 0, stream>>>(G0 /*hseg*/, G1 /*pseg->hstart*/);
    scan_p2_k<<<4096, 256, 0, stream>>>(xdbl, xin_s, xin_T, A_logs, dt_proj_w,
                                        dt_proj_b, G1 /*hstart*/, Ds, ybuf);
    finalize_k<<<512, 256, 0, stream>>>(ybuf, zbuf, x1, out_norm_g, out_norm_b,
                                        out_proj_w, skip_scale, G0 /*res*/);
    conv3x3_k<<<256, 512, 0, stream>>>(G0 /*res*/, cb_w, cb_b, x1, G1 /*tmp*/);
    inorm_lrelu_k<<<256, 256, 0, stream>>>(G1 /*tmp*/, (float*)d_out);
}

// Round 10
// 449.779 us; speedup vs baseline: 5.1681x; 1.5336x over previous
//
#include <hip/hip_runtime.h>
#include <hip/hip_bf16.h>

// All inputs/outputs are float32 (per the reference file's setup_inputs).

typedef __attribute__((ext_vector_type(8))) short bf16x8;
typedef __attribute__((ext_vector_type(4))) float f32x4;

static __device__ __forceinline__ short f2bf(float f)
{
    unsigned u = __float_as_uint(f);
    unsigned r = u + 0x7FFFu + ((u >> 16) & 1u);   // RNE
    return (short)(r >> 16);
}

// 16-lane butterfly sum via DPP (VALU, no DS-pipe traffic).
static __device__ __forceinline__ float dpp_sum16(float x)
{
    x += __int_as_float(__builtin_amdgcn_update_dpp(
        0, __float_as_int(x), 0xB1, 0xF, 0xF, true));   // quad_perm [1,0,3,2]
    x += __int_as_float(__builtin_amdgcn_update_dpp(
        0, __float_as_int(x), 0x4E, 0xF, 0xF, true));   // quad_perm [2,3,0,1]
    x += __int_as_float(__builtin_amdgcn_update_dpp(
        0, __float_as_int(x), 0x141, 0xF, 0xF, true));  // row_half_mirror
    x += __int_as_float(__builtin_amdgcn_update_dpp(
        0, __float_as_int(x), 0x140, 0xF, 0xF, true));  // row_mirror
    return x;
}

// ---------------------------------------------------------------------------
// Weight conversion: 4 conv weight sets fp32 [64co][64ci][3][3] ->
// bf16 wbf[conv][tap][co][ci]. Tiny, runs once per launch.
// ---------------------------------------------------------------------------
__global__ __launch_bounds__(256) void wconv_k(const float* __restrict__ w1,
    const float* __restrict__ w2, const float* __restrict__ w3,
    const float* __restrict__ w4, short* __restrict__ wbf)
{
    const int idx = blockIdx.x * 256 + threadIdx.x;  // 0..147455
    const int c = idx / 36864, rem = idx % 36864;
    const int tap = rem >> 12, r2 = rem & 4095;
    const int co = r2 >> 6, ci = r2 & 63;
    const float* src = (c == 0) ? w1 : (c == 1) ? w2 : (c == 2) ? w3 : w4;
    wbf[idx] = f2bf(src[(co * 64 + ci) * 9 + tap]);
}

// ---------------------------------------------------------------------------
// MFMA 3x3 SAME conv, 64->64 ch, NCHW. Block = one (b,h) row, 256 threads
// (4 waves). Per tap: y[co,pix] += W_t[co,ci] * X[ci,pix] as
// mfma_f32_16x16x32_bf16. Wave = co-tile (16 co), 4 pixel-tiles of 16.
// LDS: input staged bf16 as [3 rows][w+1 (66)][ci (pad 72)] -> B-fragment
// reads are 16B-aligned ds_read_b128 of 8 consecutive ci; dx shifts are just
// +1 column (boundary cols pre-zeroed). A-fragment = 16B global loads of
// wbf[tap][co][ci] (L2-hot). fp32 accumulate; bias/addsrc fused at store.
// Fragment layouts per verified m89/m91 mappings.
// ---------------------------------------------------------------------------
__global__ __launch_bounds__(256) void conv3x3_mfma_k(const float* __restrict__ in,
    const short* __restrict__ wtap, const float* __restrict__ bias,
    const float* __restrict__ addsrc, float* __restrict__ out)
{
    const int bh = blockIdx.x;
    const int b = bh >> 6, h = bh & 63;
    const int t = threadIdx.x;
    __shared__ __align__(16) short lin[3 * 66 * 72];  // [r][w+1][ci]
    int* lz = (int*)lin;
    for (int i = t; i < (3 * 66 * 72) / 2; i += 256) lz[i] = 0;
    __syncthreads();
    {
        const int ci = t >> 2, w16 = (t & 3) * 16;
#pragma unroll
        for (int r = 0; r < 3; ++r) {
            const int hh = h - 1 + r;
            if (hh < 0 || hh > 63) continue;
            const float* src = in + ((size_t)(b * 64 + ci) * 64 + hh) * 64 + w16;
#pragma unroll
            for (int q = 0; q < 4; ++q) {
                const float4 v = *(const float4*)(src + q * 4);
                const int wb = w16 + q * 4;
                lin[(r * 66 + wb + 1) * 72 + ci] = f2bf(v.x);
                lin[(r * 66 + wb + 2) * 72 + ci] = f2bf(v.y);
                lin[(r * 66 + wb + 3) * 72 + ci] = f2bf(v.z);
                lin[(r * 66 + wb + 4) * 72 + ci] = f2bf(v.w);
            }
        }
    }
    __syncthreads();
    const int lane = t & 63, ct = t >> 6;     // wave = co-tile
    const int n16 = lane & 15, quad = lane >> 4;
    f32x4 acc0 = {0.f, 0.f, 0.f, 0.f};
    f32x4 acc1 = {0.f, 0.f, 0.f, 0.f};
    f32x4 acc2 = {0.f, 0.f, 0.f, 0.f};
    f32x4 acc3 = {0.f, 0.f, 0.f, 0.f};
#pragma unroll
    for (int tap = 0; tap < 9; ++tap) {
        const int dy = tap / 3, dx = tap % 3;
#pragma unroll
        for (int kh = 0; kh < 2; ++kh) {
            const int kk = kh * 32;
            const bf16x8 a = *(const bf16x8*)(wtap +
                ((size_t)tap * 64 + ct * 16 + n16) * 64 + kk + quad * 8);
            const int rb = (dy * 66 + n16 + dx) * 72 + kk + quad * 8;
            const bf16x8 b0 = *(const bf16x8*)&lin[rb + 0 * 16 * 72];
            const bf16x8 b1 = *(const bf16x8*)&lin[rb + 1 * 16 * 72];
            const bf16x8 b2 = *(const bf16x8*)&lin[rb + 2 * 16 * 72];
            const bf16x8 b3 = *(const bf16x8*)&lin[rb + 3 * 16 * 72];
            acc0 = __builtin_amdgcn_mfma_f32_16x16x32_bf16(a, b0, acc0, 0, 0, 0);
            acc1 = __builtin_amdgcn_mfma_f32_16x16x32_bf16(a, b1, acc1, 0, 0, 0);
            acc2 = __builtin_amdgcn_mfma_f32_16x16x32_bf16(a, b2, acc2, 0, 0, 0);
            acc3 = __builtin_amdgcn_mfma_f32_16x16x32_bf16(a, b3, acc3, 0, 0, 0);
        }
    }
#pragma unroll
    for (int r = 0; r < 4; ++r) {
        const int co = ct * 16 + quad * 4 + r;
        const float bv = bias[co];
        float* orow = out + ((size_t)(b * 64 + co) * 64 + h) * 64;
        float v0 = acc0[r] + bv, v1 = acc1[r] + bv, v2 = acc2[r] + bv, v3 = acc3[r] + bv;
        if (addsrc) {
            const float* arow = addsrc + ((size_t)(b * 64 + co) * 64 + h) * 64;
            v0 += arow[n16]; v1 += arow[16 + n16];
            v2 += arow[32 + n16]; v3 += arow[48 + n16];
        }
        orow[n16] = v0; orow[16 + n16] = v1;
        orow[32 + n16] = v2; orow[48 + n16] = v3;
    }
}

// ---------------------------------------------------------------------------
// InstanceNorm over HxW per (b,c) + LeakyReLU(0.2). Block per (b,c).
// ---------------------------------------------------------------------------
__global__ __launch_bounds__(256) void inorm_lrelu_k(const float* __restrict__ in,
                                                     float* __restrict__ out)
{
    const int bc = blockIdx.x;
    const float* row = in + (size_t)bc * 4096;
    float s1 = 0.f, s2 = 0.f;
    for (int i = threadIdx.x; i < 4096; i += 256) {
        const float v = row[i];
        s1 += v; s2 = fmaf(v, v, s2);
    }
#pragma unroll
    for (int mk = 1; mk < 64; mk <<= 1) {
        s1 += __shfl_xor(s1, mk, 64);
        s2 += __shfl_xor(s2, mk, 64);
    }
    __shared__ float a1[4], a2[4];
    const int wid = threadIdx.x >> 6;
    if ((threadIdx.x & 63) == 0) { a1[wid] = s1; a2[wid] = s2; }
    __syncthreads();
    const float S1 = a1[0] + a1[1] + a1[2] + a1[3];
    const float S2 = a2[0] + a2[1] + a2[2] + a2[3];
    const float mu = S1 * (1.f / 4096.f);
    const float var = S2 * (1.f / 4096.f) - mu * mu;
    const float rstd = rsqrtf(var + 1e-5f);
    float* orow = out + (size_t)bc * 4096;
    for (int i = threadIdx.x; i < 4096; i += 256) {
        float v = (row[i] - mu) * rstd;
        v = (v >= 0.f) ? v : 0.2f * v;
        orow[i] = v;
    }
}

// ---------------------------------------------------------------------------
// LayerNorm over 64 ch (NHWC view of x1) + in_proj (256x64). No LDS.
// ---------------------------------------------------------------------------
__global__ __launch_bounds__(256) void ln_inproj_k(const float* __restrict__ x1,
    const float* __restrict__ g, const float* __restrict__ be,
    const float* __restrict__ w, float* __restrict__ xin_raw, float* __restrict__ z)
{
    const int bx = blockIdx.x;
    const int b = bx >> 7, l0 = (bx & 127) * 32;
    const int t = threadIdx.x;
    const int j = t & 31, co0 = (t >> 5) * 32;
    float xr[64];
    float s1 = 0.f, s2 = 0.f;
#pragma unroll
    for (int c = 0; c < 64; ++c) {
        const float v = x1[(b * 64 + c) * 4096 + l0 + j];
        xr[c] = v; s1 += v; s2 = fmaf(v, v, s2);
    }
    const float mu = s1 * (1.f / 64.f);
    const float var = s2 * (1.f / 64.f) - mu * mu;
    const float rstd = rsqrtf(var + 1e-5f);
#pragma unroll
    for (int c = 0; c < 64; ++c)
        xr[c] = (xr[c] - mu) * rstd * g[c] + be[c];
    for (int i = 0; i < 32; ++i) {
        const int e = co0 + i;
        const float4* wp = (const float4*)(w + e * 64);
        float a = 0.f;
#pragma unroll
        for (int c4 = 0; c4 < 16; ++c4) {
            const float4 wv = wp[c4];
            a = fmaf(xr[c4 * 4 + 0], wv.x, a);
            a = fmaf(xr[c4 * 4 + 1], wv.y, a);
            a = fmaf(xr[c4 * 4 + 2], wv.z, a);
            a = fmaf(xr[c4 * 4 + 3], wv.w, a);
        }
        if (e < 128) xin_raw[(b * 128 + e) * 4096 + l0 + j] = a;
        else z[((size_t)(b * 4096 + l0 + j)) * 128 + (e - 128)] = a;
    }
}

// ---------------------------------------------------------------------------
// Depthwise 3x3 SAME conv + bias + SiLU on (b,128,64,64).
// ---------------------------------------------------------------------------
__global__ __launch_bounds__(256) void dwconv_silu_k(const float* __restrict__ in,
    const float* __restrict__ w, const float* __restrict__ bias, float* __restrict__ out)
{
    const int idx = blockIdx.x * 256 + threadIdx.x;  // (b*128+d)*4096 + l
    const int l = idx & 4095, bd = idx >> 12, d = bd & 127;
    const int hh = l >> 6, ww = l & 63;
    const float* base = in + (size_t)bd * 4096;
    float acc = bias[d];
    const float* wp = w + d * 9;
#pragma unroll
    for (int dy = 0; dy < 3; ++dy) {
        const int y = hh + dy - 1;
        if (y < 0 || y > 63) continue;
#pragma unroll
        for (int dx = 0; dx < 3; ++dx) {
            const int xx = ww + dx - 1;
            if (xx < 0 || xx > 63) continue;
            acc = fmaf(base[y * 64 + xx], wp[dy * 3 + dx], acc);
        }
    }
    out[idx] = acc / (1.f + __expf(-acc));  // silu
}

// ---------------------------------------------------------------------------
// 64x64 spatial transpose per (b,d).
// ---------------------------------------------------------------------------
__global__ __launch_bounds__(256) void transpose_k(const float* __restrict__ in,
                                                   float* __restrict__ out)
{
    const int bd = blockIdx.x;
    __shared__ float tl[64 * 65];
    const float* src = in + (size_t)bd * 4096;
    for (int e = threadIdx.x; e < 4096; e += 256) {
        const int r = e >> 6, c = e & 63;
        tl[r * 65 + c] = src[e];
    }
    __syncthreads();
    float* dst = out + (size_t)bd * 4096;
    for (int e = threadIdx.x; e < 4096; e += 256) {
        const int wi = e >> 6, hi = e & 63;
        dst[e] = tl[hi * 65 + wi];
    }
}

// ---------------------------------------------------------------------------
// x_dbl[b,k,c,m] = sum_d xs[b,k,d,m] * x_proj_w[k,c,d]  (c=36, scan order m).
// ---------------------------------------------------------------------------
__global__ __launch_bounds__(256) void xdbl_k(const float* __restrict__ xin_s,
    const float* __restrict__ xin_T, const float* __restrict__ xpw,
    float* __restrict__ xdbl)
{
    const int bx = blockIdx.x;
    const int bk = bx >> 7, m0 = (bx & 127) * 32;
    const int b = bk >> 2, k = bk & 3;
    __shared__ float tl[32 * 132];   // [j][d], pad 132
    const float* src = (k & 1) ? xin_T : xin_s;
    const bool rev = (k >= 2);
    for (int e = threadIdx.x; e < 4096; e += 256) {
        const int d = e >> 5, j = e & 31;
        const int m = m0 + j;
        const int um = rev ? (4095 - m) : m;
        tl[j * 132 + d] = src[(b * 128 + d) * 4096 + um];
    }
    __syncthreads();
    const int j = threadIdx.x & 31, c0 = threadIdx.x >> 5;
    const float4* xv4 = (const float4*)(tl + j * 132);
    float acc[5] = {0.f, 0.f, 0.f, 0.f, 0.f};
    for (int d4 = 0; d4 < 32; ++d4) {
        const float4 xv = xv4[d4];
#pragma unroll
        for (int q = 0; q < 5; ++q) {
            const int c = c0 + q * 8;
            if (c < 36) {
                const float4 wv = *(const float4*)&xpw[((size_t)(k * 36 + c)) * 128 + d4 * 4];
                acc[q] = fmaf(xv.x, wv.x, acc[q]);
                acc[q] = fmaf(xv.y, wv.y, acc[q]);
                acc[q] = fmaf(xv.z, wv.z, acc[q]);
                acc[q] = fmaf(xv.w, wv.w, acc[q]);
            }
        }
    }
#pragma unroll
    for (int q = 0; q < 5; ++q) {
        const int c = c0 + q * 8;
        if (c < 36) xdbl[((size_t)bk * 36 + c) * 4096 + m0 + j] = acc[q];
    }
}

// ---------------------------------------------------------------------------
// Segmented scan, phase 1. Two 64-step staging chunks (13KB LDS).
// ---------------------------------------------------------------------------
__global__ __launch_bounds__(256) void scan_p1_k(const float* __restrict__ xdbl,
    const float* __restrict__ xin_s, const float* __restrict__ xin_T,
    const float* __restrict__ A_logs, const float* __restrict__ dtw,
    const float* __restrict__ dtb, float* __restrict__ hseg,
    float* __restrict__ pseg)
{
    const int bx = blockIdx.x;
    const int seg = bx & 31, d8 = (bx >> 5) & 7, bk = bx >> 8;
    const int b = bk >> 2, k = bk & 3;
    const int t = threadIdx.x;
    const int chain = t >> 4, n = t & 15;
    const int d = d8 * 16 + chain;
    const float A = -__expf(A_logs[(k * 128 + d) * 16 + n]);
    __shared__ float sB[16 * 68], sdt[16 * 68], su[16 * 68];
    const float* srcu = (k & 1) ? xin_T : xin_s;
    const bool rev = (k >= 2);
    const int col = t & 63, r0 = t >> 6;
    const int m0 = seg * 128;
    float h = 0.f, pr = 1.f;
    for (int c = 0; c < 2; ++c) {
        const int cb = m0 + c * 64;
        __syncthreads();
        const float dts0 = xdbl[((size_t)bk * 36 + 0) * 4096 + cb + col];
        const float dts1 = xdbl[((size_t)bk * 36 + 1) * 4096 + cb + col];
        const float dts2 = xdbl[((size_t)bk * 36 + 2) * 4096 + cb + col];
        const float dts3 = xdbl[((size_t)bk * 36 + 3) * 4096 + cb + col];
        const int m = cb + col;
        const int um = rev ? (4095 - m) : m;
#pragma unroll
        for (int i = 0; i < 4; ++i) {
            const int nn = r0 + 4 * i;
            sB[nn * 68 + col] = xdbl[((size_t)bk * 36 + 4 + nn) * 4096 + cb + col];
            const int dd = d8 * 16 + nn;
            const float* wp = dtw + (k * 128 + dd) * 4;
            float s = dtb[k * 128 + dd];
            s = fmaf(dts0, wp[0], s);
            s = fmaf(dts1, wp[1], s);
            s = fmaf(dts2, wp[2], s);
            s = fmaf(dts3, wp[3], s);
            sdt[nn * 68 + col] = (s > 20.f) ? s : log1pf(__expf(s));
            su[nn * 68 + col] = srcu[(b * 128 + dd) * 4096 + um];
        }
        __syncthreads();
        const float4* B4  = (const float4*)(sB + n * 68);
        const float4* dt4 = (const float4*)(sdt + chain * 68);
        const float4* u4  = (const float4*)(su + chain * 68);
#pragma unroll 4
        for (int q = 0; q < 16; ++q) {
            const float4 dt = dt4[q], uu = u4[q], BB = B4[q];
            float a;
            a = __expf(dt.x * A); h = fmaf(h, a, dt.x * uu.x * BB.x); pr *= a;
            a = __expf(dt.y * A); h = fmaf(h, a, dt.y * uu.y * BB.y); pr *= a;
            a = __expf(dt.z * A); h = fmaf(h, a, dt.z * uu.z * BB.z); pr *= a;
            a = __expf(dt.w * A); h = fmaf(h, a, dt.w * uu.w * BB.w); pr *= a;
        }
    }
    const size_t idx = (size_t)seg * 32768 + (size_t)(bk * 128 + d) * 16 + n;
    hseg[idx] = h;
    pseg[idx] = pr;
}

// ---------------------------------------------------------------------------
// Combine segment summaries (coalesced). pseg is overwritten with h_start.
// ---------------------------------------------------------------------------
__global__ __launch_bounds__(256) void scan_combine_k(const float* __restrict__ hseg,
                                                      float* __restrict__ pseg)
{
    const int i = blockIdx.x * 256 + threadIdx.x;  // 0..32767
    float h = 0.f;
#pragma unroll 4
    for (int s = 0; s < 32; ++s) {
        const size_t idx = (size_t)s * 32768 + i;
        const float p = pseg[idx];
        const float he = hseg[idx];
        pseg[idx] = h;
        h = fmaf(h, p, he);
    }
}

// ---------------------------------------------------------------------------
// Segmented scan, phase 2. Two 64-step staging chunks (25.6KB LDS, 6 blk/CU).
// Dsum*u folded in-loop (k==0). Direction map applied at store. No atomics.
// ---------------------------------------------------------------------------
__global__ __launch_bounds__(256) void scan_p2_k(const float* __restrict__ xdbl,
    const float* __restrict__ xin_s, const float* __restrict__ xin_T,
    const float* __restrict__ A_logs, const float* __restrict__ dtw,
    const float* __restrict__ dtb, const float* __restrict__ hstart,
    const float* __restrict__ Dsp, float* __restrict__ ybuf)
{
    const int bx = blockIdx.x;
    const int seg = bx & 31, d8 = (bx >> 5) & 7, bk = bx >> 8;
    const int b = bk >> 2, k = bk & 3;
    const int t = threadIdx.x;
    const int chain = t >> 4, n = t & 15;
    const int d = d8 * 16 + chain;
    const float A = -__expf(A_logs[(k * 128 + d) * 16 + n]);
    __shared__ float sB[16 * 68], sC[16 * 68], sdt[16 * 68], su[16 * 68];
    __shared__ float sy[128 * 16];  // [j][dd]
    const float* srcu = (k & 1) ? xin_T : xin_s;
    const bool rev = (k >= 2);
    const int col = t & 63, r0 = t >> 6;
    const int m0 = seg * 128;
    const float Dk0 = (k == 0)
        ? (Dsp[d] + Dsp[128 + d] + Dsp[256 + d] + Dsp[384 + d]) : 0.f;
    float h = hstart[(size_t)seg * 32768 + (size_t)(bk * 128 + d) * 16 + n];
    for (int c = 0; c < 2; ++c) {
        const int cb = m0 + c * 64;
        __syncthreads();
        const float dts0 = xdbl[((size_t)bk * 36 + 0) * 4096 + cb + col];
        const float dts1 = xdbl[((size_t)bk * 36 + 1) * 4096 + cb + col];
        const float dts2 = xdbl[((size_t)bk * 36 + 2) * 4096 + cb + col];
        const float dts3 = xdbl[((size_t)bk * 36 + 3) * 4096 + cb + col];
        const int m = cb + col;
        const int um = rev ? (4095 - m) : m;
#pragma unroll
        for (int i = 0; i < 4; ++i) {
            const int nn = r0 + 4 * i;
            sB[nn * 68 + col] = xdbl[((size_t)bk * 36 + 4 + nn) * 4096 + cb + col];
            sC[nn * 68 + col] = xdbl[((size_t)bk * 36 + 20 + nn) * 4096 + cb + col];
            const int dd = d8 * 16 + nn;
            const float* wp = dtw + (k * 128 + dd) * 4;
            float s = dtb[k * 128 + dd];
            s = fmaf(dts0, wp[0], s);
            s = fmaf(dts1, wp[1], s);
            s = fmaf(dts2, wp[2], s);
            s = fmaf(dts3, wp[3], s);
            sdt[nn * 68 + col] = (s > 20.f) ? s : log1pf(__expf(s));
            su[nn * 68 + col] = srcu[(b * 128 + dd) * 4096 + um];
        }
        __syncthreads();
        const float4* B4  = (const float4*)(sB + n * 68);
        const float4* C4  = (const float4*)(sC + n * 68);
        const float4* dt4 = (const float4*)(sdt + chain * 68);
        const float4* u4  = (const float4*)(su + chain * 68);
#pragma unroll 4
        for (int q = 0; q < 16; ++q) {
            const float4 dt = dt4[q], uu = u4[q], BB = B4[q], CC = C4[q];
            float a, p;
#define SCAN_STEP(E, IDX)                                                     \
            a = __expf(dt.E * A);                                             \
            h = fmaf(h, a, dt.E * uu.E * BB.E);                               \
            p = dpp_sum16(h * CC.E);                                          \
            if (n == 0) {                                                     \
                const int jg = c * 64 + q * 4 + IDX;                          \
                sy[jg * 16 + chain] = fmaf(Dk0, uu.E, p);                     \
            }
            SCAN_STEP(x, 0)
            SCAN_STEP(y, 1)
            SCAN_STEP(z, 2)
            SCAN_STEP(w, 3)
#undef SCAN_STEP
        }
    }
    __syncthreads();
    const int ddl = t & 15;
    const int dg = d8 * 16 + ddl;
    float* yk = ybuf + (size_t)(k * 4 + b) * 4096 * 128;
#pragma unroll
    for (int p2 = 0; p2 < 8; ++p2) {
        const int e = p2 * 256 + t;
        const int j = e >> 4;               // 0..127
        const int m = m0 + j;
        int l;
        if (k == 0) l = m;
        else if (k == 1) l = ((m & 63) << 6) | (m >> 6);
        else if (k == 2) l = 4095 - m;
        else { const int mf = 4095 - m; l = ((mf & 63) << 6) | (mf >> 6); }
        yk[(size_t)l * 128 + dg] = sy[j * 16 + ddl];
    }
}

// ---------------------------------------------------------------------------
// Finalize: v[d] = sum_k ybuf[k][b][l][d]; LN over 128; * silu(z); out_proj
// GEMV; LDS-transposed coalesced store + skip*x1. Block = 32 l, 256 thr.
// ---------------------------------------------------------------------------
__global__ __launch_bounds__(256) void finalize_k(const float* __restrict__ ybuf,
    const float* __restrict__ z, const float* __restrict__ x1,
    const float* __restrict__ ong, const float* __restrict__ onb,
    const float* __restrict__ opw, const float* __restrict__ skipp,
    float* __restrict__ res)
{
    const int bx = blockIdx.x;               // b*128 + tile
    const int b = bx >> 7, l0 = (bx & 127) * 32;
    const int t = threadIdx.x;
    const int j = t & 31, g = t >> 5;        // g 0..7
    const int l = l0 + j;
    const float4* y0p = (const float4*)(ybuf + ((size_t)(0 + b) * 4096 + l) * 128);
    const float4* y1p = (const float4*)(ybuf + ((size_t)(4 + b) * 4096 + l) * 128);
    const float4* y2p = (const float4*)(ybuf + ((size_t)(8 + b) * 4096 + l) * 128);
    const float4* y3p = (const float4*)(ybuf + ((size_t)(12 + b) * 4096 + l) * 128);
    float4 v4[32];
    float s1 = 0.f, s2 = 0.f;
#pragma unroll
    for (int d4 = 0; d4 < 32; ++d4) {
        const float4 a0 = y0p[d4], a1 = y1p[d4], a2 = y2p[d4], a3 = y3p[d4];
        float4 a;
        a.x = (a0.x + a1.x) + (a2.x + a3.x);
        a.y = (a0.y + a1.y) + (a2.y + a3.y);
        a.z = (a0.z + a1.z) + (a2.z + a3.z);
        a.w = (a0.w + a1.w) + (a2.w + a3.w);
        v4[d4] = a;
        s1 += (a.x + a.y) + (a.z + a.w);
        s2 = fmaf(a.x, a.x, s2); s2 = fmaf(a.y, a.y, s2);
        s2 = fmaf(a.z, a.z, s2); s2 = fmaf(a.w, a.w, s2);
    }
    const float mu = s1 * (1.f / 128.f);
    const float var = s2 * (1.f / 128.f) - mu * mu;
    const float rstd = rsqrtf(var + 1e-5f);
    const float4* zp = (const float4*)(z + ((size_t)(b * 4096 + l)) * 128);
    const float4* gp = (const float4*)ong;
    const float4* bp = (const float4*)onb;
#pragma unroll
    for (int d4 = 0; d4 < 32; ++d4) {
        const float4 gg = gp[d4], bb = bp[d4], zz = zp[d4];
        float4 a = v4[d4];
#define GATE(E)                                                               \
        {                                                                     \
            const float yln = (a.E - mu) * rstd * gg.E + bb.E;                \
            a.E = yln * (zz.E / (1.f + __expf(-zz.E)));                       \
        }
        GATE(x) GATE(y) GATE(z) GATE(w)
#undef GATE
        v4[d4] = a;
    }
    float acc[8] = {0.f, 0.f, 0.f, 0.f, 0.f, 0.f, 0.f, 0.f};
    for (int d4 = 0; d4 < 32; ++d4) {
        const float4 a = v4[d4];
#pragma unroll
        for (int q = 0; q < 8; ++q) {
            const float4 wv = *(const float4*)&opw[(size_t)(g * 8 + q) * 128 + d4 * 4];
            acc[q] = fmaf(a.x, wv.x, acc[q]);
            acc[q] = fmaf(a.y, wv.y, acc[q]);
            acc[q] = fmaf(a.z, wv.z, acc[q]);
            acc[q] = fmaf(a.w, wv.w, acc[q]);
        }
    }
    __shared__ float sres[64 * 33];
#pragma unroll
    for (int q = 0; q < 8; ++q) sres[(g * 8 + q) * 33 + j] = acc[q];
    __syncthreads();
    const float sk = skipp[0];
    for (int e = t; e < 2048; e += 256) {
        const int co = e >> 5, jj = e & 31;
        const size_t o = ((size_t)(b * 64 + co)) * 4096 + l0 + jj;
        res[o] = sres[co * 33 + jj] + sk * x1[o];
    }
}

// ---------------------------------------------------------------------------
// Workspace layout (floats), total 20,258,816 floats = 77.3 MB:
//   x1 @0 (1M), xin_s @1M (2M), zbuf @3M (2M), xin_T @5M (2M),
//   xdbl @7,340,032 (2,359,296), ybuf @9,699,328 (8,388,608, [k][b][l][d]),
//   G @18,087,936 (2M): xin_raw / hseg+pseg / res+tmp + conv chain,
//   wbf @20,185,088 (73,728 floats = 147,456 bf16 = [4conv][9tap][64co][64ci])
// ---------------------------------------------------------------------------
extern "C" void kernel_launch(void* const* d_in, const int* in_sizes, int n_in,
                              void* d_out, int out_size, void* d_ws, size_t ws_size,
                              hipStream_t stream)
{
    const float* x          = (const float*)d_in[0];
    const float* conv1_w    = (const float*)d_in[1];
    const float* conv1_b    = (const float*)d_in[2];
    const float* conv2_w    = (const float*)d_in[3];
    const float* conv2_b    = (const float*)d_in[4];
    const float* cf_w       = (const float*)d_in[5];
    const float* cf_b       = (const float*)d_in[6];
    const float* ln_g       = (const float*)d_in[7];
    const float* ln_b       = (const float*)d_in[8];
    const float* in_proj_w  = (const float*)d_in[9];
    const float* dw_w       = (const float*)d_in[10];
    const float* dw_b       = (const float*)d_in[11];
    const float* x_proj_w   = (const float*)d_in[12];
    const float* dt_proj_w  = (const float*)d_in[13];
    const float* dt_proj_b  = (const float*)d_in[14];
    const float* A_logs     = (const float*)d_in[15];
    const float* Ds         = (const float*)d_in[16];
    const float* out_norm_g = (const float*)d_in[17];
    const float* out_norm_b = (const float*)d_in[18];
    const float* out_proj_w = (const float*)d_in[19];
    const float* skip_scale = (const float*)d_in[20];
    const float* cb_w       = (const float*)d_in[21];
    const float* cb_b       = (const float*)d_in[22];

    float* ws = (float*)d_ws;
    float* x1    = ws;                 // 1,048,576
    float* xin_s = ws + 1048576;       // 2,097,152
    float* zbuf  = ws + 3145728;       // 2,097,152
    float* xin_T = ws + 5242880;       // 2,097,152
    float* xdbl  = ws + 7340032;       // 2,359,296
    float* ybuf  = ws + 9699328;       // 8,388,608
    float* G     = ws + 18087936;      // 2,097,152 scratch
    float* G0 = G;
    float* G1 = G + 1048576;
    short* wbf  = (short*)(ws + 20185088);  // 147,456 bf16
    short* wbf1 = wbf;                       // conv1
    short* wbf2 = wbf + 36864;               // conv2
    short* wbf3 = wbf + 73728;               // cf
    short* wbf4 = wbf + 110592;              // cb

    wconv_k<<<576, 256, 0, stream>>>(conv1_w, conv2_w, cf_w, cb_w, wbf);

    conv3x3_mfma_k<<<256, 256, 0, stream>>>(x, wbf1, conv1_b, nullptr, G0);
    inorm_lrelu_k<<<256, 256, 0, stream>>>(G0, G1);
    conv3x3_mfma_k<<<256, 256, 0, stream>>>(G1, wbf2, conv2_b, nullptr, G0);
    conv3x3_mfma_k<<<256, 256, 0, stream>>>(G0, wbf3, cf_b, nullptr, x1);
    ln_inproj_k<<<512, 256, 0, stream>>>(x1, ln_g, ln_b, in_proj_w, G /*xin_raw*/, zbuf);
    dwconv_silu_k<<<8192, 256, 0, stream>>>(G /*xin_raw*/, dw_w, dw_b, xin_s);
    transpose_k<<<512, 256, 0, stream>>>(xin_s, xin_T);
    xdbl_k<<<2048, 256, 0, stream>>>(xin_s, xin_T, x_proj_w, xdbl);
    scan_p1_k<<<4096, 256, 0, stream>>>(xdbl, xin_s, xin_T, A_logs, dt_proj_w,
                                        dt_proj_b, G0 /*hseg*/, G1 /*pseg*/);
    scan_combine_k<<<128, 256, 0, stream>>>(G0 /*hseg*/, G1 /*pseg->hstart*/);
    scan_p2_k<<<4096, 256, 0, stream>>>(xdbl, xin_s, xin_T, A_logs, dt_proj_w,
                                        dt_proj_b, G1 /*hstart*/, Ds, ybuf);
    finalize_k<<<512, 256, 0, stream>>>(ybuf, zbuf, x1, out_norm_g, out_norm_b,
                                        out_proj_w, skip_scale, G0 /*res*/);
    conv3x3_mfma_k<<<256, 256, 0, stream>>>(G0 /*res*/, wbf4, cb_b, x1, G1 /*tmp*/);
    inorm_lrelu_k<<<256, 256, 0, stream>>>(G1 /*tmp*/, (float*)d_out);
}

// Round 11
// 413.074 us; speedup vs baseline: 5.6274x; 1.0889x over previous
//
#include <hip/hip_runtime.h>
#include <hip/hip_bf16.h>

// All inputs/outputs are float32 (per the reference file's setup_inputs).

typedef __attribute__((ext_vector_type(8))) short bf16x8;
typedef __attribute__((ext_vector_type(4))) float f32x4;

static __device__ __forceinline__ short f2bf(float f)
{
    unsigned u = __float_as_uint(f);
    unsigned r = u + 0x7FFFu + ((u >> 16) & 1u);   // RNE
    return (short)(r >> 16);
}

// 16-lane butterfly sum via DPP (VALU, no DS-pipe traffic).
static __device__ __forceinline__ float dpp_sum16(float x)
{
    x += __int_as_float(__builtin_amdgcn_update_dpp(
        0, __float_as_int(x), 0xB1, 0xF, 0xF, true));   // quad_perm [1,0,3,2]
    x += __int_as_float(__builtin_amdgcn_update_dpp(
        0, __float_as_int(x), 0x4E, 0xF, 0xF, true));   // quad_perm [2,3,0,1]
    x += __int_as_float(__builtin_amdgcn_update_dpp(
        0, __float_as_int(x), 0x141, 0xF, 0xF, true));  // row_half_mirror
    x += __int_as_float(__builtin_amdgcn_update_dpp(
        0, __float_as_int(x), 0x140, 0xF, 0xF, true));  // row_mirror
    return x;
}

// ---------------------------------------------------------------------------
// Weight conversion: 4 conv sets [64co][64ci][3][3] -> wbf[conv][tap][co][ci]
// + in_proj_w [256e][64c] -> wip (bf16, same layout). 163840 elems total.
// ---------------------------------------------------------------------------
__global__ __launch_bounds__(256) void wconv_k(const float* __restrict__ w1,
    const float* __restrict__ w2, const float* __restrict__ w3,
    const float* __restrict__ w4, const float* __restrict__ ipw,
    short* __restrict__ wbf)
{
    const int idx = blockIdx.x * 256 + threadIdx.x;  // 0..163839
    if (idx < 147456) {
        const int c = idx / 36864, rem = idx % 36864;
        const int tap = rem >> 12, r2 = rem & 4095;
        const int co = r2 >> 6, ci = r2 & 63;
        const float* src = (c == 0) ? w1 : (c == 1) ? w2 : (c == 2) ? w3 : w4;
        wbf[idx] = f2bf(src[(co * 64 + ci) * 9 + tap]);
    } else {
        const int i2 = idx - 147456;                 // 0..16383, [e][c]
        wbf[idx] = f2bf(ipw[i2]);
    }
}

// ---------------------------------------------------------------------------
// MFMA 3x3 SAME conv, 64->64 ch, NCHW. Block = one (b,h) row, 256 threads.
// (verified R10: ~10us/conv, absmax ok)
// ---------------------------------------------------------------------------
__global__ __launch_bounds__(256) void conv3x3_mfma_k(const float* __restrict__ in,
    const short* __restrict__ wtap, const float* __restrict__ bias,
    const float* __restrict__ addsrc, float* __restrict__ out)
{
    const int bh = blockIdx.x;
    const int b = bh >> 6, h = bh & 63;
    const int t = threadIdx.x;
    __shared__ __align__(16) short lin[3 * 66 * 72];  // [r][w+1][ci]
    int* lz = (int*)lin;
    for (int i = t; i < (3 * 66 * 72) / 2; i += 256) lz[i] = 0;
    __syncthreads();
    {
        const int ci = t >> 2, w16 = (t & 3) * 16;
#pragma unroll
        for (int r = 0; r < 3; ++r) {
            const int hh = h - 1 + r;
            if (hh < 0 || hh > 63) continue;
            const float* src = in + ((size_t)(b * 64 + ci) * 64 + hh) * 64 + w16;
#pragma unroll
            for (int q = 0; q < 4; ++q) {
                const float4 v = *(const float4*)(src + q * 4);
                const int wb = w16 + q * 4;
                lin[(r * 66 + wb + 1) * 72 + ci] = f2bf(v.x);
                lin[(r * 66 + wb + 2) * 72 + ci] = f2bf(v.y);
                lin[(r * 66 + wb + 3) * 72 + ci] = f2bf(v.z);
                lin[(r * 66 + wb + 4) * 72 + ci] = f2bf(v.w);
            }
        }
    }
    __syncthreads();
    const int lane = t & 63, ct = t >> 6;     // wave = co-tile
    const int n16 = lane & 15, quad = lane >> 4;
    f32x4 acc0 = {0.f, 0.f, 0.f, 0.f};
    f32x4 acc1 = {0.f, 0.f, 0.f, 0.f};
    f32x4 acc2 = {0.f, 0.f, 0.f, 0.f};
    f32x4 acc3 = {0.f, 0.f, 0.f, 0.f};
#pragma unroll
    for (int tap = 0; tap < 9; ++tap) {
        const int dy = tap / 3, dx = tap % 3;
#pragma unroll
        for (int kh = 0; kh < 2; ++kh) {
            const int kk = kh * 32;
            const bf16x8 a = *(const bf16x8*)(wtap +
                ((size_t)tap * 64 + ct * 16 + n16) * 64 + kk + quad * 8);
            const int rb = (dy * 66 + n16 + dx) * 72 + kk + quad * 8;
            const bf16x8 b0 = *(const bf16x8*)&lin[rb + 0 * 16 * 72];
            const bf16x8 b1 = *(const bf16x8*)&lin[rb + 1 * 16 * 72];
            const bf16x8 b2 = *(const bf16x8*)&lin[rb + 2 * 16 * 72];
            const bf16x8 b3 = *(const bf16x8*)&lin[rb + 3 * 16 * 72];
            acc0 = __builtin_amdgcn_mfma_f32_16x16x32_bf16(a, b0, acc0, 0, 0, 0);
            acc1 = __builtin_amdgcn_mfma_f32_16x16x32_bf16(a, b1, acc1, 0, 0, 0);
            acc2 = __builtin_amdgcn_mfma_f32_16x16x32_bf16(a, b2, acc2, 0, 0, 0);
            acc3 = __builtin_amdgcn_mfma_f32_16x16x32_bf16(a, b3, acc3, 0, 0, 0);
        }
    }
#pragma unroll
    for (int r = 0; r < 4; ++r) {
        const int co = ct * 16 + quad * 4 + r;
        const float bv = bias[co];
        float* orow = out + ((size_t)(b * 64 + co) * 64 + h) * 64;
        float v0 = acc0[r] + bv, v1 = acc1[r] + bv, v2 = acc2[r] + bv, v3 = acc3[r] + bv;
        if (addsrc) {
            const float* arow = addsrc + ((size_t)(b * 64 + co) * 64 + h) * 64;
            v0 += arow[n16]; v1 += arow[16 + n16];
            v2 += arow[32 + n16]; v3 += arow[48 + n16];
        }
        orow[n16] = v0; orow[16 + n16] = v1;
        orow[32 + n16] = v2; orow[48 + n16] = v3;
    }
}

// ---------------------------------------------------------------------------
// InstanceNorm over HxW per (b,c) + LeakyReLU(0.2). Block per (b,c).
// ---------------------------------------------------------------------------
__global__ __launch_bounds__(256) void inorm_lrelu_k(const float* __restrict__ in,
                                                     float* __restrict__ out)
{
    const int bc = blockIdx.x;
    const float* row = in + (size_t)bc * 4096;
    float s1 = 0.f, s2 = 0.f;
    for (int i = threadIdx.x; i < 4096; i += 256) {
        const float v = row[i];
        s1 += v; s2 = fmaf(v, v, s2);
    }
#pragma unroll
    for (int mk = 1; mk < 64; mk <<= 1) {
        s1 += __shfl_xor(s1, mk, 64);
        s2 += __shfl_xor(s2, mk, 64);
    }
    __shared__ float a1[4], a2[4];
    const int wid = threadIdx.x >> 6;
    if ((threadIdx.x & 63) == 0) { a1[wid] = s1; a2[wid] = s2; }
    __syncthreads();
    const float S1 = a1[0] + a1[1] + a1[2] + a1[3];
    const float S2 = a2[0] + a2[1] + a2[2] + a2[3];
    const float mu = S1 * (1.f / 4096.f);
    const float var = S2 * (1.f / 4096.f) - mu * mu;
    const float rstd = rsqrtf(var + 1e-5f);
    float* orow = out + (size_t)bc * 4096;
    for (int i = threadIdx.x; i < 4096; i += 256) {
        float v = (row[i] - mu) * rstd;
        v = (v >= 0.f) ? v : 0.2f * v;
        orow[i] = v;
    }
}

// ---------------------------------------------------------------------------
// LayerNorm over 64 ch + in_proj (256x64) via MFMA. Block = 32 positions.
// LN'd x -> bf16 LDS tile [32 pos][72 c-pad]; A = wip bf16 [256e][64c].
// Per wave: 4 co-tiles x 2 pos-tiles x 2 kh = 16 MFMA. z staged in LDS,
// written coalesced (fixes R10's stride-512B z stores).
// ---------------------------------------------------------------------------
__global__ __launch_bounds__(256) void ln_inproj_mfma_k(const float* __restrict__ x1,
    const float* __restrict__ g, const float* __restrict__ be,
    const short* __restrict__ wip, float* __restrict__ xin_raw,
    float* __restrict__ z)
{
    const int bx = blockIdx.x;
    const int b = bx >> 7, l0 = (bx & 127) * 32;
    const int t = threadIdx.x;
    __shared__ __align__(16) short ltile[32 * 72];   // [pos][c]
    __shared__ float ztile[32 * 132];                // [pos][d]
    {
        const int j = t & 31, gg = t >> 5;           // pos, c-group
        float xr[64];
        float s1 = 0.f, s2 = 0.f;
#pragma unroll
        for (int c = 0; c < 64; ++c) {
            const float v = x1[(b * 64 + c) * 4096 + l0 + j];
            xr[c] = v; s1 += v; s2 = fmaf(v, v, s2);
        }
        const float mu = s1 * (1.f / 64.f);
        const float var = s2 * (1.f / 64.f) - mu * mu;
        const float rstd = rsqrtf(var + 1e-5f);
#pragma unroll
        for (int i = 0; i < 8; ++i) {
            const int c = gg * 8 + i;
            ltile[j * 72 + c] = f2bf((xr[c] - mu) * rstd * g[c] + be[c]);
        }
    }
    __syncthreads();
    const int lane = t & 63, wv = t >> 6;
    const int n16 = lane & 15, quad = lane >> 4;
    f32x4 acc[4][2];
#pragma unroll
    for (int i = 0; i < 4; ++i)
#pragma unroll
        for (int p = 0; p < 2; ++p) acc[i][p] = (f32x4){0.f, 0.f, 0.f, 0.f};
#pragma unroll
    for (int i = 0; i < 4; ++i) {
        const int cot = wv * 4 + i;                  // co-tile 0..15
#pragma unroll
        for (int kh = 0; kh < 2; ++kh) {
            const bf16x8 a = *(const bf16x8*)(wip +
                (size_t)(cot * 16 + n16) * 64 + kh * 32 + quad * 8);
#pragma unroll
            for (int p = 0; p < 2; ++p) {
                const bf16x8 bb = *(const bf16x8*)&ltile[
                    (p * 16 + n16) * 72 + kh * 32 + quad * 8];
                acc[i][p] = __builtin_amdgcn_mfma_f32_16x16x32_bf16(a, bb, acc[i][p], 0, 0, 0);
            }
        }
    }
#pragma unroll
    for (int i = 0; i < 4; ++i) {
        const int cot = wv * 4 + i;
#pragma unroll
        for (int p = 0; p < 2; ++p) {
            const int pos = p * 16 + n16;
#pragma unroll
            for (int r = 0; r < 4; ++r) {
                const int e = cot * 16 + quad * 4 + r;
                const float v = acc[i][p][r];
                if (e < 128) xin_raw[((size_t)(b * 128 + e)) * 4096 + l0 + pos] = v;
                else ztile[pos * 132 + (e - 128)] = v;
            }
        }
    }
    __syncthreads();
    {
        const int pos = t >> 3, d0 = (t & 7) * 16;
        float* dst = z + ((size_t)(b * 4096 + l0 + pos)) * 128 + d0;
        const float* srcz = ztile + pos * 132 + d0;
#pragma unroll
        for (int q = 0; q < 4; ++q)
            *(float4*)(dst + q * 4) = *(const float4*)(srcz + q * 4);
    }
}

// ---------------------------------------------------------------------------
// Depthwise 3x3 SAME conv + bias + SiLU, fused with spatial transpose.
// Block per (b,d): plane in LDS, writes xin_s (row-major) AND xin_T
// (transposed) from the output tile. Replaces dwconv + transpose kernels.
// ---------------------------------------------------------------------------
__global__ __launch_bounds__(256) void dwconv_silu_T_k(const float* __restrict__ in,
    const float* __restrict__ w, const float* __restrict__ bias,
    float* __restrict__ xin_s, float* __restrict__ xin_T)
{
    const int bd = blockIdx.x;                       // b*128 + d
    const int d = bd & 127;
    const int t = threadIdx.x;
    __shared__ float pin[64 * 65], pout[64 * 65];
    const float* src = in + (size_t)bd * 4096;
#pragma unroll
    for (int i = 0; i < 16; ++i) {
        const int e = i * 256 + t;
        pin[(e >> 6) * 65 + (e & 63)] = src[e];
    }
    __syncthreads();
    const float w0 = w[d * 9 + 0], w1 = w[d * 9 + 1], w2 = w[d * 9 + 2];
    const float w3 = w[d * 9 + 3], w4 = w[d * 9 + 4], w5 = w[d * 9 + 5];
    const float w6 = w[d * 9 + 6], w7 = w[d * 9 + 7], w8 = w[d * 9 + 8];
    const float bv = bias[d];
    float* outs = xin_s + (size_t)bd * 4096;
#pragma unroll
    for (int i = 0; i < 16; ++i) {
        const int e = i * 256 + t;
        const int hh = e >> 6, ww = e & 63;
        float acc = bv;
        const bool h0 = hh > 0, h1 = hh < 63, v0 = ww > 0, v1 = ww < 63;
        const float* rm = pin + (hh - 1) * 65;
        const float* rc = pin + hh * 65;
        const float* rp = pin + (hh + 1) * 65;
        if (h0) {
            if (v0) acc = fmaf(rm[ww - 1], w0, acc);
            acc = fmaf(rm[ww], w1, acc);
            if (v1) acc = fmaf(rm[ww + 1], w2, acc);
        }
        if (v0) acc = fmaf(rc[ww - 1], w3, acc);
        acc = fmaf(rc[ww], w4, acc);
        if (v1) acc = fmaf(rc[ww + 1], w5, acc);
        if (h1) {
            if (v0) acc = fmaf(rp[ww - 1], w6, acc);
            acc = fmaf(rp[ww], w7, acc);
            if (v1) acc = fmaf(rp[ww + 1], w8, acc);
        }
        const float val = acc / (1.f + __expf(-acc));
        pout[hh * 65 + ww] = val;
        outs[e] = val;
    }
    __syncthreads();
    float* outT = xin_T + (size_t)bd * 4096;
#pragma unroll
    for (int i = 0; i < 16; ++i) {
        const int e = i * 256 + t;
        const int wi = e >> 6, hi = e & 63;
        outT[e] = pout[hi * 65 + wi];
    }
}

// ---------------------------------------------------------------------------
// x_dbl[b,k,c,m] = sum_d xs[b,k,d,m] * x_proj_w[k,c,d]  (c=36, scan order m).
// ---------------------------------------------------------------------------
__global__ __launch_bounds__(256) void xdbl_k(const float* __restrict__ xin_s,
    const float* __restrict__ xin_T, const float* __restrict__ xpw,
    float* __restrict__ xdbl)
{
    const int bx = blockIdx.x;
    const int bk = bx >> 7, m0 = (bx & 127) * 32;
    const int b = bk >> 2, k = bk & 3;
    __shared__ float tl[32 * 132];   // [j][d], pad 132
    const float* src = (k & 1) ? xin_T : xin_s;
    const bool rev = (k >= 2);
    for (int e = threadIdx.x; e < 4096; e += 256) {
        const int d = e >> 5, j = e & 31;
        const int m = m0 + j;
        const int um = rev ? (4095 - m) : m;
        tl[j * 132 + d] = src[(b * 128 + d) * 4096 + um];
    }
    __syncthreads();
    const int j = threadIdx.x & 31, c0 = threadIdx.x >> 5;
    const float4* xv4 = (const float4*)(tl + j * 132);
    float acc[5] = {0.f, 0.f, 0.f, 0.f, 0.f};
    for (int d4 = 0; d4 < 32; ++d4) {
        const float4 xv = xv4[d4];
#pragma unroll
        for (int q = 0; q < 5; ++q) {
            const int c = c0 + q * 8;
            if (c < 36) {
                const float4 wv = *(const float4*)&xpw[((size_t)(k * 36 + c)) * 128 + d4 * 4];
                acc[q] = fmaf(xv.x, wv.x, acc[q]);
                acc[q] = fmaf(xv.y, wv.y, acc[q]);
                acc[q] = fmaf(xv.z, wv.z, acc[q]);
                acc[q] = fmaf(xv.w, wv.w, acc[q]);
            }
        }
    }
#pragma unroll
    for (int q = 0; q < 5; ++q) {
        const int c = c0 + q * 8;
        if (c < 36) xdbl[((size_t)bk * 36 + c) * 4096 + m0 + j] = acc[q];
    }
}

// ---------------------------------------------------------------------------
// Segmented scan, phase 1. Two 64-step staging chunks (13KB LDS).
// ---------------------------------------------------------------------------
__global__ __launch_bounds__(256) void scan_p1_k(const float* __restrict__ xdbl,
    const float* __restrict__ xin_s, const float* __restrict__ xin_T,
    const float* __restrict__ A_logs, const float* __restrict__ dtw,
    const float* __restrict__ dtb, float* __restrict__ hseg,
    float* __restrict__ pseg)
{
    const int bx = blockIdx.x;
    const int seg = bx & 31, d8 = (bx >> 5) & 7, bk = bx >> 8;
    const int b = bk >> 2, k = bk & 3;
    const int t = threadIdx.x;
    const int chain = t >> 4, n = t & 15;
    const int d = d8 * 16 + chain;
    const float A = -__expf(A_logs[(k * 128 + d) * 16 + n]);
    __shared__ float sB[16 * 68], sdt[16 * 68], su[16 * 68];
    const float* srcu = (k & 1) ? xin_T : xin_s;
    const bool rev = (k >= 2);
    const int col = t & 63, r0 = t >> 6;
    const int m0 = seg * 128;
    float h = 0.f, pr = 1.f;
    for (int c = 0; c < 2; ++c) {
        const int cb = m0 + c * 64;
        __syncthreads();
        const float dts0 = xdbl[((size_t)bk * 36 + 0) * 4096 + cb + col];
        const float dts1 = xdbl[((size_t)bk * 36 + 1) * 4096 + cb + col];
        const float dts2 = xdbl[((size_t)bk * 36 + 2) * 4096 + cb + col];
        const float dts3 = xdbl[((size_t)bk * 36 + 3) * 4096 + cb + col];
        const int m = cb + col;
        const int um = rev ? (4095 - m) : m;
#pragma unroll
        for (int i = 0; i < 4; ++i) {
            const int nn = r0 + 4 * i;
            sB[nn * 68 + col] = xdbl[((size_t)bk * 36 + 4 + nn) * 4096 + cb + col];
            const int dd = d8 * 16 + nn;
            const float* wp = dtw + (k * 128 + dd) * 4;
            float s = dtb[k * 128 + dd];
            s = fmaf(dts0, wp[0], s);
            s = fmaf(dts1, wp[1], s);
            s = fmaf(dts2, wp[2], s);
            s = fmaf(dts3, wp[3], s);
            sdt[nn * 68 + col] = (s > 20.f) ? s : log1pf(__expf(s));
            su[nn * 68 + col] = srcu[(b * 128 + dd) * 4096 + um];
        }
        __syncthreads();
        const float4* B4  = (const float4*)(sB + n * 68);
        const float4* dt4 = (const float4*)(sdt + chain * 68);
        const float4* u4  = (const float4*)(su + chain * 68);
#pragma unroll 4
        for (int q = 0; q < 16; ++q) {
            const float4 dt = dt4[q], uu = u4[q], BB = B4[q];
            float a;
            a = __expf(dt.x * A); h = fmaf(h, a, dt.x * uu.x * BB.x); pr *= a;
            a = __expf(dt.y * A); h = fmaf(h, a, dt.y * uu.y * BB.y); pr *= a;
            a = __expf(dt.z * A); h = fmaf(h, a, dt.z * uu.z * BB.z); pr *= a;
            a = __expf(dt.w * A); h = fmaf(h, a, dt.w * uu.w * BB.w); pr *= a;
        }
    }
    const size_t idx = (size_t)seg * 32768 + (size_t)(bk * 128 + d) * 16 + n;
    hseg[idx] = h;
    pseg[idx] = pr;
}

// ---------------------------------------------------------------------------
// Combine segment summaries (coalesced). pseg is overwritten with h_start.
// ---------------------------------------------------------------------------
__global__ __launch_bounds__(256) void scan_combine_k(const float* __restrict__ hseg,
                                                      float* __restrict__ pseg)
{
    const int i = blockIdx.x * 256 + threadIdx.x;  // 0..32767
    float h = 0.f;
#pragma unroll 4
    for (int s = 0; s < 32; ++s) {
        const size_t idx = (size_t)s * 32768 + i;
        const float p = pseg[idx];
        const float he = hseg[idx];
        pseg[idx] = h;
        h = fmaf(h, p, he);
    }
}

// ---------------------------------------------------------------------------
// Segmented scan, phase 2. Two 64-step staging chunks (25.6KB LDS, 6 blk/CU).
// Dsum*u folded in-loop (k==0). Direction map applied at store. No atomics.
// ---------------------------------------------------------------------------
__global__ __launch_bounds__(256) void scan_p2_k(const float* __restrict__ xdbl,
    const float* __restrict__ xin_s, const float* __restrict__ xin_T,
    const float* __restrict__ A_logs, const float* __restrict__ dtw,
    const float* __restrict__ dtb, const float* __restrict__ hstart,
    const float* __restrict__ Dsp, float* __restrict__ ybuf)
{
    const int bx = blockIdx.x;
    const int seg = bx & 31, d8 = (bx >> 5) & 7, bk = bx >> 8;
    const int b = bk >> 2, k = bk & 3;
    const int t = threadIdx.x;
    const int chain = t >> 4, n = t & 15;
    const int d = d8 * 16 + chain;
    const float A = -__expf(A_logs[(k * 128 + d) * 16 + n]);
    __shared__ float sB[16 * 68], sC[16 * 68], sdt[16 * 68], su[16 * 68];
    __shared__ float sy[128 * 16];  // [j][dd]
    const float* srcu = (k & 1) ? xin_T : xin_s;
    const bool rev = (k >= 2);
    const int col = t & 63, r0 = t >> 6;
    const int m0 = seg * 128;
    const float Dk0 = (k == 0)
        ? (Dsp[d] + Dsp[128 + d] + Dsp[256 + d] + Dsp[384 + d]) : 0.f;
    float h = hstart[(size_t)seg * 32768 + (size_t)(bk * 128 + d) * 16 + n];
    for (int c = 0; c < 2; ++c) {
        const int cb = m0 + c * 64;
        __syncthreads();
        const float dts0 = xdbl[((size_t)bk * 36 + 0) * 4096 + cb + col];
        const float dts1 = xdbl[((size_t)bk * 36 + 1) * 4096 + cb + col];
        const float dts2 = xdbl[((size_t)bk * 36 + 2) * 4096 + cb + col];
        const float dts3 = xdbl[((size_t)bk * 36 + 3) * 4096 + cb + col];
        const int m = cb + col;
        const int um = rev ? (4095 - m) : m;
#pragma unroll
        for (int i = 0; i < 4; ++i) {
            const int nn = r0 + 4 * i;
            sB[nn * 68 + col] = xdbl[((size_t)bk * 36 + 4 + nn) * 4096 + cb + col];
            sC[nn * 68 + col] = xdbl[((size_t)bk * 36 + 20 + nn) * 4096 + cb + col];
            const int dd = d8 * 16 + nn;
            const float* wp = dtw + (k * 128 + dd) * 4;
            float s = dtb[k * 128 + dd];
            s = fmaf(dts0, wp[0], s);
            s = fmaf(dts1, wp[1], s);
            s = fmaf(dts2, wp[2], s);
            s = fmaf(dts3, wp[3], s);
            sdt[nn * 68 + col] = (s > 20.f) ? s : log1pf(__expf(s));
            su[nn * 68 + col] = srcu[(b * 128 + dd) * 4096 + um];
        }
        __syncthreads();
        const float4* B4  = (const float4*)(sB + n * 68);
        const float4* C4  = (const float4*)(sC + n * 68);
        const float4* dt4 = (const float4*)(sdt + chain * 68);
        const float4* u4  = (const float4*)(su + chain * 68);
#pragma unroll 4
        for (int q = 0; q < 16; ++q) {
            const float4 dt = dt4[q], uu = u4[q], BB = B4[q], CC = C4[q];
            float a, p;
#define SCAN_STEP(E, IDX)                                                     \
            a = __expf(dt.E * A);                                             \
            h = fmaf(h, a, dt.E * uu.E * BB.E);                               \
            p = dpp_sum16(h * CC.E);                                          \
            if (n == 0) {                                                     \
                const int jg = c * 64 + q * 4 + IDX;                          \
                sy[jg * 16 + chain] = fmaf(Dk0, uu.E, p);                     \
            }
            SCAN_STEP(x, 0)
            SCAN_STEP(y, 1)
            SCAN_STEP(z, 2)
            SCAN_STEP(w, 3)
#undef SCAN_STEP
        }
    }
    __syncthreads();
    const int ddl = t & 15;
    const int dg = d8 * 16 + ddl;
    float* yk = ybuf + (size_t)(k * 4 + b) * 4096 * 128;
#pragma unroll
    for (int p2 = 0; p2 < 8; ++p2) {
        const int e = p2 * 256 + t;
        const int j = e >> 4;               // 0..127
        const int m = m0 + j;
        int l;
        if (k == 0) l = m;
        else if (k == 1) l = ((m & 63) << 6) | (m >> 6);
        else if (k == 2) l = 4095 - m;
        else { const int mf = 4095 - m; l = ((mf & 63) << 6) | (mf >> 6); }
        yk[(size_t)l * 128 + dg] = sy[j * 16 + ddl];
    }
}

// ---------------------------------------------------------------------------
// Finalize: v[d] = sum_k ybuf[k][b][l][d]; LN over 128; * silu(z); out_proj
// GEMV; LDS-transposed coalesced store + skip*x1. Block = 32 l, 256 thr.
// ---------------------------------------------------------------------------
__global__ __launch_bounds__(256) void finalize_k(const float* __restrict__ ybuf,
    const float* __restrict__ z, const float* __restrict__ x1,
    const float* __restrict__ ong, const float* __restrict__ onb,
    const float* __restrict__ opw, const float* __restrict__ skipp,
    float* __restrict__ res)
{
    const int bx = blockIdx.x;               // b*128 + tile
    const int b = bx >> 7, l0 = (bx & 127) * 32;
    const int t = threadIdx.x;
    const int j = t & 31, g = t >> 5;        // g 0..7
    const int l = l0 + j;
    const float4* y0p = (const float4*)(ybuf + ((size_t)(0 + b) * 4096 + l) * 128);
    const float4* y1p = (const float4*)(ybuf + ((size_t)(4 + b) * 4096 + l) * 128);
    const float4* y2p = (const float4*)(ybuf + ((size_t)(8 + b) * 4096 + l) * 128);
    const float4* y3p = (const float4*)(ybuf + ((size_t)(12 + b) * 4096 + l) * 128);
    float4 v4[32];
    float s1 = 0.f, s2 = 0.f;
#pragma unroll
    for (int d4 = 0; d4 < 32; ++d4) {
        const float4 a0 = y0p[d4], a1 = y1p[d4], a2 = y2p[d4], a3 = y3p[d4];
        float4 a;
        a.x = (a0.x + a1.x) + (a2.x + a3.x);
        a.y = (a0.y + a1.y) + (a2.y + a3.y);
        a.z = (a0.z + a1.z) + (a2.z + a3.z);
        a.w = (a0.w + a1.w) + (a2.w + a3.w);
        v4[d4] = a;
        s1 += (a.x + a.y) + (a.z + a.w);
        s2 = fmaf(a.x, a.x, s2); s2 = fmaf(a.y, a.y, s2);
        s2 = fmaf(a.z, a.z, s2); s2 = fmaf(a.w, a.w, s2);
    }
    const float mu = s1 * (1.f / 128.f);
    const float var = s2 * (1.f / 128.f) - mu * mu;
    const float rstd = rsqrtf(var + 1e-5f);
    const float4* zp = (const float4*)(z + ((size_t)(b * 4096 + l)) * 128);
    const float4* gp = (const float4*)ong;
    const float4* bp = (const float4*)onb;
#pragma unroll
    for (int d4 = 0; d4 < 32; ++d4) {
        const float4 gg = gp[d4], bb = bp[d4], zz = zp[d4];
        float4 a = v4[d4];
#define GATE(E)                                                               \
        {                                                                     \
            const float yln = (a.E - mu) * rstd * gg.E + bb.E;                \
            a.E = yln * (zz.E / (1.f + __expf(-zz.E)));                       \
        }
        GATE(x) GATE(y) GATE(z) GATE(w)
#undef GATE
        v4[d4] = a;
    }
    float acc[8] = {0.f, 0.f, 0.f, 0.f, 0.f, 0.f, 0.f, 0.f};
    for (int d4 = 0; d4 < 32; ++d4) {
        const float4 a = v4[d4];
#pragma unroll
        for (int q = 0; q < 8; ++q) {
            const float4 wv = *(const float4*)&opw[(size_t)(g * 8 + q) * 128 + d4 * 4];
            acc[q] = fmaf(a.x, wv.x, acc[q]);
            acc[q] = fmaf(a.y, wv.y, acc[q]);
            acc[q] = fmaf(a.z, wv.z, acc[q]);
            acc[q] = fmaf(a.w, wv.w, acc[q]);
        }
    }
    __shared__ float sres[64 * 33];
#pragma unroll
    for (int q = 0; q < 8; ++q) sres[(g * 8 + q) * 33 + j] = acc[q];
    __syncthreads();
    const float sk = skipp[0];
    for (int e = t; e < 2048; e += 256) {
        const int co = e >> 5, jj = e & 31;
        const size_t o = ((size_t)(b * 64 + co)) * 4096 + l0 + jj;
        res[o] = sres[co * 33 + jj] + sk * x1[o];
    }
}

// ---------------------------------------------------------------------------
// Workspace layout (floats), total 20,267,008 floats = 77.3 MB:
//   x1 @0 (1M), xin_s @1M (2M), zbuf @3M (2M), xin_T @5M (2M),
//   xdbl @7,340,032 (2,359,296), ybuf @9,699,328 (8,388,608, [k][b][l][d]),
//   G @18,087,936 (2M): xin_raw / hseg+pseg / res+tmp + conv chain,
//   wbf @20,185,088 (81,920 floats = 163,840 bf16: 4 convs + in_proj)
// ---------------------------------------------------------------------------
extern "C" void kernel_launch(void* const* d_in, const int* in_sizes, int n_in,
                              void* d_out, int out_size, void* d_ws, size_t ws_size,
                              hipStream_t stream)
{
    const float* x          = (const float*)d_in[0];
    const float* conv1_w    = (const float*)d_in[1];
    const float* conv1_b    = (const float*)d_in[2];
    const float* conv2_w    = (const float*)d_in[3];
    const float* conv2_b    = (const float*)d_in[4];
    const float* cf_w       = (const float*)d_in[5];
    const float* cf_b       = (const float*)d_in[6];
    const float* ln_g       = (const float*)d_in[7];
    const float* ln_b       = (const float*)d_in[8];
    const float* in_proj_w  = (const float*)d_in[9];
    const float* dw_w       = (const float*)d_in[10];
    const float* dw_b       = (const float*)d_in[11];
    const float* x_proj_w   = (const float*)d_in[12];
    const float* dt_proj_w  = (const float*)d_in[13];
    const float* dt_proj_b  = (const float*)d_in[14];
    const float* A_logs     = (const float*)d_in[15];
    const float* Ds         = (const float*)d_in[16];
    const float* out_norm_g = (const float*)d_in[17];
    const float* out_norm_b = (const float*)d_in[18];
    const float* out_proj_w = (const float*)d_in[19];
    const float* skip_scale = (const float*)d_in[20];
    const float* cb_w       = (const float*)d_in[21];
    const float* cb_b       = (const float*)d_in[22];

    float* ws = (float*)d_ws;
    float* x1    = ws;                 // 1,048,576
    float* xin_s = ws + 1048576;       // 2,097,152
    float* zbuf  = ws + 3145728;       // 2,097,152
    float* xin_T = ws + 5242880;       // 2,097,152
    float* xdbl  = ws + 7340032;       // 2,359,296
    float* ybuf  = ws + 9699328;       // 8,388,608
    float* G     = ws + 18087936;      // 2,097,152 scratch
    float* G0 = G;
    float* G1 = G + 1048576;
    short* wbf  = (short*)(ws + 20185088);  // 163,840 bf16
    short* wbf1 = wbf;                       // conv1
    short* wbf2 = wbf + 36864;               // conv2
    short* wbf3 = wbf + 73728;               // cf
    short* wbf4 = wbf + 110592;              // cb
    short* wip  = wbf + 147456;              // in_proj [256e][64c]

    wconv_k<<<640, 256, 0, stream>>>(conv1_w, conv2_w, cf_w, cb_w, in_proj_w, wbf);

    conv3x3_mfma_k<<<256, 256, 0, stream>>>(x, wbf1, conv1_b, nullptr, G0);
    inorm_lrelu_k<<<256, 256, 0, stream>>>(G0, G1);
    conv3x3_mfma_k<<<256, 256, 0, stream>>>(G1, wbf2, conv2_b, nullptr, G0);
    conv3x3_mfma_k<<<256, 256, 0, stream>>>(G0, wbf3, cf_b, nullptr, x1);
    ln_inproj_mfma_k<<<512, 256, 0, stream>>>(x1, ln_g, ln_b, wip, G /*xin_raw*/, zbuf);
    dwconv_silu_T_k<<<512, 256, 0, stream>>>(G /*xin_raw*/, dw_w, dw_b, xin_s, xin_T);
    xdbl_k<<<2048, 256, 0, stream>>>(xin_s, xin_T, x_proj_w, xdbl);
    scan_p1_k<<<4096, 256, 0, stream>>>(xdbl, xin_s, xin_T, A_logs, dt_proj_w,
                                        dt_proj_b, G0 /*hseg*/, G1 /*pseg*/);
    scan_combine_k<<<128, 256, 0, stream>>>(G0 /*hseg*/, G1 /*pseg->hstart*/);
    scan_p2_k<<<4096, 256, 0, stream>>>(xdbl, xin_s, xin_T, A_logs, dt_proj_w,
                                        dt_proj_b, G1 /*hstart*/, Ds, ybuf);
    finalize_k<<<512, 256, 0, stream>>>(ybuf, zbuf, x1, out_norm_g, out_norm_b,
                                        out_proj_w, skip_scale, G0 /*res*/);
    conv3x3_mfma_k<<<256, 256, 0, stream>>>(G0 /*res*/, wbf4, cb_b, x1, G1 /*tmp*/);
    inorm_lrelu_k<<<256, 256, 0, stream>>>(G1 /*tmp*/, (float*)d_out);
}

// Round 12
// 393.382 us; speedup vs baseline: 5.9091x; 1.0501x over previous
//
#include <hip/hip_runtime.h>
#include <hip/hip_bf16.h>

// All inputs/outputs are float32 (per the reference file's setup_inputs).

typedef __attribute__((ext_vector_type(8))) short bf16x8;
typedef __attribute__((ext_vector_type(8))) unsigned short u16x8;
typedef __attribute__((ext_vector_type(4))) float f32x4;

static __device__ __forceinline__ short f2bf(float f)
{
    unsigned u = __float_as_uint(f);
    unsigned r = u + 0x7FFFu + ((u >> 16) & 1u);   // RNE
    return (short)(r >> 16);
}
static __device__ __forceinline__ float b2f(unsigned short s)
{
    return __uint_as_float((unsigned)s << 16);
}

// 16-lane butterfly sum via DPP (VALU, no DS-pipe traffic).
static __device__ __forceinline__ float dpp_sum16(float x)
{
    x += __int_as_float(__builtin_amdgcn_update_dpp(
        0, __float_as_int(x), 0xB1, 0xF, 0xF, true));   // quad_perm [1,0,3,2]
    x += __int_as_float(__builtin_amdgcn_update_dpp(
        0, __float_as_int(x), 0x4E, 0xF, 0xF, true));   // quad_perm [2,3,0,1]
    x += __int_as_float(__builtin_amdgcn_update_dpp(
        0, __float_as_int(x), 0x141, 0xF, 0xF, true));  // row_half_mirror
    x += __int_as_float(__builtin_amdgcn_update_dpp(
        0, __float_as_int(x), 0x140, 0xF, 0xF, true));  // row_mirror
    return x;
}

// ---------------------------------------------------------------------------
// Weight conversion: 4 conv sets [64co][64ci][3][3] -> wbf[conv][tap][co][ci]
// + in_proj_w [256e][64c] -> wip (bf16, same layout). 163840 elems total.
// ---------------------------------------------------------------------------
__global__ __launch_bounds__(256) void wconv_k(const float* __restrict__ w1,
    const float* __restrict__ w2, const float* __restrict__ w3,
    const float* __restrict__ w4, const float* __restrict__ ipw,
    short* __restrict__ wbf)
{
    const int idx = blockIdx.x * 256 + threadIdx.x;  // 0..163839
    if (idx < 147456) {
        const int c = idx / 36864, rem = idx % 36864;
        const int tap = rem >> 12, r2 = rem & 4095;
        const int co = r2 >> 6, ci = r2 & 63;
        const float* src = (c == 0) ? w1 : (c == 1) ? w2 : (c == 2) ? w3 : w4;
        wbf[idx] = f2bf(src[(co * 64 + ci) * 9 + tap]);
    } else {
        const int i2 = idx - 147456;                 // 0..16383, [e][c]
        wbf[idx] = f2bf(ipw[i2]);
    }
}

// ---------------------------------------------------------------------------
// MFMA 3x3 SAME conv, 64->64 ch, NCHW. Block = one (b,h) row, 256 threads.
// R12: single-pass staging (zeros written inline for missing h rows; only
// pad columns w=0/65 get a dedicated zero) -> one __syncthreads, no full
// LDS-clear pass.
// ---------------------------------------------------------------------------
__global__ __launch_bounds__(256) void conv3x3_mfma_k(const float* __restrict__ in,
    const short* __restrict__ wtap, const float* __restrict__ bias,
    const float* __restrict__ addsrc, float* __restrict__ out)
{
    const int bh = blockIdx.x;
    const int b = bh >> 6, h = bh & 63;
    const int t = threadIdx.x;
    __shared__ __align__(16) short lin[3 * 66 * 72];  // [r][w+1][ci]
    {
        const int ci = t >> 2, w16 = (t & 3) * 16;
#pragma unroll
        for (int r = 0; r < 3; ++r) {
            const int hh = h - 1 + r;
            const bool ok = (hh >= 0 && hh < 64);
            const float* src = in + ((size_t)(b * 64 + ci) * 64 + (ok ? hh : 0)) * 64 + w16;
#pragma unroll
            for (int q = 0; q < 4; ++q) {
                float4 v = make_float4(0.f, 0.f, 0.f, 0.f);
                if (ok) v = *(const float4*)(src + q * 4);
                const int wb = w16 + q * 4;
                lin[(r * 66 + wb + 1) * 72 + ci] = f2bf(v.x);
                lin[(r * 66 + wb + 2) * 72 + ci] = f2bf(v.y);
                lin[(r * 66 + wb + 3) * 72 + ci] = f2bf(v.z);
                lin[(r * 66 + wb + 4) * 72 + ci] = f2bf(v.w);
            }
        }
        // pad columns w=0 and w=65: 3 r x 2 cols x 72 ci shorts = 216 ints
        if (t < 216) {
            const int r3 = t / 72, rem = t % 72;
            const int colp = (rem >= 36) ? 65 : 0, ci2 = rem % 36;
            ((int*)lin)[(r3 * 66 + colp) * 36 + ci2] = 0;
        }
    }
    __syncthreads();
    const int lane = t & 63, ct = t >> 6;     // wave = co-tile
    const int n16 = lane & 15, quad = lane >> 4;
    f32x4 acc0 = {0.f, 0.f, 0.f, 0.f};
    f32x4 acc1 = {0.f, 0.f, 0.f, 0.f};
    f32x4 acc2 = {0.f, 0.f, 0.f, 0.f};
    f32x4 acc3 = {0.f, 0.f, 0.f, 0.f};
#pragma unroll
    for (int tap = 0; tap < 9; ++tap) {
        const int dy = tap / 3, dx = tap % 3;
#pragma unroll
        for (int kh = 0; kh < 2; ++kh) {
            const int kk = kh * 32;
            const bf16x8 a = *(const bf16x8*)(wtap +
                ((size_t)tap * 64 + ct * 16 + n16) * 64 + kk + quad * 8);
            const int rb = (dy * 66 + n16 + dx) * 72 + kk + quad * 8;
            const bf16x8 b0 = *(const bf16x8*)&lin[rb + 0 * 16 * 72];
            const bf16x8 b1 = *(const bf16x8*)&lin[rb + 1 * 16 * 72];
            const bf16x8 b2 = *(const bf16x8*)&lin[rb + 2 * 16 * 72];
            const bf16x8 b3 = *(const bf16x8*)&lin[rb + 3 * 16 * 72];
            acc0 = __builtin_amdgcn_mfma_f32_16x16x32_bf16(a, b0, acc0, 0, 0, 0);
            acc1 = __builtin_amdgcn_mfma_f32_16x16x32_bf16(a, b1, acc1, 0, 0, 0);
            acc2 = __builtin_amdgcn_mfma_f32_16x16x32_bf16(a, b2, acc2, 0, 0, 0);
            acc3 = __builtin_amdgcn_mfma_f32_16x16x32_bf16(a, b3, acc3, 0, 0, 0);
        }
    }
#pragma unroll
    for (int r = 0; r < 4; ++r) {
        const int co = ct * 16 + quad * 4 + r;
        const float bv = bias[co];
        float* orow = out + ((size_t)(b * 64 + co) * 64 + h) * 64;
        float v0 = acc0[r] + bv, v1 = acc1[r] + bv, v2 = acc2[r] + bv, v3 = acc3[r] + bv;
        if (addsrc) {
            const float* arow = addsrc + ((size_t)(b * 64 + co) * 64 + h) * 64;
            v0 += arow[n16]; v1 += arow[16 + n16];
            v2 += arow[32 + n16]; v3 += arow[48 + n16];
        }
        orow[n16] = v0; orow[16 + n16] = v1;
        orow[32 + n16] = v2; orow[48 + n16] = v3;
    }
}

// ---------------------------------------------------------------------------
// InstanceNorm over HxW per (b,c) + LeakyReLU(0.2). Block per (b,c).
// ---------------------------------------------------------------------------
__global__ __launch_bounds__(256) void inorm_lrelu_k(const float* __restrict__ in,
                                                     float* __restrict__ out)
{
    const int bc = blockIdx.x;
    const float* row = in + (size_t)bc * 4096;
    float s1 = 0.f, s2 = 0.f;
    for (int i = threadIdx.x; i < 4096; i += 256) {
        const float v = row[i];
        s1 += v; s2 = fmaf(v, v, s2);
    }
#pragma unroll
    for (int mk = 1; mk < 64; mk <<= 1) {
        s1 += __shfl_xor(s1, mk, 64);
        s2 += __shfl_xor(s2, mk, 64);
    }
    __shared__ float a1[4], a2[4];
    const int wid = threadIdx.x >> 6;
    if ((threadIdx.x & 63) == 0) { a1[wid] = s1; a2[wid] = s2; }
    __syncthreads();
    const float S1 = a1[0] + a1[1] + a1[2] + a1[3];
    const float S2 = a2[0] + a2[1] + a2[2] + a2[3];
    const float mu = S1 * (1.f / 4096.f);
    const float var = S2 * (1.f / 4096.f) - mu * mu;
    const float rstd = rsqrtf(var + 1e-5f);
    float* orow = out + (size_t)bc * 4096;
    for (int i = threadIdx.x; i < 4096; i += 256) {
        float v = (row[i] - mu) * rstd;
        v = (v >= 0.f) ? v : 0.2f * v;
        orow[i] = v;
    }
}

// ---------------------------------------------------------------------------
// LayerNorm over 64 ch + in_proj (256x64) via MFMA. Block = 32 positions.
// ---------------------------------------------------------------------------
__global__ __launch_bounds__(256) void ln_inproj_mfma_k(const float* __restrict__ x1,
    const float* __restrict__ g, const float* __restrict__ be,
    const short* __restrict__ wip, float* __restrict__ xin_raw,
    float* __restrict__ z)
{
    const int bx = blockIdx.x;
    const int b = bx >> 7, l0 = (bx & 127) * 32;
    const int t = threadIdx.x;
    __shared__ __align__(16) short ltile[32 * 72];   // [pos][c]
    __shared__ float ztile[32 * 132];                // [pos][d]
    {
        const int j = t & 31, gg = t >> 5;           // pos, c-group
        float xr[64];
        float s1 = 0.f, s2 = 0.f;
#pragma unroll
        for (int c = 0; c < 64; ++c) {
            const float v = x1[(b * 64 + c) * 4096 + l0 + j];
            xr[c] = v; s1 += v; s2 = fmaf(v, v, s2);
        }
        const float mu = s1 * (1.f / 64.f);
        const float var = s2 * (1.f / 64.f) - mu * mu;
        const float rstd = rsqrtf(var + 1e-5f);
#pragma unroll
        for (int i = 0; i < 8; ++i) {
            const int c = gg * 8 + i;
            ltile[j * 72 + c] = f2bf((xr[c] - mu) * rstd * g[c] + be[c]);
        }
    }
    __syncthreads();
    const int lane = t & 63, wv = t >> 6;
    const int n16 = lane & 15, quad = lane >> 4;
    f32x4 acc[4][2];
#pragma unroll
    for (int i = 0; i < 4; ++i)
#pragma unroll
        for (int p = 0; p < 2; ++p) acc[i][p] = (f32x4){0.f, 0.f, 0.f, 0.f};
#pragma unroll
    for (int i = 0; i < 4; ++i) {
        const int cot = wv * 4 + i;                  // co-tile 0..15
#pragma unroll
        for (int kh = 0; kh < 2; ++kh) {
            const bf16x8 a = *(const bf16x8*)(wip +
                (size_t)(cot * 16 + n16) * 64 + kh * 32 + quad * 8);
#pragma unroll
            for (int p = 0; p < 2; ++p) {
                const bf16x8 bb = *(const bf16x8*)&ltile[
                    (p * 16 + n16) * 72 + kh * 32 + quad * 8];
                acc[i][p] = __builtin_amdgcn_mfma_f32_16x16x32_bf16(a, bb, acc[i][p], 0, 0, 0);
            }
        }
    }
#pragma unroll
    for (int i = 0; i < 4; ++i) {
        const int cot = wv * 4 + i;
#pragma unroll
        for (int p = 0; p < 2; ++p) {
            const int pos = p * 16 + n16;
#pragma unroll
            for (int r = 0; r < 4; ++r) {
                const int e = cot * 16 + quad * 4 + r;
                const float v = acc[i][p][r];
                if (e < 128) xin_raw[((size_t)(b * 128 + e)) * 4096 + l0 + pos] = v;
                else ztile[pos * 132 + (e - 128)] = v;
            }
        }
    }
    __syncthreads();
    {
        const int pos = t >> 3, d0 = (t & 7) * 16;
        float* dst = z + ((size_t)(b * 4096 + l0 + pos)) * 128 + d0;
        const float* srcz = ztile + pos * 132 + d0;
#pragma unroll
        for (int q = 0; q < 4; ++q)
            *(float4*)(dst + q * 4) = *(const float4*)(srcz + q * 4);
    }
}

// ---------------------------------------------------------------------------
// Depthwise 3x3 SAME conv + bias + SiLU, fused with spatial transpose.
// ---------------------------------------------------------------------------
__global__ __launch_bounds__(256) void dwconv_silu_T_k(const float* __restrict__ in,
    const float* __restrict__ w, const float* __restrict__ bias,
    float* __restrict__ xin_s, float* __restrict__ xin_T)
{
    const int bd = blockIdx.x;                       // b*128 + d
    const int d = bd & 127;
    const int t = threadIdx.x;
    __shared__ float pin[64 * 65], pout[64 * 65];
    const float* src = in + (size_t)bd * 4096;
#pragma unroll
    for (int i = 0; i < 16; ++i) {
        const int e = i * 256 + t;
        pin[(e >> 6) * 65 + (e & 63)] = src[e];
    }
    __syncthreads();
    const float w0 = w[d * 9 + 0], w1 = w[d * 9 + 1], w2 = w[d * 9 + 2];
    const float w3 = w[d * 9 + 3], w4 = w[d * 9 + 4], w5 = w[d * 9 + 5];
    const float w6 = w[d * 9 + 6], w7 = w[d * 9 + 7], w8 = w[d * 9 + 8];
    const float bv = bias[d];
    float* outs = xin_s + (size_t)bd * 4096;
#pragma unroll
    for (int i = 0; i < 16; ++i) {
        const int e = i * 256 + t;
        const int hh = e >> 6, ww = e & 63;
        float acc = bv;
        const bool h0 = hh > 0, h1 = hh < 63, v0 = ww > 0, v1 = ww < 63;
        const float* rm = pin + (hh - 1) * 65;
        const float* rc = pin + hh * 65;
        const float* rp = pin + (hh + 1) * 65;
        if (h0) {
            if (v0) acc = fmaf(rm[ww - 1], w0, acc);
            acc = fmaf(rm[ww], w1, acc);
            if (v1) acc = fmaf(rm[ww + 1], w2, acc);
        }
        if (v0) acc = fmaf(rc[ww - 1], w3, acc);
        acc = fmaf(rc[ww], w4, acc);
        if (v1) acc = fmaf(rc[ww + 1], w5, acc);
        if (h1) {
            if (v0) acc = fmaf(rp[ww - 1], w6, acc);
            acc = fmaf(rp[ww], w7, acc);
            if (v1) acc = fmaf(rp[ww + 1], w8, acc);
        }
        const float val = acc / (1.f + __expf(-acc));
        pout[hh * 65 + ww] = val;
        outs[e] = val;
    }
    __syncthreads();
    float* outT = xin_T + (size_t)bd * 4096;
#pragma unroll
    for (int i = 0; i < 16; ++i) {
        const int e = i * 256 + t;
        const int wi = e >> 6, hi = e & 63;
        outT[e] = pout[hi * 65 + wi];
    }
}

// ---------------------------------------------------------------------------
// x_dbl[b,k,c,m] = sum_d xs[b,k,d,m] * x_proj_w[k,c,d]  (c=36, scan order m).
// ---------------------------------------------------------------------------
__global__ __launch_bounds__(256) void xdbl_k(const float* __restrict__ xin_s,
    const float* __restrict__ xin_T, const float* __restrict__ xpw,
    float* __restrict__ xdbl)
{
    const int bx = blockIdx.x;
    const int bk = bx >> 7, m0 = (bx & 127) * 32;
    const int b = bk >> 2, k = bk & 3;
    __shared__ float tl[32 * 132];   // [j][d], pad 132
    const float* src = (k & 1) ? xin_T : xin_s;
    const bool rev = (k >= 2);
    for (int e = threadIdx.x; e < 4096; e += 256) {
        const int d = e >> 5, j = e & 31;
        const int m = m0 + j;
        const int um = rev ? (4095 - m) : m;
        tl[j * 132 + d] = src[(b * 128 + d) * 4096 + um];
    }
    __syncthreads();
    const int j = threadIdx.x & 31, c0 = threadIdx.x >> 5;
    const float4* xv4 = (const float4*)(tl + j * 132);
    float acc[5] = {0.f, 0.f, 0.f, 0.f, 0.f};
    for (int d4 = 0; d4 < 32; ++d4) {
        const float4 xv = xv4[d4];
#pragma unroll
        for (int q = 0; q < 5; ++q) {
            const int c = c0 + q * 8;
            if (c < 36) {
                const float4 wv = *(const float4*)&xpw[((size_t)(k * 36 + c)) * 128 + d4 * 4];
                acc[q] = fmaf(xv.x, wv.x, acc[q]);
                acc[q] = fmaf(xv.y, wv.y, acc[q]);
                acc[q] = fmaf(xv.z, wv.z, acc[q]);
                acc[q] = fmaf(xv.w, wv.w, acc[q]);
            }
        }
    }
#pragma unroll
    for (int q = 0; q < 5; ++q) {
        const int c = c0 + q * 8;
        if (c < 36) xdbl[((size_t)bk * 36 + c) * 4096 + m0 + j] = acc[q];
    }
}

// ---------------------------------------------------------------------------
// Segmented scan, phase 1. R12: stage du = dt*u (saves one v_mul/step in the
// issue-bound inner loop). Two 64-step chunks (13KB LDS).
// ---------------------------------------------------------------------------
__global__ __launch_bounds__(256) void scan_p1_k(const float* __restrict__ xdbl,
    const float* __restrict__ xin_s, const float* __restrict__ xin_T,
    const float* __restrict__ A_logs, const float* __restrict__ dtw,
    const float* __restrict__ dtb, float* __restrict__ hseg,
    float* __restrict__ pseg)
{
    const int bx = blockIdx.x;
    const int seg = bx & 31, d8 = (bx >> 5) & 7, bk = bx >> 8;
    const int b = bk >> 2, k = bk & 3;
    const int t = threadIdx.x;
    const int chain = t >> 4, n = t & 15;
    const int d = d8 * 16 + chain;
    const float A = -__expf(A_logs[(k * 128 + d) * 16 + n]);
    __shared__ float sB[16 * 68], sdt[16 * 68], sdu[16 * 68];
    const float* srcu = (k & 1) ? xin_T : xin_s;
    const bool rev = (k >= 2);
    const int col = t & 63, r0 = t >> 6;
    const int m0 = seg * 128;
    float h = 0.f, pr = 1.f;
    for (int c = 0; c < 2; ++c) {
        const int cb = m0 + c * 64;
        __syncthreads();
        const float dts0 = xdbl[((size_t)bk * 36 + 0) * 4096 + cb + col];
        const float dts1 = xdbl[((size_t)bk * 36 + 1) * 4096 + cb + col];
        const float dts2 = xdbl[((size_t)bk * 36 + 2) * 4096 + cb + col];
        const float dts3 = xdbl[((size_t)bk * 36 + 3) * 4096 + cb + col];
        const int m = cb + col;
        const int um = rev ? (4095 - m) : m;
#pragma unroll
        for (int i = 0; i < 4; ++i) {
            const int nn = r0 + 4 * i;
            sB[nn * 68 + col] = xdbl[((size_t)bk * 36 + 4 + nn) * 4096 + cb + col];
            const int dd = d8 * 16 + nn;
            const float* wp = dtw + (k * 128 + dd) * 4;
            float s = dtb[k * 128 + dd];
            s = fmaf(dts0, wp[0], s);
            s = fmaf(dts1, wp[1], s);
            s = fmaf(dts2, wp[2], s);
            s = fmaf(dts3, wp[3], s);
            const float sp = (s > 20.f) ? s : log1pf(__expf(s));
            sdt[nn * 68 + col] = sp;
            sdu[nn * 68 + col] = sp * srcu[(b * 128 + dd) * 4096 + um];
        }
        __syncthreads();
        const float4* B4  = (const float4*)(sB + n * 68);
        const float4* dt4 = (const float4*)(sdt + chain * 68);
        const float4* du4 = (const float4*)(sdu + chain * 68);
#pragma unroll 4
        for (int q = 0; q < 16; ++q) {
            const float4 dt = dt4[q], du = du4[q], BB = B4[q];
            float a;
            a = __expf(dt.x * A); h = fmaf(h, a, du.x * BB.x); pr *= a;
            a = __expf(dt.y * A); h = fmaf(h, a, du.y * BB.y); pr *= a;
            a = __expf(dt.z * A); h = fmaf(h, a, du.z * BB.z); pr *= a;
            a = __expf(dt.w * A); h = fmaf(h, a, du.w * BB.w); pr *= a;
        }
    }
    const size_t idx = (size_t)seg * 32768 + (size_t)(bk * 128 + d) * 16 + n;
    hseg[idx] = h;
    pseg[idx] = pr;
}

// ---------------------------------------------------------------------------
// Combine segment summaries (coalesced). pseg is overwritten with h_start.
// ---------------------------------------------------------------------------
__global__ __launch_bounds__(256) void scan_combine_k(const float* __restrict__ hseg,
                                                      float* __restrict__ pseg)
{
    const int i = blockIdx.x * 256 + threadIdx.x;  // 0..32767
    float h = 0.f;
#pragma unroll 4
    for (int s = 0; s < 32; ++s) {
        const size_t idx = (size_t)s * 32768 + i;
        const float p = pseg[idx];
        const float he = hseg[idx];
        pseg[idx] = h;
        h = fmaf(h, p, he);
    }
}

// ---------------------------------------------------------------------------
// Segmented scan, phase 2. R12: k!=0 blocks stage du = dt*u (one fewer
// v_mul/step); k==0 keeps u for the Dsum fold. ybuf stored as bf16
// (halves WRITE_SIZE + finalize's read). No atomics.
// ---------------------------------------------------------------------------
__global__ __launch_bounds__(256) void scan_p2_k(const float* __restrict__ xdbl,
    const float* __restrict__ xin_s, const float* __restrict__ xin_T,
    const float* __restrict__ A_logs, const float* __restrict__ dtw,
    const float* __restrict__ dtb, const float* __restrict__ hstart,
    const float* __restrict__ Dsp, unsigned short* __restrict__ ybuf)
{
    const int bx = blockIdx.x;
    const int seg = bx & 31, d8 = (bx >> 5) & 7, bk = bx >> 8;
    const int b = bk >> 2, k = bk & 3;
    const int t = threadIdx.x;
    const int chain = t >> 4, n = t & 15;
    const int d = d8 * 16 + chain;
    const float A = -__expf(A_logs[(k * 128 + d) * 16 + n]);
    __shared__ float sB[16 * 68], sC[16 * 68], sdt[16 * 68], su[16 * 68];
    __shared__ float sy[128 * 16];  // [j][dd]
    const float* srcu = (k & 1) ? xin_T : xin_s;
    const bool rev = (k >= 2);
    const int col = t & 63, r0 = t >> 6;
    const int m0 = seg * 128;
    const float Dk0 = (k == 0)
        ? (Dsp[d] + Dsp[128 + d] + Dsp[256 + d] + Dsp[384 + d]) : 0.f;
    float h = hstart[(size_t)seg * 32768 + (size_t)(bk * 128 + d) * 16 + n];
    for (int c = 0; c < 2; ++c) {
        const int cb = m0 + c * 64;
        __syncthreads();
        const float dts0 = xdbl[((size_t)bk * 36 + 0) * 4096 + cb + col];
        const float dts1 = xdbl[((size_t)bk * 36 + 1) * 4096 + cb + col];
        const float dts2 = xdbl[((size_t)bk * 36 + 2) * 4096 + cb + col];
        const float dts3 = xdbl[((size_t)bk * 36 + 3) * 4096 + cb + col];
        const int m = cb + col;
        const int um = rev ? (4095 - m) : m;
#pragma unroll
        for (int i = 0; i < 4; ++i) {
            const int nn = r0 + 4 * i;
            sB[nn * 68 + col] = xdbl[((size_t)bk * 36 + 4 + nn) * 4096 + cb + col];
            sC[nn * 68 + col] = xdbl[((size_t)bk * 36 + 20 + nn) * 4096 + cb + col];
            const int dd = d8 * 16 + nn;
            const float* wp = dtw + (k * 128 + dd) * 4;
            float s = dtb[k * 128 + dd];
            s = fmaf(dts0, wp[0], s);
            s = fmaf(dts1, wp[1], s);
            s = fmaf(dts2, wp[2], s);
            s = fmaf(dts3, wp[3], s);
            const float sp = (s > 20.f) ? s : log1pf(__expf(s));
            sdt[nn * 68 + col] = sp;
            const float uval = srcu[(b * 128 + dd) * 4096 + um];
            su[nn * 68 + col] = (k == 0) ? uval : sp * uval;   // u or du
        }
        __syncthreads();
        const float4* B4  = (const float4*)(sB + n * 68);
        const float4* C4  = (const float4*)(sC + n * 68);
        const float4* dt4 = (const float4*)(sdt + chain * 68);
        const float4* u4  = (const float4*)(su + chain * 68);
        if (k == 0) {
#pragma unroll 4
            for (int q = 0; q < 16; ++q) {
                const float4 dt = dt4[q], uu = u4[q], BB = B4[q], CC = C4[q];
                float a, p;
#define SCAN_STEP(E, IDX)                                                     \
                a = __expf(dt.E * A);                                         \
                h = fmaf(h, a, dt.E * uu.E * BB.E);                           \
                p = dpp_sum16(h * CC.E);                                      \
                if (n == 0) {                                                 \
                    const int jg = c * 64 + q * 4 + IDX;                      \
                    sy[jg * 16 + chain] = fmaf(Dk0, uu.E, p);                 \
                }
                SCAN_STEP(x, 0)
                SCAN_STEP(y, 1)
                SCAN_STEP(z, 2)
                SCAN_STEP(w, 3)
#undef SCAN_STEP
            }
        } else {
#pragma unroll 4
            for (int q = 0; q < 16; ++q) {
                const float4 dt = dt4[q], du = u4[q], BB = B4[q], CC = C4[q];
                float a, p;
#define SCAN_STEP(E, IDX)                                                     \
                a = __expf(dt.E * A);                                         \
                h = fmaf(h, a, du.E * BB.E);                                  \
                p = dpp_sum16(h * CC.E);                                      \
                if (n == 0) {                                                 \
                    const int jg = c * 64 + q * 4 + IDX;                      \
                    sy[jg * 16 + chain] = p;                                  \
                }
                SCAN_STEP(x, 0)
                SCAN_STEP(y, 1)
                SCAN_STEP(z, 2)
                SCAN_STEP(w, 3)
#undef SCAN_STEP
            }
        }
    }
    __syncthreads();
    const int ddl = t & 15;
    const int dg = d8 * 16 + ddl;
    unsigned short* yk = ybuf + (size_t)(k * 4 + b) * 4096 * 128;
#pragma unroll
    for (int p2 = 0; p2 < 8; ++p2) {
        const int e = p2 * 256 + t;
        const int j = e >> 4;               // 0..127
        const int m = m0 + j;
        int l;
        if (k == 0) l = m;
        else if (k == 1) l = ((m & 63) << 6) | (m >> 6);
        else if (k == 2) l = 4095 - m;
        else { const int mf = 4095 - m; l = ((mf & 63) << 6) | (mf >> 6); }
        yk[(size_t)l * 128 + dg] = (unsigned short)f2bf(sy[j * 16 + ddl]);
    }
}

// ---------------------------------------------------------------------------
// Finalize: v[d] = sum_k ybuf[k][b][l][d] (bf16); LN over 128; * silu(z);
// out_proj GEMV; LDS-transposed coalesced store + skip*x1. Block = 32 l.
// ---------------------------------------------------------------------------
__global__ __launch_bounds__(256) void finalize_k(const unsigned short* __restrict__ ybuf,
    const float* __restrict__ z, const float* __restrict__ x1,
    const float* __restrict__ ong, const float* __restrict__ onb,
    const float* __restrict__ opw, const float* __restrict__ skipp,
    float* __restrict__ res)
{
    const int bx = blockIdx.x;               // b*128 + tile
    const int b = bx >> 7, l0 = (bx & 127) * 32;
    const int t = threadIdx.x;
    const int j = t & 31, g = t >> 5;        // g 0..7
    const int l = l0 + j;
    const u16x8* y0p = (const u16x8*)(ybuf + ((size_t)(0 + b) * 4096 + l) * 128);
    const u16x8* y1p = (const u16x8*)(ybuf + ((size_t)(4 + b) * 4096 + l) * 128);
    const u16x8* y2p = (const u16x8*)(ybuf + ((size_t)(8 + b) * 4096 + l) * 128);
    const u16x8* y3p = (const u16x8*)(ybuf + ((size_t)(12 + b) * 4096 + l) * 128);
    float vr[128];
    float s1 = 0.f, s2 = 0.f;
#pragma unroll
    for (int g8 = 0; g8 < 16; ++g8) {
        const u16x8 a0 = y0p[g8], a1 = y1p[g8], a2 = y2p[g8], a3 = y3p[g8];
#pragma unroll
        for (int e = 0; e < 8; ++e) {
            const float f = (b2f(a0[e]) + b2f(a1[e])) + (b2f(a2[e]) + b2f(a3[e]));
            vr[g8 * 8 + e] = f;
            s1 += f; s2 = fmaf(f, f, s2);
        }
    }
    const float mu = s1 * (1.f / 128.f);
    const float var = s2 * (1.f / 128.f) - mu * mu;
    const float rstd = rsqrtf(var + 1e-5f);
    const float4* zp = (const float4*)(z + ((size_t)(b * 4096 + l)) * 128);
    const float4* gp = (const float4*)ong;
    const float4* bp = (const float4*)onb;
#pragma unroll
    for (int d4 = 0; d4 < 32; ++d4) {
        const float4 gg = gp[d4], bb = bp[d4], zz = zp[d4];
#define GATE(E, IDX)                                                          \
        {                                                                     \
            const float yln = (vr[d4 * 4 + IDX] - mu) * rstd * gg.E + bb.E;   \
            vr[d4 * 4 + IDX] = yln * (zz.E / (1.f + __expf(-zz.E)));          \
        }
        GATE(x, 0) GATE(y, 1) GATE(z, 2) GATE(w, 3)
#undef GATE
    }
    float acc[8] = {0.f, 0.f, 0.f, 0.f, 0.f, 0.f, 0.f, 0.f};
    for (int d4 = 0; d4 < 32; ++d4) {
#pragma unroll
        for (int q = 0; q < 8; ++q) {
            const float4 wv = *(const float4*)&opw[(size_t)(g * 8 + q) * 128 + d4 * 4];
            acc[q] = fmaf(vr[d4 * 4 + 0], wv.x, acc[q]);
            acc[q] = fmaf(vr[d4 * 4 + 1], wv.y, acc[q]);
            acc[q] = fmaf(vr[d4 * 4 + 2], wv.z, acc[q]);
            acc[q] = fmaf(vr[d4 * 4 + 3], wv.w, acc[q]);
        }
    }
    __shared__ float sres[64 * 33];
#pragma unroll
    for (int q = 0; q < 8; ++q) sres[(g * 8 + q) * 33 + j] = acc[q];
    __syncthreads();
    const float sk = skipp[0];
    for (int e = t; e < 2048; e += 256) {
        const int co = e >> 5, jj = e & 31;
        const size_t o = ((size_t)(b * 64 + co)) * 4096 + l0 + jj;
        res[o] = sres[co * 33 + jj] + sk * x1[o];
    }
}

// ---------------------------------------------------------------------------
// Workspace layout (floats), total 20,267,008 floats = 77.3 MB:
//   x1 @0 (1M), xin_s @1M (2M), zbuf @3M (2M), xin_T @5M (2M),
//   xdbl @7,340,032 (2,359,296), ybuf @9,699,328 (bf16 now: uses 4M of 8M),
//   G @18,087,936 (2M): xin_raw / hseg+pseg / res+tmp,
//   wbf @20,185,088 (81,920 floats = 163,840 bf16: 4 convs + in_proj)
// ---------------------------------------------------------------------------
extern "C" void kernel_launch(void* const* d_in, const int* in_sizes, int n_in,
                              void* d_out, int out_size, void* d_ws, size_t ws_size,
                              hipStream_t stream)
{
    const float* x          = (const float*)d_in[0];
    const float* conv1_w    = (const float*)d_in[1];
    const float* conv1_b    = (const float*)d_in[2];
    const float* conv2_w    = (const float*)d_in[3];
    const float* conv2_b    = (const float*)d_in[4];
    const float* cf_w       = (const float*)d_in[5];
    const float* cf_b       = (const float*)d_in[6];
    const float* ln_g       = (const float*)d_in[7];
    const float* ln_b       = (const float*)d_in[8];
    const float* in_proj_w  = (const float*)d_in[9];
    const float* dw_w       = (const float*)d_in[10];
    const float* dw_b       = (const float*)d_in[11];
    const float* x_proj_w   = (const float*)d_in[12];
    const float* dt_proj_w  = (const float*)d_in[13];
    const float* dt_proj_b  = (const float*)d_in[14];
    const float* A_logs     = (const float*)d_in[15];
    const float* Ds         = (const float*)d_in[16];
    const float* out_norm_g = (const float*)d_in[17];
    const float* out_norm_b = (const float*)d_in[18];
    const float* out_proj_w = (const float*)d_in[19];
    const float* skip_scale = (const float*)d_in[20];
    const float* cb_w       = (const float*)d_in[21];
    const float* cb_b       = (const float*)d_in[22];

    float* ws = (float*)d_ws;
    float* x1    = ws;                 // 1,048,576
    float* xin_s = ws + 1048576;       // 2,097,152
    float* zbuf  = ws + 3145728;       // 2,097,152
    float* xin_T = ws + 5242880;       // 2,097,152
    float* xdbl  = ws + 7340032;       // 2,359,296
    unsigned short* ybuf = (unsigned short*)(ws + 9699328);  // bf16 [k][b][l][d]
    float* G     = ws + 18087936;      // 2,097,152 scratch
    float* G0 = G;
    float* G1 = G + 1048576;
    short* wbf  = (short*)(ws + 20185088);  // 163,840 bf16
    short* wbf1 = wbf;                       // conv1
    short* wbf2 = wbf + 36864;               // conv2
    short* wbf3 = wbf + 73728;               // cf
    short* wbf4 = wbf + 110592;              // cb
    short* wip  = wbf + 147456;              // in_proj [256e][64c]

    wconv_k<<<640, 256, 0, stream>>>(conv1_w, conv2_w, cf_w, cb_w, in_proj_w, wbf);

    conv3x3_mfma_k<<<256, 256, 0, stream>>>(x, wbf1, conv1_b, nullptr, G0);
    inorm_lrelu_k<<<256, 256, 0, stream>>>(G0, G1);
    conv3x3_mfma_k<<<256, 256, 0, stream>>>(G1, wbf2, conv2_b, nullptr, G0);
    conv3x3_mfma_k<<<256, 256, 0, stream>>>(G0, wbf3, cf_b, nullptr, x1);
    ln_inproj_mfma_k<<<512, 256, 0, stream>>>(x1, ln_g, ln_b, wip, G /*xin_raw*/, zbuf);
    dwconv_silu_T_k<<<512, 256, 0, stream>>>(G /*xin_raw*/, dw_w, dw_b, xin_s, xin_T);
    xdbl_k<<<2048, 256, 0, stream>>>(xin_s, xin_T, x_proj_w, xdbl);
    scan_p1_k<<<4096, 256, 0, stream>>>(xdbl, xin_s, xin_T, A_logs, dt_proj_w,
                                        dt_proj_b, G0 /*hseg*/, G1 /*pseg*/);
    scan_combine_k<<<128, 256, 0, stream>>>(G0 /*hseg*/, G1 /*pseg->hstart*/);
    scan_p2_k<<<4096, 256, 0, stream>>>(xdbl, xin_s, xin_T, A_logs, dt_proj_w,
                                        dt_proj_b, G1 /*hstart*/, Ds, ybuf);
    finalize_k<<<512, 256, 0, stream>>>(ybuf, zbuf, x1, out_norm_g, out_norm_b,
                                        out_proj_w, skip_scale, G0 /*res*/);
    conv3x3_mfma_k<<<256, 256, 0, stream>>>(G0 /*res*/, wbf4, cb_b, x1, G1 /*tmp*/);
    inorm_lrelu_k<<<256, 256, 0, stream>>>(G1 /*tmp*/, (float*)d_out);
}

// Round 13
// 383.977 us; speedup vs baseline: 6.0538x; 1.0245x over previous
//
#include <hip/hip_runtime.h>
#include <hip/hip_bf16.h>

// All inputs/outputs are float32 (per the reference file's setup_inputs).

typedef __attribute__((ext_vector_type(8))) short bf16x8;
typedef __attribute__((ext_vector_type(8))) unsigned short u16x8;
typedef __attribute__((ext_vector_type(4))) float f32x4;

static __device__ __forceinline__ short f2bf(float f)
{
    unsigned u = __float_as_uint(f);
    unsigned r = u + 0x7FFFu + ((u >> 16) & 1u);   // RNE
    return (short)(r >> 16);
}
static __device__ __forceinline__ float b2f(unsigned short s)
{
    return __uint_as_float((unsigned)s << 16);
}

// 16-lane butterfly sum via DPP (VALU, no DS-pipe traffic).
static __device__ __forceinline__ float dpp_sum16(float x)
{
    x += __int_as_float(__builtin_amdgcn_update_dpp(
        0, __float_as_int(x), 0xB1, 0xF, 0xF, true));   // quad_perm [1,0,3,2]
    x += __int_as_float(__builtin_amdgcn_update_dpp(
        0, __float_as_int(x), 0x4E, 0xF, 0xF, true));   // quad_perm [2,3,0,1]
    x += __int_as_float(__builtin_amdgcn_update_dpp(
        0, __float_as_int(x), 0x141, 0xF, 0xF, true));  // row_half_mirror
    x += __int_as_float(__builtin_amdgcn_update_dpp(
        0, __float_as_int(x), 0x140, 0xF, 0xF, true));  // row_mirror
    return x;
}

// ---------------------------------------------------------------------------
// Weight conversion: 4 conv sets [64co][64ci][3][3] -> wbf[conv][tap][co][ci]
// + in_proj_w [256e][64c] -> wip (bf16, same layout). 163840 elems total.
// ---------------------------------------------------------------------------
__global__ __launch_bounds__(256) void wconv_k(const float* __restrict__ w1,
    const float* __restrict__ w2, const float* __restrict__ w3,
    const float* __restrict__ w4, const float* __restrict__ ipw,
    short* __restrict__ wbf)
{
    const int idx = blockIdx.x * 256 + threadIdx.x;  // 0..163839
    if (idx < 147456) {
        const int c = idx / 36864, rem = idx % 36864;
        const int tap = rem >> 12, r2 = rem & 4095;
        const int co = r2 >> 6, ci = r2 & 63;
        const float* src = (c == 0) ? w1 : (c == 1) ? w2 : (c == 2) ? w3 : w4;
        wbf[idx] = f2bf(src[(co * 64 + ci) * 9 + tap]);
    } else {
        const int i2 = idx - 147456;                 // 0..16383, [e][c]
        wbf[idx] = f2bf(ipw[i2]);
    }
}

// ---------------------------------------------------------------------------
// MFMA 3x3 SAME conv, 64->64 ch, NCHW. Block = one (b,h) row, 256 threads.
// Single-pass staging; only pad columns get a dedicated zero.
// ---------------------------------------------------------------------------
__global__ __launch_bounds__(256) void conv3x3_mfma_k(const float* __restrict__ in,
    const short* __restrict__ wtap, const float* __restrict__ bias,
    const float* __restrict__ addsrc, float* __restrict__ out)
{
    const int bh = blockIdx.x;
    const int b = bh >> 6, h = bh & 63;
    const int t = threadIdx.x;
    __shared__ __align__(16) short lin[3 * 66 * 72];  // [r][w+1][ci]
    {
        const int ci = t >> 2, w16 = (t & 3) * 16;
#pragma unroll
        for (int r = 0; r < 3; ++r) {
            const int hh = h - 1 + r;
            const bool ok = (hh >= 0 && hh < 64);
            const float* src = in + ((size_t)(b * 64 + ci) * 64 + (ok ? hh : 0)) * 64 + w16;
#pragma unroll
            for (int q = 0; q < 4; ++q) {
                float4 v = make_float4(0.f, 0.f, 0.f, 0.f);
                if (ok) v = *(const float4*)(src + q * 4);
                const int wb = w16 + q * 4;
                lin[(r * 66 + wb + 1) * 72 + ci] = f2bf(v.x);
                lin[(r * 66 + wb + 2) * 72 + ci] = f2bf(v.y);
                lin[(r * 66 + wb + 3) * 72 + ci] = f2bf(v.z);
                lin[(r * 66 + wb + 4) * 72 + ci] = f2bf(v.w);
            }
        }
        // pad columns w=0 and w=65: 3 r x 2 cols x 72 ci shorts = 216 ints
        if (t < 216) {
            const int r3 = t / 72, rem = t % 72;
            const int colp = (rem >= 36) ? 65 : 0, ci2 = rem % 36;
            ((int*)lin)[(r3 * 66 + colp) * 36 + ci2] = 0;
        }
    }
    __syncthreads();
    const int lane = t & 63, ct = t >> 6;     // wave = co-tile
    const int n16 = lane & 15, quad = lane >> 4;
    f32x4 acc0 = {0.f, 0.f, 0.f, 0.f};
    f32x4 acc1 = {0.f, 0.f, 0.f, 0.f};
    f32x4 acc2 = {0.f, 0.f, 0.f, 0.f};
    f32x4 acc3 = {0.f, 0.f, 0.f, 0.f};
#pragma unroll
    for (int tap = 0; tap < 9; ++tap) {
        const int dy = tap / 3, dx = tap % 3;
#pragma unroll
        for (int kh = 0; kh < 2; ++kh) {
            const int kk = kh * 32;
            const bf16x8 a = *(const bf16x8*)(wtap +
                ((size_t)tap * 64 + ct * 16 + n16) * 64 + kk + quad * 8);
            const int rb = (dy * 66 + n16 + dx) * 72 + kk + quad * 8;
            const bf16x8 b0 = *(const bf16x8*)&lin[rb + 0 * 16 * 72];
            const bf16x8 b1 = *(const bf16x8*)&lin[rb + 1 * 16 * 72];
            const bf16x8 b2 = *(const bf16x8*)&lin[rb + 2 * 16 * 72];
            const bf16x8 b3 = *(const bf16x8*)&lin[rb + 3 * 16 * 72];
            acc0 = __builtin_amdgcn_mfma_f32_16x16x32_bf16(a, b0, acc0, 0, 0, 0);
            acc1 = __builtin_amdgcn_mfma_f32_16x16x32_bf16(a, b1, acc1, 0, 0, 0);
            acc2 = __builtin_amdgcn_mfma_f32_16x16x32_bf16(a, b2, acc2, 0, 0, 0);
            acc3 = __builtin_amdgcn_mfma_f32_16x16x32_bf16(a, b3, acc3, 0, 0, 0);
        }
    }
#pragma unroll
    for (int r = 0; r < 4; ++r) {
        const int co = ct * 16 + quad * 4 + r;
        const float bv = bias[co];
        float* orow = out + ((size_t)(b * 64 + co) * 64 + h) * 64;
        float v0 = acc0[r] + bv, v1 = acc1[r] + bv, v2 = acc2[r] + bv, v3 = acc3[r] + bv;
        if (addsrc) {
            const float* arow = addsrc + ((size_t)(b * 64 + co) * 64 + h) * 64;
            v0 += arow[n16]; v1 += arow[16 + n16];
            v2 += arow[32 + n16]; v3 += arow[48 + n16];
        }
        orow[n16] = v0; orow[16 + n16] = v1;
        orow[32 + n16] = v2; orow[48 + n16] = v3;
    }
}

// ---------------------------------------------------------------------------
// InstanceNorm over HxW per (b,c) + LeakyReLU(0.2). Block per (b,c).
// ---------------------------------------------------------------------------
__global__ __launch_bounds__(256) void inorm_lrelu_k(const float* __restrict__ in,
                                                     float* __restrict__ out)
{
    const int bc = blockIdx.x;
    const float* row = in + (size_t)bc * 4096;
    float s1 = 0.f, s2 = 0.f;
    for (int i = threadIdx.x; i < 4096; i += 256) {
        const float v = row[i];
        s1 += v; s2 = fmaf(v, v, s2);
    }
#pragma unroll
    for (int mk = 1; mk < 64; mk <<= 1) {
        s1 += __shfl_xor(s1, mk, 64);
        s2 += __shfl_xor(s2, mk, 64);
    }
    __shared__ float a1[4], a2[4];
    const int wid = threadIdx.x >> 6;
    if ((threadIdx.x & 63) == 0) { a1[wid] = s1; a2[wid] = s2; }
    __syncthreads();
    const float S1 = a1[0] + a1[1] + a1[2] + a1[3];
    const float S2 = a2[0] + a2[1] + a2[2] + a2[3];
    const float mu = S1 * (1.f / 4096.f);
    const float var = S2 * (1.f / 4096.f) - mu * mu;
    const float rstd = rsqrtf(var + 1e-5f);
    float* orow = out + (size_t)bc * 4096;
    for (int i = threadIdx.x; i < 4096; i += 256) {
        float v = (row[i] - mu) * rstd;
        v = (v >= 0.f) ? v : 0.2f * v;
        orow[i] = v;
    }
}

// ---------------------------------------------------------------------------
// LayerNorm over 64 ch + in_proj (256x64) via MFMA. Block = 32 positions.
// R13: ztile pad 132 -> 140 (bank stride 12 mod 32 -> 2-way = free; was 8-way).
// ---------------------------------------------------------------------------
__global__ __launch_bounds__(256) void ln_inproj_mfma_k(const float* __restrict__ x1,
    const float* __restrict__ g, const float* __restrict__ be,
    const short* __restrict__ wip, float* __restrict__ xin_raw,
    float* __restrict__ z)
{
    const int bx = blockIdx.x;
    const int b = bx >> 7, l0 = (bx & 127) * 32;
    const int t = threadIdx.x;
    __shared__ __align__(16) short ltile[32 * 72];   // [pos][c]
    __shared__ float ztile[32 * 140];                // [pos][d], pad 140
    {
        const int j = t & 31, gg = t >> 5;           // pos, c-group
        float xr[64];
        float s1 = 0.f, s2 = 0.f;
#pragma unroll
        for (int c = 0; c < 64; ++c) {
            const float v = x1[(b * 64 + c) * 4096 + l0 + j];
            xr[c] = v; s1 += v; s2 = fmaf(v, v, s2);
        }
        const float mu = s1 * (1.f / 64.f);
        const float var = s2 * (1.f / 64.f) - mu * mu;
        const float rstd = rsqrtf(var + 1e-5f);
#pragma unroll
        for (int i = 0; i < 8; ++i) {
            const int c = gg * 8 + i;
            ltile[j * 72 + c] = f2bf((xr[c] - mu) * rstd * g[c] + be[c]);
        }
    }
    __syncthreads();
    const int lane = t & 63, wv = t >> 6;
    const int n16 = lane & 15, quad = lane >> 4;
    f32x4 acc[4][2];
#pragma unroll
    for (int i = 0; i < 4; ++i)
#pragma unroll
        for (int p = 0; p < 2; ++p) acc[i][p] = (f32x4){0.f, 0.f, 0.f, 0.f};
#pragma unroll
    for (int i = 0; i < 4; ++i) {
        const int cot = wv * 4 + i;                  // co-tile 0..15
#pragma unroll
        for (int kh = 0; kh < 2; ++kh) {
            const bf16x8 a = *(const bf16x8*)(wip +
                (size_t)(cot * 16 + n16) * 64 + kh * 32 + quad * 8);
#pragma unroll
            for (int p = 0; p < 2; ++p) {
                const bf16x8 bb = *(const bf16x8*)&ltile[
                    (p * 16 + n16) * 72 + kh * 32 + quad * 8];
                acc[i][p] = __builtin_amdgcn_mfma_f32_16x16x32_bf16(a, bb, acc[i][p], 0, 0, 0);
            }
        }
    }
#pragma unroll
    for (int i = 0; i < 4; ++i) {
        const int cot = wv * 4 + i;
#pragma unroll
        for (int p = 0; p < 2; ++p) {
            const int pos = p * 16 + n16;
#pragma unroll
            for (int r = 0; r < 4; ++r) {
                const int e = cot * 16 + quad * 4 + r;
                const float v = acc[i][p][r];
                if (e < 128) xin_raw[((size_t)(b * 128 + e)) * 4096 + l0 + pos] = v;
                else ztile[pos * 140 + (e - 128)] = v;
            }
        }
    }
    __syncthreads();
    {
        const int pos = t >> 3, d0 = (t & 7) * 16;
        float* dst = z + ((size_t)(b * 4096 + l0 + pos)) * 128 + d0;
        const float* srcz = ztile + pos * 140 + d0;
#pragma unroll
        for (int q = 0; q < 4; ++q)
            *(float4*)(dst + q * 4) = *(const float4*)(srcz + q * 4);
    }
}

// ---------------------------------------------------------------------------
// Depthwise 3x3 SAME conv + bias + SiLU, fused with spatial transpose.
// ---------------------------------------------------------------------------
__global__ __launch_bounds__(256) void dwconv_silu_T_k(const float* __restrict__ in,
    const float* __restrict__ w, const float* __restrict__ bias,
    float* __restrict__ xin_s, float* __restrict__ xin_T)
{
    const int bd = blockIdx.x;                       // b*128 + d
    const int d = bd & 127;
    const int t = threadIdx.x;
    __shared__ float pin[64 * 65], pout[64 * 65];
    const float* src = in + (size_t)bd * 4096;
#pragma unroll
    for (int i = 0; i < 16; ++i) {
        const int e = i * 256 + t;
        pin[(e >> 6) * 65 + (e & 63)] = src[e];
    }
    __syncthreads();
    const float w0 = w[d * 9 + 0], w1 = w[d * 9 + 1], w2 = w[d * 9 + 2];
    const float w3 = w[d * 9 + 3], w4 = w[d * 9 + 4], w5 = w[d * 9 + 5];
    const float w6 = w[d * 9 + 6], w7 = w[d * 9 + 7], w8 = w[d * 9 + 8];
    const float bv = bias[d];
    float* outs = xin_s + (size_t)bd * 4096;
#pragma unroll
    for (int i = 0; i < 16; ++i) {
        const int e = i * 256 + t;
        const int hh = e >> 6, ww = e & 63;
        float acc = bv;
        const bool h0 = hh > 0, h1 = hh < 63, v0 = ww > 0, v1 = ww < 63;
        const float* rm = pin + (hh - 1) * 65;
        const float* rc = pin + hh * 65;
        const float* rp = pin + (hh + 1) * 65;
        if (h0) {
            if (v0) acc = fmaf(rm[ww - 1], w0, acc);
            acc = fmaf(rm[ww], w1, acc);
            if (v1) acc = fmaf(rm[ww + 1], w2, acc);
        }
        if (v0) acc = fmaf(rc[ww - 1], w3, acc);
        acc = fmaf(rc[ww], w4, acc);
        if (v1) acc = fmaf(rc[ww + 1], w5, acc);
        if (h1) {
            if (v0) acc = fmaf(rp[ww - 1], w6, acc);
            acc = fmaf(rp[ww], w7, acc);
            if (v1) acc = fmaf(rp[ww + 1], w8, acc);
        }
        const float val = acc / (1.f + __expf(-acc));
        pout[hh * 65 + ww] = val;
        outs[e] = val;
    }
    __syncthreads();
    float* outT = xin_T + (size_t)bd * 4096;
#pragma unroll
    for (int i = 0; i < 16; ++i) {
        const int e = i * 256 + t;
        const int wi = e >> 6, hi = e & 63;
        outT[e] = pout[hi * 65 + wi];
    }
}

// ---------------------------------------------------------------------------
// x_dbl[b,k,c,m] = sum_d xs[b,k,d,m] * x_proj_w[k,c,d]  (c=36, scan order m).
// ---------------------------------------------------------------------------
__global__ __launch_bounds__(256) void xdbl_k(const float* __restrict__ xin_s,
    const float* __restrict__ xin_T, const float* __restrict__ xpw,
    float* __restrict__ xdbl)
{
    const int bx = blockIdx.x;
    const int bk = bx >> 7, m0 = (bx & 127) * 32;
    const int b = bk >> 2, k = bk & 3;
    __shared__ float tl[32 * 132];   // [j][d], pad 132
    const float* src = (k & 1) ? xin_T : xin_s;
    const bool rev = (k >= 2);
    for (int e = threadIdx.x; e < 4096; e += 256) {
        const int d = e >> 5, j = e & 31;
        const int m = m0 + j;
        const int um = rev ? (4095 - m) : m;
        tl[j * 132 + d] = src[(b * 128 + d) * 4096 + um];
    }
    __syncthreads();
    const int j = threadIdx.x & 31, c0 = threadIdx.x >> 5;
    const float4* xv4 = (const float4*)(tl + j * 132);
    float acc[5] = {0.f, 0.f, 0.f, 0.f, 0.f};
    for (int d4 = 0; d4 < 32; ++d4) {
        const float4 xv = xv4[d4];
#pragma unroll
        for (int q = 0; q < 5; ++q) {
            const int c = c0 + q * 8;
            if (c < 36) {
                const float4 wv = *(const float4*)&xpw[((size_t)(k * 36 + c)) * 128 + d4 * 4];
                acc[q] = fmaf(xv.x, wv.x, acc[q]);
                acc[q] = fmaf(xv.y, wv.y, acc[q]);
                acc[q] = fmaf(xv.z, wv.z, acc[q]);
                acc[q] = fmaf(xv.w, wv.w, acc[q]);
            }
        }
    }
#pragma unroll
    for (int q = 0; q < 5; ++q) {
        const int c = c0 + q * 8;
        if (c < 36) xdbl[((size_t)bk * 36 + c) * 4096 + m0 + j] = acc[q];
    }
}

// ---------------------------------------------------------------------------
// Segmented scan, phase 1. R13: SEG=64 (64 segments x 64 steps) -> 8192
// blocks, half the serial depth, single staging chunk (13KB LDS).
// ---------------------------------------------------------------------------
__global__ __launch_bounds__(256) void scan_p1_k(const float* __restrict__ xdbl,
    const float* __restrict__ xin_s, const float* __restrict__ xin_T,
    const float* __restrict__ A_logs, const float* __restrict__ dtw,
    const float* __restrict__ dtb, float* __restrict__ hseg,
    float* __restrict__ pseg)
{
    const int bx = blockIdx.x;
    const int seg = bx & 63, d8 = (bx >> 6) & 7, bk = bx >> 9;
    const int b = bk >> 2, k = bk & 3;
    const int t = threadIdx.x;
    const int chain = t >> 4, n = t & 15;
    const int d = d8 * 16 + chain;
    const float A = -__expf(A_logs[(k * 128 + d) * 16 + n]);
    __shared__ float sB[16 * 68], sdt[16 * 68], sdu[16 * 68];
    const float* srcu = (k & 1) ? xin_T : xin_s;
    const bool rev = (k >= 2);
    const int col = t & 63, r0 = t >> 6;
    const int m0 = seg * 64;
    {
        const float dts0 = xdbl[((size_t)bk * 36 + 0) * 4096 + m0 + col];
        const float dts1 = xdbl[((size_t)bk * 36 + 1) * 4096 + m0 + col];
        const float dts2 = xdbl[((size_t)bk * 36 + 2) * 4096 + m0 + col];
        const float dts3 = xdbl[((size_t)bk * 36 + 3) * 4096 + m0 + col];
        const int m = m0 + col;
        const int um = rev ? (4095 - m) : m;
#pragma unroll
        for (int i = 0; i < 4; ++i) {
            const int nn = r0 + 4 * i;
            sB[nn * 68 + col] = xdbl[((size_t)bk * 36 + 4 + nn) * 4096 + m0 + col];
            const int dd = d8 * 16 + nn;
            const float* wp = dtw + (k * 128 + dd) * 4;
            float s = dtb[k * 128 + dd];
            s = fmaf(dts0, wp[0], s);
            s = fmaf(dts1, wp[1], s);
            s = fmaf(dts2, wp[2], s);
            s = fmaf(dts3, wp[3], s);
            const float sp = (s > 20.f) ? s : log1pf(__expf(s));
            sdt[nn * 68 + col] = sp;
            sdu[nn * 68 + col] = sp * srcu[(b * 128 + dd) * 4096 + um];
        }
    }
    __syncthreads();
    const float4* B4  = (const float4*)(sB + n * 68);
    const float4* dt4 = (const float4*)(sdt + chain * 68);
    const float4* du4 = (const float4*)(sdu + chain * 68);
    float h = 0.f, pr = 1.f;
#pragma unroll 4
    for (int q = 0; q < 16; ++q) {
        const float4 dt = dt4[q], du = du4[q], BB = B4[q];
        float a;
        a = __expf(dt.x * A); h = fmaf(h, a, du.x * BB.x); pr *= a;
        a = __expf(dt.y * A); h = fmaf(h, a, du.y * BB.y); pr *= a;
        a = __expf(dt.z * A); h = fmaf(h, a, du.z * BB.z); pr *= a;
        a = __expf(dt.w * A); h = fmaf(h, a, du.w * BB.w); pr *= a;
    }
    const size_t idx = (size_t)seg * 32768 + (size_t)(bk * 128 + d) * 16 + n;
    hseg[idx] = h;
    pseg[idx] = pr;
}

// ---------------------------------------------------------------------------
// Combine segment summaries (coalesced), 64 links. pseg -> h_start in place.
// ---------------------------------------------------------------------------
__global__ __launch_bounds__(256) void scan_combine_k(const float* __restrict__ hseg,
                                                      float* __restrict__ pseg)
{
    const int i = blockIdx.x * 256 + threadIdx.x;  // 0..32767
    float h = 0.f;
#pragma unroll 4
    for (int s = 0; s < 64; ++s) {
        const size_t idx = (size_t)s * 32768 + i;
        const float p = pseg[idx];
        const float he = hseg[idx];
        pseg[idx] = h;
        h = fmaf(h, p, he);
    }
}

// ---------------------------------------------------------------------------
// Segmented scan, phase 2. R13: SEG=64 -> 8192 blocks, 21.25KB LDS
// (~7 blocks/CU), half serial depth. bf16 ybuf stores at output l. No atomics.
// ---------------------------------------------------------------------------
__global__ __launch_bounds__(256) void scan_p2_k(const float* __restrict__ xdbl,
    const float* __restrict__ xin_s, const float* __restrict__ xin_T,
    const float* __restrict__ A_logs, const float* __restrict__ dtw,
    const float* __restrict__ dtb, const float* __restrict__ hstart,
    const float* __restrict__ Dsp, unsigned short* __restrict__ ybuf)
{
    const int bx = blockIdx.x;
    const int seg = bx & 63, d8 = (bx >> 6) & 7, bk = bx >> 9;
    const int b = bk >> 2, k = bk & 3;
    const int t = threadIdx.x;
    const int chain = t >> 4, n = t & 15;
    const int d = d8 * 16 + chain;
    const float A = -__expf(A_logs[(k * 128 + d) * 16 + n]);
    __shared__ float sB[16 * 68], sC[16 * 68], sdt[16 * 68], su[16 * 68];
    __shared__ float sy[64 * 16];   // [j][dd]
    const float* srcu = (k & 1) ? xin_T : xin_s;
    const bool rev = (k >= 2);
    const int col = t & 63, r0 = t >> 6;
    const int m0 = seg * 64;
    const float Dk0 = (k == 0)
        ? (Dsp[d] + Dsp[128 + d] + Dsp[256 + d] + Dsp[384 + d]) : 0.f;
    float h = hstart[(size_t)seg * 32768 + (size_t)(bk * 128 + d) * 16 + n];
    {
        const float dts0 = xdbl[((size_t)bk * 36 + 0) * 4096 + m0 + col];
        const float dts1 = xdbl[((size_t)bk * 36 + 1) * 4096 + m0 + col];
        const float dts2 = xdbl[((size_t)bk * 36 + 2) * 4096 + m0 + col];
        const float dts3 = xdbl[((size_t)bk * 36 + 3) * 4096 + m0 + col];
        const int m = m0 + col;
        const int um = rev ? (4095 - m) : m;
#pragma unroll
        for (int i = 0; i < 4; ++i) {
            const int nn = r0 + 4 * i;
            sB[nn * 68 + col] = xdbl[((size_t)bk * 36 + 4 + nn) * 4096 + m0 + col];
            sC[nn * 68 + col] = xdbl[((size_t)bk * 36 + 20 + nn) * 4096 + m0 + col];
            const int dd = d8 * 16 + nn;
            const float* wp = dtw + (k * 128 + dd) * 4;
            float s = dtb[k * 128 + dd];
            s = fmaf(dts0, wp[0], s);
            s = fmaf(dts1, wp[1], s);
            s = fmaf(dts2, wp[2], s);
            s = fmaf(dts3, wp[3], s);
            const float sp = (s > 20.f) ? s : log1pf(__expf(s));
            sdt[nn * 68 + col] = sp;
            const float uval = srcu[(b * 128 + dd) * 4096 + um];
            su[nn * 68 + col] = (k == 0) ? uval : sp * uval;   // u or du
        }
    }
    __syncthreads();
    const float4* B4  = (const float4*)(sB + n * 68);
    const float4* C4  = (const float4*)(sC + n * 68);
    const float4* dt4 = (const float4*)(sdt + chain * 68);
    const float4* u4  = (const float4*)(su + chain * 68);
    if (k == 0) {
#pragma unroll 4
        for (int q = 0; q < 16; ++q) {
            const float4 dt = dt4[q], uu = u4[q], BB = B4[q], CC = C4[q];
            float a, p;
#define SCAN_STEP(E, IDX)                                                     \
            a = __expf(dt.E * A);                                             \
            h = fmaf(h, a, dt.E * uu.E * BB.E);                               \
            p = dpp_sum16(h * CC.E);                                          \
            if (n == 0) {                                                     \
                const int jg = q * 4 + IDX;                                   \
                sy[jg * 16 + chain] = fmaf(Dk0, uu.E, p);                     \
            }
            SCAN_STEP(x, 0)
            SCAN_STEP(y, 1)
            SCAN_STEP(z, 2)
            SCAN_STEP(w, 3)
#undef SCAN_STEP
        }
    } else {
#pragma unroll 4
        for (int q = 0; q < 16; ++q) {
            const float4 dt = dt4[q], du = u4[q], BB = B4[q], CC = C4[q];
            float a, p;
#define SCAN_STEP(E, IDX)                                                     \
            a = __expf(dt.E * A);                                             \
            h = fmaf(h, a, du.E * BB.E);                                      \
            p = dpp_sum16(h * CC.E);                                          \
            if (n == 0) {                                                     \
                const int jg = q * 4 + IDX;                                   \
                sy[jg * 16 + chain] = p;                                      \
            }
            SCAN_STEP(x, 0)
            SCAN_STEP(y, 1)
            SCAN_STEP(z, 2)
            SCAN_STEP(w, 3)
#undef SCAN_STEP
        }
    }
    __syncthreads();
    const int ddl = t & 15;
    const int dg = d8 * 16 + ddl;
    unsigned short* yk = ybuf + (size_t)(k * 4 + b) * 4096 * 128;
#pragma unroll
    for (int p2 = 0; p2 < 4; ++p2) {
        const int e = p2 * 256 + t;
        const int j = e >> 4;               // 0..63
        const int m = m0 + j;
        int l;
        if (k == 0) l = m;
        else if (k == 1) l = ((m & 63) << 6) | (m >> 6);
        else if (k == 2) l = 4095 - m;
        else { const int mf = 4095 - m; l = ((mf & 63) << 6) | (mf >> 6); }
        yk[(size_t)l * 128 + dg] = (unsigned short)f2bf(sy[j * 16 + ddl]);
    }
}

// ---------------------------------------------------------------------------
// Finalize: v[d] = sum_k ybuf[k][b][l][d] (bf16); LN over 128; * silu(z);
// out_proj GEMV; LDS-transposed coalesced store + skip*x1. Block = 32 l.
// ---------------------------------------------------------------------------
__global__ __launch_bounds__(256) void finalize_k(const unsigned short* __restrict__ ybuf,
    const float* __restrict__ z, const float* __restrict__ x1,
    const float* __restrict__ ong, const float* __restrict__ onb,
    const float* __restrict__ opw, const float* __restrict__ skipp,
    float* __restrict__ res)
{
    const int bx = blockIdx.x;               // b*128 + tile
    const int b = bx >> 7, l0 = (bx & 127) * 32;
    const int t = threadIdx.x;
    const int j = t & 31, g = t >> 5;        // g 0..7
    const int l = l0 + j;
    const u16x8* y0p = (const u16x8*)(ybuf + ((size_t)(0 + b) * 4096 + l) * 128);
    const u16x8* y1p = (const u16x8*)(ybuf + ((size_t)(4 + b) * 4096 + l) * 128);
    const u16x8* y2p = (const u16x8*)(ybuf + ((size_t)(8 + b) * 4096 + l) * 128);
    const u16x8* y3p = (const u16x8*)(ybuf + ((size_t)(12 + b) * 4096 + l) * 128);
    float vr[128];
    float s1 = 0.f, s2 = 0.f;
#pragma unroll
    for (int g8 = 0; g8 < 16; ++g8) {
        const u16x8 a0 = y0p[g8], a1 = y1p[g8], a2 = y2p[g8], a3 = y3p[g8];
#pragma unroll
        for (int e = 0; e < 8; ++e) {
            const float f = (b2f(a0[e]) + b2f(a1[e])) + (b2f(a2[e]) + b2f(a3[e]));
            vr[g8 * 8 + e] = f;
            s1 += f; s2 = fmaf(f, f, s2);
        }
    }
    const float mu = s1 * (1.f / 128.f);
    const float var = s2 * (1.f / 128.f) - mu * mu;
    const float rstd = rsqrtf(var + 1e-5f);
    const float4* zp = (const float4*)(z + ((size_t)(b * 4096 + l)) * 128);
    const float4* gp = (const float4*)ong;
    const float4* bp = (const float4*)onb;
#pragma unroll
    for (int d4 = 0; d4 < 32; ++d4) {
        const float4 gg = gp[d4], bb = bp[d4], zz = zp[d4];
#define GATE(E, IDX)                                                          \
        {                                                                     \
            const float yln = (vr[d4 * 4 + IDX] - mu) * rstd * gg.E + bb.E;   \
            vr[d4 * 4 + IDX] = yln * (zz.E / (1.f + __expf(-zz.E)));          \
        }
        GATE(x, 0) GATE(y, 1) GATE(z, 2) GATE(w, 3)
#undef GATE
    }
    float acc[8] = {0.f, 0.f, 0.f, 0.f, 0.f, 0.f, 0.f, 0.f};
    for (int d4 = 0; d4 < 32; ++d4) {
#pragma unroll
        for (int q = 0; q < 8; ++q) {
            const float4 wv = *(const float4*)&opw[(size_t)(g * 8 + q) * 128 + d4 * 4];
            acc[q] = fmaf(vr[d4 * 4 + 0], wv.x, acc[q]);
            acc[q] = fmaf(vr[d4 * 4 + 1], wv.y, acc[q]);
            acc[q] = fmaf(vr[d4 * 4 + 2], wv.z, acc[q]);
            acc[q] = fmaf(vr[d4 * 4 + 3], wv.w, acc[q]);
        }
    }
    __shared__ float sres[64 * 33];
#pragma unroll
    for (int q = 0; q < 8; ++q) sres[(g * 8 + q) * 33 + j] = acc[q];
    __syncthreads();
    const float sk = skipp[0];
    for (int e = t; e < 2048; e += 256) {
        const int co = e >> 5, jj = e & 31;
        const size_t o = ((size_t)(b * 64 + co)) * 4096 + l0 + jj;
        res[o] = sres[co * 33 + jj] + sk * x1[o];
    }
}

// ---------------------------------------------------------------------------
// Workspace layout (floats), total 20,267,008 floats = 77.3 MB:
//   x1 @0 (1M), xin_s @1M (2M), zbuf @3M (2M), xin_T @5M (2M),
//   xdbl @7,340,032 (2,359,296),
//   ybuf @9,699,328 (bf16, 8,388,608 shorts = 4,194,304 float-slots),
//   hseg @13,893,632 (2,097,152), pseg @15,990,784 (2,097,152),
//   G @18,087,936 (2M): xin_raw / res+tmp + conv chain,
//   wbf @20,185,088 (81,920 floats = 163,840 bf16: 4 convs + in_proj)
// ---------------------------------------------------------------------------
extern "C" void kernel_launch(void* const* d_in, const int* in_sizes, int n_in,
                              void* d_out, int out_size, void* d_ws, size_t ws_size,
                              hipStream_t stream)
{
    const float* x          = (const float*)d_in[0];
    const float* conv1_w    = (const float*)d_in[1];
    const float* conv1_b    = (const float*)d_in[2];
    const float* conv2_w    = (const float*)d_in[3];
    const float* conv2_b    = (const float*)d_in[4];
    const float* cf_w       = (const float*)d_in[5];
    const float* cf_b       = (const float*)d_in[6];
    const float* ln_g       = (const float*)d_in[7];
    const float* ln_b       = (const float*)d_in[8];
    const float* in_proj_w  = (const float*)d_in[9];
    const float* dw_w       = (const float*)d_in[10];
    const float* dw_b       = (const float*)d_in[11];
    const float* x_proj_w   = (const float*)d_in[12];
    const float* dt_proj_w  = (const float*)d_in[13];
    const float* dt_proj_b  = (const float*)d_in[14];
    const float* A_logs     = (const float*)d_in[15];
    const float* Ds         = (const float*)d_in[16];
    const float* out_norm_g = (const float*)d_in[17];
    const float* out_norm_b = (const float*)d_in[18];
    const float* out_proj_w = (const float*)d_in[19];
    const float* skip_scale = (const float*)d_in[20];
    const float* cb_w       = (const float*)d_in[21];
    const float* cb_b       = (const float*)d_in[22];

    float* ws = (float*)d_ws;
    float* x1    = ws;                 // 1,048,576
    float* xin_s = ws + 1048576;       // 2,097,152
    float* zbuf  = ws + 3145728;       // 2,097,152
    float* xin_T = ws + 5242880;       // 2,097,152
    float* xdbl  = ws + 7340032;       // 2,359,296
    unsigned short* ybuf = (unsigned short*)(ws + 9699328);  // bf16 [k][b][l][d]
    float* hseg  = ws + 13893632;      // 2,097,152
    float* pseg  = ws + 15990784;      // 2,097,152
    float* G     = ws + 18087936;      // 2,097,152 scratch
    float* G0 = G;
    float* G1 = G + 1048576;
    short* wbf  = (short*)(ws + 20185088);  // 163,840 bf16
    short* wbf1 = wbf;                       // conv1
    short* wbf2 = wbf + 36864;               // conv2
    short* wbf3 = wbf + 73728;               // cf
    short* wbf4 = wbf + 110592;              // cb
    short* wip  = wbf + 147456;              // in_proj [256e][64c]

    wconv_k<<<640, 256, 0, stream>>>(conv1_w, conv2_w, cf_w, cb_w, in_proj_w, wbf);

    conv3x3_mfma_k<<<256, 256, 0, stream>>>(x, wbf1, conv1_b, nullptr, G0);
    inorm_lrelu_k<<<256, 256, 0, stream>>>(G0, G1);
    conv3x3_mfma_k<<<256, 256, 0, stream>>>(G1, wbf2, conv2_b, nullptr, G0);
    conv3x3_mfma_k<<<256, 256, 0, stream>>>(G0, wbf3, cf_b, nullptr, x1);
    ln_inproj_mfma_k<<<512, 256, 0, stream>>>(x1, ln_g, ln_b, wip, G /*xin_raw*/, zbuf);
    dwconv_silu_T_k<<<512, 256, 0, stream>>>(G /*xin_raw*/, dw_w, dw_b, xin_s, xin_T);
    xdbl_k<<<2048, 256, 0, stream>>>(xin_s, xin_T, x_proj_w, xdbl);
    scan_p1_k<<<8192, 256, 0, stream>>>(xdbl, xin_s, xin_T, A_logs, dt_proj_w,
                                        dt_proj_b, hseg, pseg);
    scan_combine_k<<<128, 256, 0, stream>>>(hseg, pseg /*-> hstart*/);
    scan_p2_k<<<8192, 256, 0, stream>>>(xdbl, xin_s, xin_T, A_logs, dt_proj_w,
                                        dt_proj_b, pseg /*hstart*/, Ds, ybuf);
    finalize_k<<<512, 256, 0, stream>>>(ybuf, zbuf, x1, out_norm_g, out_norm_b,
                                        out_proj_w, skip_scale, G0 /*res*/);
    conv3x3_mfma_k<<<256, 256, 0, stream>>>(G0 /*res*/, wbf4, cb_b, x1, G1 /*tmp*/);
    inorm_lrelu_k<<<256, 256, 0, stream>>>(G1 /*tmp*/, (float*)d_out);
}